// Round 9
// baseline (147.224 us; speedup 1.0000x reference)
//
#include <hip/hip_runtime.h>
#include <math.h>

// Problem constants (match reference)
#define N_ATOMS 768
#define FD 128          // feature width
#define NRBF 32
#define MAXN 64         // per-atom neighbor cap (mean ~26)
#define PPF 32          // fwd: pairs per block (2 M-tiles of 16)
#define PPBW 32         // bwd: pairs per block (2 M-tiles of 16) — MUST equal PPF (gate mask reuse)
#define FTILES (N_ATOMS * MAXN / PPF)     // 1536
#define BTILES (N_ATOMS * MAXN / PPBW)    // 1536
#define AST 132         // padded LDS stride for [*][128] f32 tiles
#define TST 136         // padded LDS stride for [*][128] bf16 (ushort) tiles
#define RSTU 40         // padded ushort stride for [*][32] bf16 rbf tiles (80B, 16B-aligned)

constexpr float  CUT2   = 25.0f;
constexpr float  GAMMA_ = 40.96f;            // 1/(5/32)^2
constexpr float  CSTEP  = 5.0f / 31.0f;      // linspace(0,5,32) step
constexpr double KB_D   = 8.617330337217213e-05;
constexpr double KT_D   = 300.0 * KB_D;
constexpr float  KT_F   = (float)KT_D;
constexpr float  TARGET_KE = (float)(0.5 * 2304.0 * KT_D);
constexpr float  Q0_F   = (float)(2.0 * 2304.0 * KT_D * 400.0);  // Q[0]
constexpr float  QI_F   = (float)(2.0 * KT_D * 400.0);           // Q[1..3]

#define DVDT_OFF 0
#define V_OFF    (3 * N_ATOMS)
#define PETA_OFF (6 * N_ATOMS)

using short8v = __attribute__((ext_vector_type(8))) short;
using f32x4   = __attribute__((ext_vector_type(4))) float;

#define MFMA_B16 __builtin_amdgcn_mfma_f32_16x16x32_bf16

__device__ __forceinline__ unsigned short f2bf(float x) {
    unsigned int u = __float_as_uint(x);
    u += 0x7FFF + ((u >> 16) & 1);           // round-to-nearest-even
    return (unsigned short)(u >> 16);
}
__device__ __forceinline__ float bf2f(unsigned short h) {
    return __uint_as_float(((unsigned int)h) << 16);
}

// Hard-won rules (25 rounds of counters):
// 1. NO __launch_bounds__ min-wave hints on GEMM kernels (spill cliff).
// 2. Reduce register demand STRUCTURALLY — phase-split through LDS.
// 3. NEVER put __threadfence / completion counters on the hot grid (R14).
// 4. R18/R19 FAILED: wave-spread mbar, LDS weight staging — vector GEMM was
//    in-phase-L2-latency bound; tiling/staging knobs don't move it.
// 5. R20 WIN: mbar extracted to own 768-block kernel (bwd 56->45.7).
// 6. R22-R24 WIN: MFMA split-bf16 (AhBh+AhBl+AlBh, err ~2^-17) for ALL dense
//    phases; absmax identical to fp32 baseline. Layouts: bwd w2b native,
//    fwd w2f[c][k]=W2[k][c], w1f[c][k]=W1[k][c]. C/D: col=lane&15,
//    row=(lane>>4)*4+reg (verified by exact absmax match).
// 7. R25 (+1.3us only): gate-mask reuse, in-reg gef, h-prefetch. Lesson:
//    math is no longer the cost — per-block fixed costs (staging gathers,
//    barriers, LDS round-trips, atomics tail, launch ramp) dominate.
// 8. R26: (a) fwd phase C fused into phase-B MFMA epilogue — filt produced
//    in the exact regs C consumed via a 16.9KB LDS buffer + barrier + serial
//    tail; now direct run-length-accumulated atomics (LDS 39.7->22.8 KB,
//    one barrier less). (b) bwd ts-fill split issue-early/convert-late so
//    gather latency hides under crbf __expf staging (T14).

// ---------------------------------------------------------------- prep
__global__ __launch_bounds__(256) void prep_kernel(
    const float* __restrict__ q, const int* __restrict__ z,
    const float* __restrict__ embed, const float* __restrict__ W1,
    const float* __restrict__ W2, const float* __restrict__ W3,
    float* __restrict__ h, float* __restrict__ W3T,
    unsigned short* __restrict__ w1fh, unsigned short* __restrict__ w1fl,
    unsigned short* __restrict__ w2fh, unsigned short* __restrict__ w2fl,
    unsigned short* __restrict__ w2bh, unsigned short* __restrict__ w2bl,
    int* __restrict__ pair_i, int* __restrict__ pair_j,
    float* __restrict__ pair_d, float* __restrict__ pair_dx,
    float* __restrict__ pair_dy, float* __restrict__ pair_dz,
    int* __restrict__ npairs_ctr,
    float* __restrict__ m, float* __restrict__ f_acc)
{
    __shared__ int   nj[MAXN];
    __shared__ float nd[MAXN], ndx[MAXN], ndy[MAXN], ndz[MAXN];
    __shared__ int cnt_s, base_s;
    int i = blockIdx.x, t = threadIdx.x;
    if (t == 0) cnt_s = 0;
    __syncthreads();
    float qx = q[i*3], qy = q[i*3+1], qz = q[i*3+2];
    for (int j = t; j < N_ATOMS; j += 256) {
        if (j == i) continue;
        float dx = qx - q[j*3], dy = qy - q[j*3+1], dz = qz - q[j*3+2];
        float d2 = dx*dx + dy*dy + dz*dz;
        if (d2 < CUT2) {
            int p = atomicAdd(&cnt_s, 1);
            if (p < MAXN) { nj[p] = j; nd[p] = sqrtf(d2);
                            ndx[p] = dx; ndy[p] = dy; ndz[p] = dz; }
        }
    }
    int g = i * 256 + t;                         // 196608 global ids
    if (g < N_ATOMS * FD) { h[g] = embed[z[g >> 7] * FD + (g & 127)]; m[g] = 0.f; }
    int g2 = g - N_ATOMS * FD;
    if (g2 >= 0 && g2 < FD * FD) {
        int r = g2 >> 7, c = g2 & 127;
        float w = W2[g2];                        // W2[r][c]
        unsigned short hb = f2bf(w);
        unsigned short lb = f2bf(w - bf2f(hb));
        w2bh[g2] = hb;                           // bwd B: w2b[c'][k]=W2[c'][k]
        w2bl[g2] = lb;                           //   (native layout)
        w2fh[c * FD + r] = hb;                   // fwd B: w2f[c][k]=W2[k][c]
        w2fl[c * FD + r] = lb;                   //   (transposed layout)
        W3T[c * FD + r] = W3[g2];
        if (g2 < NRBF * FD) {                    // W1: NRBF x FD, r=k, c=col
            float w1v = W1[g2];
            unsigned short h1 = f2bf(w1v);
            w1fh[c * NRBF + r] = h1;             // [c][k], k contiguous
            w1fl[c * NRBF + r] = f2bf(w1v - bf2f(h1));
        }
    }
    if (g < 3 * N_ATOMS) f_acc[g] = 0.f;
    __syncthreads();
    if (t == 0) base_s = atomicAdd(npairs_ctr, min(cnt_s, MAXN));
    __syncthreads();
    int cnt = min(cnt_s, MAXN), base = base_s;
    if (t < cnt) {
        pair_i[base+t] = i;      pair_j[base+t] = nj[t];
        pair_d[base+t] = nd[t];  pair_dx[base+t] = ndx[t];
        pair_dy[base+t] = ndy[t]; pair_dz[base+t] = ndz[t];
    }
}

// ---------------------------------------------------------------- fwd (PPF=32, MFMA)
// R26: stage -> h-prefetch -> phase A MFMA (+gate mask) -> phase B MFMA with
// FUSED phase-C epilogue (run-length-accumulated atomics; no filt LDS).
__global__ __launch_bounds__(256) void fwd_kernel(
    const unsigned short* __restrict__ w1fh, const unsigned short* __restrict__ w1fl,
    const float* __restrict__ b1,
    const unsigned short* __restrict__ w2fh, const unsigned short* __restrict__ w2fl,
    const float* __restrict__ b2, const float* __restrict__ h,
    const int* __restrict__ pair_i, const int* __restrict__ pair_j,
    const float* __restrict__ pair_d, const int* __restrict__ npairs_ctr,
    float* __restrict__ m, unsigned short* __restrict__ gatem)
{
    __shared__ __align__(16) unsigned short rbf_h[PPF * RSTU];  // 2560 B
    __shared__ __align__(16) unsigned short rbf_l[PPF * RSTU];  // 2560 B
    __shared__ __align__(16) unsigned short a1h[PPF * TST];     // 8704 B
    __shared__ __align__(16) unsigned short a1l[PPF * TST];     // 8704 B
    __shared__ int   pis[PPF], pjs[PPF];                        // 256 B (~22.8 KB)
    int t = threadIdx.x;
    int base = blockIdx.x * PPF;
    int np = npairs_ctr[0];
    if (base >= np) return;

    if (t < PPF) {
        int p = base + t; bool ok = p < np;
        pis[t] = ok ? pair_i[p] : 0;
        pjs[t] = ok ? pair_j[p] : 0;
    }
    for (int idx = t; idx < PPF * NRBF; idx += 256) {
        int p = idx >> 5, k = idx & 31;
        int gp = base + p;
        float d = (gp < np) ? pair_d[gp] : 1.0f;
        float u = d - CSTEP * (float)k;
        float r = __expf(-GAMMA_ * u * u);
        unsigned short hb = f2bf(r);
        rbf_h[p * RSTU + k] = hb;
        rbf_l[p * RSTU + k] = f2bf(r - bf2f(hb));
    }
    __syncthreads();

    int wid = t >> 6, lane = t & 63;
    int lr = lane & 15, lg = lane >> 4;
    int c0 = (2 * wid + 0) * 16 + lr;
    int c1 = (2 * wid + 1) * 16 + lr;

    // Fused-epilogue h prefetch: 16 scattered loads issued now, consumed
    // after phase B — latency overlaps both MFMA phases.
    float h00[4], h01[4], h10[4], h11[4];
#pragma unroll
    for (int r = 0; r < 4; r++) {
        int pA = lg * 4 + r, pB = pA + 16;
        h00[r] = h[pjs[pA] * FD + c0];
        h01[r] = h[pjs[pA] * FD + c1];
        h10[r] = h[pjs[pB] * FD + c0];
        h11[r] = h[pjs[pB] * FD + c1];
    }

    // Phase A (MFMA): u = b1 + rbf@W1 (split, 12 MFMA); relu+split in regs;
    // store 16-bit relu gate mask for bwd reuse.
    {
        float bb0 = b1[c0], bb1 = b1[c1];
        f32x4 u00 = {bb0,bb0,bb0,bb0}, u01 = {bb1,bb1,bb1,bb1};
        f32x4 u10 = {bb0,bb0,bb0,bb0}, u11 = {bb1,bb1,bb1,bb1};
        short8v rh0 = *(const short8v*)(rbf_h + lr * RSTU + lg * 8);
        short8v rh1 = *(const short8v*)(rbf_h + (16+lr) * RSTU + lg * 8);
        short8v rl0 = *(const short8v*)(rbf_l + lr * RSTU + lg * 8);
        short8v rl1 = *(const short8v*)(rbf_l + (16+lr) * RSTU + lg * 8);
        short8v bh0 = *(const short8v*)(w1fh + c0 * NRBF + lg * 8);
        short8v bh1 = *(const short8v*)(w1fh + c1 * NRBF + lg * 8);
        short8v bl0 = *(const short8v*)(w1fl + c0 * NRBF + lg * 8);
        short8v bl1 = *(const short8v*)(w1fl + c1 * NRBF + lg * 8);
        u00 = MFMA_B16(rh0, bh0, u00, 0,0,0); u01 = MFMA_B16(rh0, bh1, u01, 0,0,0);
        u10 = MFMA_B16(rh1, bh0, u10, 0,0,0); u11 = MFMA_B16(rh1, bh1, u11, 0,0,0);
        u00 = MFMA_B16(rh0, bl0, u00, 0,0,0); u01 = MFMA_B16(rh0, bl1, u01, 0,0,0);
        u10 = MFMA_B16(rh1, bl0, u10, 0,0,0); u11 = MFMA_B16(rh1, bl1, u11, 0,0,0);
        u00 = MFMA_B16(rl0, bh0, u00, 0,0,0); u01 = MFMA_B16(rl0, bh1, u01, 0,0,0);
        u10 = MFMA_B16(rl1, bh0, u10, 0,0,0); u11 = MFMA_B16(rl1, bh1, u11, 0,0,0);
        // C/D: col=lane&15, row=(lane>>4)*4+reg  [verified]
        unsigned int mk = 0;
#pragma unroll
        for (int r = 0; r < 4; r++) {
            int pA = lg * 4 + r, pB = 16 + lg * 4 + r;
            float v; unsigned short hb;
            if (u00[r] > 0.f) mk |= 1u << r;
            if (u01[r] > 0.f) mk |= 1u << (4 + r);
            if (u10[r] > 0.f) mk |= 1u << (8 + r);
            if (u11[r] > 0.f) mk |= 1u << (12 + r);
            v = fmaxf(u00[r], 0.f); hb = f2bf(v);
            a1h[pA * TST + c0] = hb; a1l[pA * TST + c0] = f2bf(v - bf2f(hb));
            v = fmaxf(u01[r], 0.f); hb = f2bf(v);
            a1h[pA * TST + c1] = hb; a1l[pA * TST + c1] = f2bf(v - bf2f(hb));
            v = fmaxf(u10[r], 0.f); hb = f2bf(v);
            a1h[pB * TST + c0] = hb; a1l[pB * TST + c0] = f2bf(v - bf2f(hb));
            v = fmaxf(u11[r], 0.f); hb = f2bf(v);
            a1h[pB * TST + c1] = hb; a1l[pB * TST + c1] = f2bf(v - bf2f(hb));
        }
        gatem[blockIdx.x * 256 + t] = (unsigned short)mk;
    }
    __syncthreads();

    // Phase B: filt = a1 @ W2 via MFMA (4 ksteps, split AhBh+AhBl+AlBh),
    // with FUSED phase-C epilogue straight from the accumulators.
    {
        f32x4 acc00 = {0.f,0.f,0.f,0.f}, acc01 = {0.f,0.f,0.f,0.f};
        f32x4 acc10 = {0.f,0.f,0.f,0.f}, acc11 = {0.f,0.f,0.f,0.f};
#pragma unroll
        for (int ks = 0; ks < 4; ks++) {
            int kb = ks * 32 + lg * 8;
            short8v ah0 = *(const short8v*)(a1h + (lr     ) * TST + kb);
            short8v ah1 = *(const short8v*)(a1h + (16 + lr) * TST + kb);
            short8v al0 = *(const short8v*)(a1l + (lr     ) * TST + kb);
            short8v al1 = *(const short8v*)(a1l + (16 + lr) * TST + kb);
            short8v bh0 = *(const short8v*)(w2fh + c0 * FD + kb);
            short8v bh1 = *(const short8v*)(w2fh + c1 * FD + kb);
            short8v bl0 = *(const short8v*)(w2fl + c0 * FD + kb);
            short8v bl1 = *(const short8v*)(w2fl + c1 * FD + kb);
            acc00 = MFMA_B16(ah0, bh0, acc00, 0,0,0);
            acc01 = MFMA_B16(ah0, bh1, acc01, 0,0,0);
            acc10 = MFMA_B16(ah1, bh0, acc10, 0,0,0);
            acc11 = MFMA_B16(ah1, bh1, acc11, 0,0,0);
            acc00 = MFMA_B16(ah0, bl0, acc00, 0,0,0);
            acc01 = MFMA_B16(ah0, bl1, acc01, 0,0,0);
            acc10 = MFMA_B16(ah1, bl0, acc10, 0,0,0);
            acc11 = MFMA_B16(ah1, bl1, acc11, 0,0,0);
            acc00 = MFMA_B16(al0, bh0, acc00, 0,0,0);
            acc01 = MFMA_B16(al0, bh1, acc01, 0,0,0);
            acc10 = MFMA_B16(al1, bh0, acc10, 0,0,0);
            acc11 = MFMA_B16(al1, bh1, acc11, 0,0,0);
        }
        // Fused phase C: m[i_p, c] += (filt[p][c] + b2[c]) * h[j_p][c].
        // Run-length accumulate over the 4 consecutive pairs this thread
        // holds per (mtile, col) before touching the atomic.
        float b2c0 = b2[c0], b2c1 = b2[c1];
        {   // mtile0, col c0
            float a = 0.f; int cur = pis[lg * 4];
#pragma unroll
            for (int r = 0; r < 4; r++) {
                int pA = lg * 4 + r; int ip = pis[pA];
                if (ip != cur) { atomicAdd(m + cur * FD + c0, a); a = 0.f; cur = ip; }
                if (base + pA < np) a += (acc00[r] + b2c0) * h00[r];
            }
            atomicAdd(m + cur * FD + c0, a);
        }
        {   // mtile0, col c1
            float a = 0.f; int cur = pis[lg * 4];
#pragma unroll
            for (int r = 0; r < 4; r++) {
                int pA = lg * 4 + r; int ip = pis[pA];
                if (ip != cur) { atomicAdd(m + cur * FD + c1, a); a = 0.f; cur = ip; }
                if (base + pA < np) a += (acc01[r] + b2c1) * h01[r];
            }
            atomicAdd(m + cur * FD + c1, a);
        }
        {   // mtile1, col c0
            float a = 0.f; int cur = pis[16 + lg * 4];
#pragma unroll
            for (int r = 0; r < 4; r++) {
                int pB = 16 + lg * 4 + r; int ip = pis[pB];
                if (ip != cur) { atomicAdd(m + cur * FD + c0, a); a = 0.f; cur = ip; }
                if (base + pB < np) a += (acc10[r] + b2c0) * h10[r];
            }
            atomicAdd(m + cur * FD + c0, a);
        }
        {   // mtile1, col c1
            float a = 0.f; int cur = pis[16 + lg * 4];
#pragma unroll
            for (int r = 0; r < 4; r++) {
                int pB = 16 + lg * 4 + r; int ip = pis[pB];
                if (ip != cur) { atomicAdd(m + cur * FD + c1, a); a = 0.f; cur = ip; }
                if (base + pB < np) a += (acc11[r] + b2c1) * h11[r];
            }
            atomicAdd(m + cur * FD + c1, a);
        }
    }
}

// ---------------------------------------------------------------- mbar (R20/R25)
// One block per atom: mbar_i = W3T @ (wout * gate(m_i @ W3)).
// Operand-swapped reads -> per-thread contiguous float4 streams.
__global__ __launch_bounds__(256) void mbar_kernel(
    const float* __restrict__ m, const float* __restrict__ W3,
    const float* __restrict__ W3T, const float* __restrict__ wout,
    float* __restrict__ mbar)
{
    __shared__ float mrow[FD];
    __shared__ float gb[FD];
    __shared__ float part[256];
    int i = blockIdx.x, t = threadIdx.x;
    if (t < FD) mrow[t] = m[i * FD + t];
    __syncthreads();
    int c = t & 127, hh = t >> 7;          // hh = 0/1 -> f half
    int f0 = hh * 64;
    float g = 0.f;
#pragma unroll 4
    for (int f4 = f0; f4 < f0 + 64; f4 += 4) {
        float4 w  = *(const float4*)(W3T + c * FD + f4);   // W3T[c][f]=W3[f][c]
        float4 mr = *(const float4*)(mrow + f4);
        g += mr.x*w.x + mr.y*w.y + mr.z*w.z + mr.w*w.w;
    }
    part[t] = g;
    __syncthreads();
    if (t < FD) gb[t] = (part[t] + part[t + 128] > 0.f) ? wout[t] : 0.f;
    __syncthreads();
    float mb = 0.f;
#pragma unroll 4
    for (int f4 = f0; f4 < f0 + 64; f4 += 4) {
        float4 w  = *(const float4*)(W3 + c * FD + f4);    // W3[c][f]=W3T[f][c]
        float4 gv = *(const float4*)(gb + f4);
        mb += gv.x*w.x + gv.y*w.y + gv.z*w.z + gv.w*w.w;
    }
    part[t] = mb;
    __syncthreads();
    if (t < FD) mbar[i * FD + t] = part[t] + part[t + 128];
}

// ---------------------------------------------------------------- bwd (PPBW=32, MFMA)
// R26: {loads issued early -> crbf expf staging (hides latency) -> ts convert}
// -> barrier -> gef MFMA (in regs, gate mask) -> GEMM MFMA -> fold+reduce ->
// scatter. 2 barriers.
__global__ __launch_bounds__(256) void bwd_kernel(
    const unsigned short* __restrict__ w1fh, const unsigned short* __restrict__ w1fl,
    const unsigned short* __restrict__ w2bh, const unsigned short* __restrict__ w2bl,
    const float* __restrict__ h, const float* __restrict__ mbar,
    const unsigned short* __restrict__ gatem,
    const int* __restrict__ pair_i, const int* __restrict__ pair_j,
    const float* __restrict__ pair_d, const float* __restrict__ pair_dx,
    const float* __restrict__ pair_dy, const float* __restrict__ pair_dz,
    const int* __restrict__ npairs_ctr, float* __restrict__ f_acc)
{
    __shared__ __align__(16) unsigned short crbf_h[PPBW * RSTU];  // 2560 B
    __shared__ __align__(16) unsigned short crbf_l[PPBW * RSTU];  // 2560 B
    __shared__ __align__(16) unsigned short ts_h[PPBW * TST];     // 8704 B
    __shared__ __align__(16) unsigned short ts_l[PPBW * TST];     // 8704 B
    __shared__ float sred[4 * PPBW];                              // 512 B
    __shared__ int   pis[PPBW], pjs[PPBW];                        // 256 B (~23.3 KB)
    int t = threadIdx.x;
    int base = blockIdx.x * PPBW;
    int np = npairs_ctr[0];
    if (base >= np) return;

    if (t < PPBW) {
        int p = base + t; bool ok = p < np;
        pis[t] = ok ? pair_i[p] : 0;
        pjs[t] = ok ? pair_j[p] : 0;
    }
    unsigned int mk = gatem[blockIdx.x * 256 + t];   // fwd-stored relu gates

    // ts-fill loads ISSUED EARLY (T14): latency hides under expf staging.
    float4 mb4v[4], hj4v[4];
#pragma unroll
    for (int e = 0; e < 4; e++) {
        int idx = t + e * 256;
        int p = idx >> 5, c4g = (idx & 31) * 4;
        int gp = base + p;
        int ip = (gp < np) ? pair_i[gp] : 0;
        int jp = (gp < np) ? pair_j[gp] : 0;
        mb4v[e] = *(const float4*)(mbar + ip * FD + c4g);
        hj4v[e] = *(const float4*)(h    + jp * FD + c4g);
    }

    // crbf staging (VALU expf) — overlaps the gathers above.
#pragma unroll
    for (int e = 0; e < 4; e++) {
        int idx = t + e * 256;
        int p = idx >> 5, k = idx & 31;
        int gp = base + p;
        float d = (gp < np) ? pair_d[gp] : 1.0f;
        float u = d - CSTEP * (float)k;
        float r = __expf(-GAMMA_ * u * u);
        float cd = -2.f * GAMMA_ * u * r;
        unsigned short hc = f2bf(cd);
        crbf_h[p * RSTU + k] = hc;
        crbf_l[p * RSTU + k] = f2bf(cd - bf2f(hc));
    }

    // scatter-phase pair data prefetch (threads 0..31)
    float pd = 1.f, pdx = 0.f, pdy = 0.f, pdz = 0.f;
    if (t < PPBW && base + t < np) {
        pd  = pair_d [base + t];
        pdx = pair_dx[base + t];
        pdy = pair_dy[base + t];
        pdz = pair_dz[base + t];
    }

    // ts convert + store (loads have landed by now).
#pragma unroll
    for (int e = 0; e < 4; e++) {
        int idx = t + e * 256;
        int p = idx >> 5, c4g = (idx & 31) * 4;
        float4 mb4 = mb4v[e], hj4 = hj4v[e];
        float v0 = mb4.x*hj4.x, v1 = mb4.y*hj4.y, v2 = mb4.z*hj4.z, v3 = mb4.w*hj4.w;
        ushort4 hv, lv;
        hv.x = f2bf(v0); lv.x = f2bf(v0 - bf2f(hv.x));
        hv.y = f2bf(v1); lv.y = f2bf(v1 - bf2f(hv.y));
        hv.z = f2bf(v2); lv.z = f2bf(v2 - bf2f(hv.z));
        hv.w = f2bf(v3); lv.w = f2bf(v3 - bf2f(hv.w));
        *(ushort4*)(ts_h + p * TST + c4g) = hv;
        *(ushort4*)(ts_l + p * TST + c4g) = lv;
    }
    __syncthreads();                       // crbf + ts + pis/pjs ready

    {
        int wid = t >> 6, lane = t & 63;
        int lr = lane & 15, lg = lane >> 4;
        int c0 = (2 * wid + 0) * 16 + lr;
        int c1 = (2 * wid + 1) * 16 + lr;

        // gef (12 MFMA, in registers): ef = crbf@W1 split; gate via mask.
        f32x4 e00 = {0.f,0.f,0.f,0.f}, e01 = {0.f,0.f,0.f,0.f};
        f32x4 e10 = {0.f,0.f,0.f,0.f}, e11 = {0.f,0.f,0.f,0.f};
        {
            short8v ch0 = *(const short8v*)(crbf_h + lr * RSTU + lg * 8);
            short8v ch1 = *(const short8v*)(crbf_h + (16+lr) * RSTU + lg * 8);
            short8v cl0 = *(const short8v*)(crbf_l + lr * RSTU + lg * 8);
            short8v cl1 = *(const short8v*)(crbf_l + (16+lr) * RSTU + lg * 8);
            short8v bh0 = *(const short8v*)(w1fh + c0 * NRBF + lg * 8);
            short8v bh1 = *(const short8v*)(w1fh + c1 * NRBF + lg * 8);
            short8v bl0 = *(const short8v*)(w1fl + c0 * NRBF + lg * 8);
            short8v bl1 = *(const short8v*)(w1fl + c1 * NRBF + lg * 8);
            e00 = MFMA_B16(ch0, bh0, e00, 0,0,0); e01 = MFMA_B16(ch0, bh1, e01, 0,0,0);
            e10 = MFMA_B16(ch1, bh0, e10, 0,0,0); e11 = MFMA_B16(ch1, bh1, e11, 0,0,0);
            e00 = MFMA_B16(ch0, bl0, e00, 0,0,0); e01 = MFMA_B16(ch0, bl1, e01, 0,0,0);
            e10 = MFMA_B16(ch1, bl0, e10, 0,0,0); e11 = MFMA_B16(ch1, bl1, e11, 0,0,0);
            e00 = MFMA_B16(cl0, bh0, e00, 0,0,0); e01 = MFMA_B16(cl0, bh1, e01, 0,0,0);
            e10 = MFMA_B16(cl1, bh0, e10, 0,0,0); e11 = MFMA_B16(cl1, bh1, e11, 0,0,0);
        }
#pragma unroll
        for (int r = 0; r < 4; r++) {
            e00[r] = (mk & (1u <<  r      )) ? e00[r] : 0.f;
            e01[r] = (mk & (1u << (4 + r))) ? e01[r] : 0.f;
            e10[r] = (mk & (1u << (8 + r))) ? e10[r] : 0.f;
            e11[r] = (mk & (1u << (12 + r))) ? e11[r] : 0.f;
        }

        // GEMM: du1 = ts @ W2T (B[k][c']=W2[c'][k] from native-layout w2b).
        f32x4 acc00 = {0.f,0.f,0.f,0.f}, acc01 = {0.f,0.f,0.f,0.f};
        f32x4 acc10 = {0.f,0.f,0.f,0.f}, acc11 = {0.f,0.f,0.f,0.f};
#pragma unroll
        for (int ks = 0; ks < 4; ks++) {
            int kb = ks * 32 + lg * 8;
            short8v ah0 = *(const short8v*)(ts_h + (lr     ) * TST + kb);
            short8v ah1 = *(const short8v*)(ts_h + (16 + lr) * TST + kb);
            short8v al0 = *(const short8v*)(ts_l + (lr     ) * TST + kb);
            short8v al1 = *(const short8v*)(ts_l + (16 + lr) * TST + kb);
            short8v bh0 = *(const short8v*)(w2bh + c0 * FD + kb);
            short8v bh1 = *(const short8v*)(w2bh + c1 * FD + kb);
            short8v bl0 = *(const short8v*)(w2bl + c0 * FD + kb);
            short8v bl1 = *(const short8v*)(w2bl + c1 * FD + kb);
            acc00 = MFMA_B16(ah0, bh0, acc00, 0,0,0);
            acc01 = MFMA_B16(ah0, bh1, acc01, 0,0,0);
            acc10 = MFMA_B16(ah1, bh0, acc10, 0,0,0);
            acc11 = MFMA_B16(ah1, bh1, acc11, 0,0,0);
            acc00 = MFMA_B16(ah0, bl0, acc00, 0,0,0);
            acc01 = MFMA_B16(ah0, bl1, acc01, 0,0,0);
            acc10 = MFMA_B16(ah1, bl0, acc10, 0,0,0);
            acc11 = MFMA_B16(ah1, bl1, acc11, 0,0,0);
            acc00 = MFMA_B16(al0, bh0, acc00, 0,0,0);
            acc01 = MFMA_B16(al0, bh1, acc01, 0,0,0);
            acc10 = MFMA_B16(al1, bh0, acc10, 0,0,0);
            acc11 = MFMA_B16(al1, bh1, acc11, 0,0,0);
        }

        // Epilogue: fold in-register gef, 16-lane shuffle reduce over cols.
        float part[8];
#pragma unroll
        for (int r = 0; r < 4; r++) {
            part[r]     = acc00[r] * e00[r] + acc01[r] * e01[r];
            part[4 + r] = acc10[r] * e10[r] + acc11[r] * e11[r];
        }
#pragma unroll
        for (int mask = 1; mask < 16; mask <<= 1) {
#pragma unroll
            for (int e = 0; e < 8; e++) part[e] += __shfl_xor(part[e], mask, 64);
        }
        if (lr == 0) {
#pragma unroll
            for (int r = 0; r < 4; r++) {
                sred[wid * PPBW + lg * 4 + r]      = part[r];
                sred[wid * PPBW + 16 + lg * 4 + r] = part[4 + r];
            }
        }
    }
    __syncthreads();

    // Final per-pair scatter (32 pairs by threads 0..31; pair data prefetched)
    if (t < PPBW) {
        int gp = base + t;
        if (gp < np) {
            float s = sred[t] + sred[PPBW + t] + sred[2*PPBW + t] + sred[3*PPBW + t];
            int ii = pis[t], jj = pjs[t];
            float coef = s / pd;
            float fx = coef * pdx;
            float fy = coef * pdy;
            float fz = coef * pdz;
            atomicAdd(f_acc + ii*3 + 0, -fx);
            atomicAdd(f_acc + ii*3 + 1, -fy);
            atomicAdd(f_acc + ii*3 + 2, -fz);
            atomicAdd(f_acc + jj*3 + 0, fx);
            atomicAdd(f_acc + jj*3 + 1, fy);
            atomicAdd(f_acc + jj*3 + 2, fz);
        }
    }
}

// ---------------------------------------------------------------- finalize
__global__ __launch_bounds__(256) void fin_kernel(
    const float* __restrict__ v, const float* __restrict__ mass,
    const float* __restrict__ p_eta, const float* __restrict__ f_acc,
    float* __restrict__ out)
{
    __shared__ float red[256];
    int t = threadIdx.x;
    float ke = 0.f;
    float c = p_eta[0] / Q0_F;
    for (int idx = t; idx < 3 * N_ATOMS; idx += 256) {
        int a = idx / 3;
        float vv = v[idx], mi = mass[a];
        out[DVDT_OFF + idx] = (f_acc[idx] - c * vv * mi) / mi;
        out[V_OFF + idx] = vv;
        ke += 0.5f * mi * vv * vv;
    }
    red[t] = ke;
    __syncthreads();
    for (int s = 128; s > 0; s >>= 1) {
        if (t < s) red[t] += red[t + s];
        __syncthreads();
    }
    if (t == 0) {
        float k0 = red[0];
        float e0 = p_eta[0], e1 = p_eta[1], e2 = p_eta[2], e3 = p_eta[3];
        out[PETA_OFF + 0] = 2.f * (k0 - TARGET_KE) - e0 * e1 / QI_F;
        out[PETA_OFF + 1] = e0 * e0 / Q0_F - KT_F - e1 * e2 / QI_F;
        out[PETA_OFF + 2] = e1 * e1 / QI_F - KT_F - e2 * e3 / QI_F;
        out[PETA_OFF + 3] = e2 * e2 / QI_F - KT_F;
    }
}

// ---------------------------------------------------------------- launch
extern "C" void kernel_launch(void* const* d_in, const int* in_sizes, int n_in,
                              void* d_out, int out_size, void* d_ws, size_t ws_size,
                              hipStream_t stream)
{
    const float* v     = (const float*)d_in[0];
    const float* q     = (const float*)d_in[1];
    const float* p_eta = (const float*)d_in[2];
    const float* mass  = (const float*)d_in[3];
    const float* embed = (const float*)d_in[4];
    const float* W1    = (const float*)d_in[5];
    const float* b1    = (const float*)d_in[6];
    const float* W2    = (const float*)d_in[7];
    const float* b2    = (const float*)d_in[8];
    const float* W3    = (const float*)d_in[9];
    const float* wout  = (const float*)d_in[10];
    const int*   z     = (const int*)d_in[11];
    float* out = (float*)d_out;

    float* h     = (float*)d_ws;
    float* W2T_unused = h + N_ATOMS * FD;        // slot kept (layout stability)
    float* W3T   = W2T_unused + FD * FD;
    float* m     = W3T + FD * FD;
    float* f_acc = m + N_ATOMS * FD;
    float* pair_d  = f_acc + 3 * N_ATOMS;
    float* pair_dx = pair_d + N_ATOMS * MAXN;
    float* pair_dy = pair_dx + N_ATOMS * MAXN;
    float* pair_dz = pair_dy + N_ATOMS * MAXN;
    int* pair_i = (int*)(pair_dz + N_ATOMS * MAXN);
    int* pair_j = pair_i + N_ATOMS * MAXN;
    int* npairs_ctr = pair_j + N_ATOMS * MAXN;
    float* mbar  = (float*)(npairs_ctr + 64);     // 64-int pad for alignment
    unsigned short* w2bh = (unsigned short*)(mbar + N_ATOMS * FD);
    unsigned short* w2bl = w2bh + FD * FD;
    unsigned short* w2fh = w2bl + FD * FD;
    unsigned short* w2fl = w2fh + FD * FD;
    unsigned short* w1fh = w2fl + FD * FD;
    unsigned short* w1fl = w1fh + NRBF * FD;
    unsigned short* gatem = w1fl + NRBF * FD;     // FTILES*256 gate masks

    hipMemsetAsync(npairs_ctr, 0, sizeof(int), stream);

    prep_kernel<<<N_ATOMS, 256, 0, stream>>>(q, z, embed, W1, W2, W3, h, W3T,
                                             w1fh, w1fl, w2fh, w2fl, w2bh, w2bl,
                                             pair_i, pair_j, pair_d,
                                             pair_dx, pair_dy, pair_dz,
                                             npairs_ctr, m, f_acc);
    fwd_kernel<<<FTILES, 256, 0, stream>>>(w1fh, w1fl, b1, w2fh, w2fl, b2, h,
                                           pair_i, pair_j, pair_d, npairs_ctr,
                                           m, gatem);
    mbar_kernel<<<N_ATOMS, 256, 0, stream>>>(m, W3, W3T, wout, mbar);
    bwd_kernel<<<BTILES, 256, 0, stream>>>(w1fh, w1fl, w2bh, w2bl, h, mbar,
                                           gatem,
                                           pair_i, pair_j, pair_d, pair_dx,
                                           pair_dy, pair_dz, npairs_ctr, f_acc);
    fin_kernel<<<1, 256, 0, stream>>>(v, mass, p_eta, f_acc, out);
}

// Round 10
// 140.920 us; speedup vs baseline: 1.0447x; 1.0447x over previous
//
#include <hip/hip_runtime.h>
#include <math.h>

// Problem constants (match reference)
#define N_ATOMS 768
#define FD 128          // feature width
#define NRBF 32
#define MAXN 64         // per-atom neighbor cap (mean ~26)
#define PPF 32          // pairs per MFMA pass (2 M-tiles of 16)
#define AST 132         // padded LDS stride for [*][128] f32 tiles
#define TST 136         // padded LDS stride for [*][128] bf16 (ushort) tiles
#define RSTU 40         // padded ushort stride for [*][32] bf16 rbf tiles (80B, 16B-aligned)

constexpr float  CUT2   = 25.0f;
constexpr float  GAMMA_ = 40.96f;            // 1/(5/32)^2
constexpr float  CSTEP  = 5.0f / 31.0f;      // linspace(0,5,32) step
constexpr double KB_D   = 8.617330337217213e-05;
constexpr double KT_D   = 300.0 * KB_D;
constexpr float  KT_F   = (float)KT_D;
constexpr float  TARGET_KE = (float)(0.5 * 2304.0 * KT_D);
constexpr float  Q0_F   = (float)(2.0 * 2304.0 * KT_D * 400.0);  // Q[0]
constexpr float  QI_F   = (float)(2.0 * KT_D * 400.0);           // Q[1..3]

#define DVDT_OFF 0
#define V_OFF    (3 * N_ATOMS)
#define PETA_OFF (6 * N_ATOMS)

using short8v = __attribute__((ext_vector_type(8))) short;
using f32x4   = __attribute__((ext_vector_type(4))) float;

#define MFMA_B16 __builtin_amdgcn_mfma_f32_16x16x32_bf16

__device__ __forceinline__ unsigned short f2bf(float x) {
    unsigned int u = __float_as_uint(x);
    u += 0x7FFF + ((u >> 16) & 1);           // round-to-nearest-even
    return (unsigned short)(u >> 16);
}
__device__ __forceinline__ float bf2f(unsigned short h) {
    return __uint_as_float(((unsigned int)h) << 16);
}

// Hard-won rules (26 rounds of counters):
// 1. NO __launch_bounds__ min-wave hints on GEMM kernels (spill cliff).
// 2. NEVER put __threadfence / completion counters on the hot grid (R14).
// 3. R18/R19 FAILED: wave-spread mbar, LDS weight staging.
// 4. R20 WIN: mbar in its own 768-block kernel (not fused into bwd tiles).
// 5. R22-R24 WIN: MFMA split-bf16 (AhBh+AhBl+AlBh, err ~2^-17) for all dense
//    phases. Layouts: bwd w2b native; fwd w2f[c][k]=W2[k][c];
//    w1f[c][k]=W1[k][c]. C/D: col=lane&15, row=(lane>>4)*4+reg (verified).
// 6. R25 WIN (small): gate-mask reuse fwd->bwd, in-reg gef.
// 7. R26 REGRESSED (+4.3us): fused fwd epilogue w/ per-run atomics = 3x
//    atomic count + 4-way same-address wave contention. Reverted.
// 8. R27: per-ATOM blocks (768) for fwd/bwd. fwd builds+persists neighbor
//    list (fixed slots, no global counter -> no memset dispatch; prep slims
//    to a fill kernel), writes m[i] DIRECTLY (shuffle-reduce over lg, zero
//    atomics, no m pre-zero). bwd reads stored list + mbar[i] once.

// ---------------------------------------------------------------- prep (fill only)
__global__ __launch_bounds__(256) void prep_kernel(
    const int* __restrict__ z, const float* __restrict__ embed,
    const float* __restrict__ W1, const float* __restrict__ W2,
    const float* __restrict__ W3,
    float* __restrict__ h, float* __restrict__ W3T,
    unsigned short* __restrict__ w1fh, unsigned short* __restrict__ w1fl,
    unsigned short* __restrict__ w2fh, unsigned short* __restrict__ w2fl,
    unsigned short* __restrict__ w2bh, unsigned short* __restrict__ w2bl,
    float* __restrict__ f_acc)
{
    int g = blockIdx.x * 256 + threadIdx.x;      // 98304 ids (384 blocks)
    if (g < N_ATOMS * FD) h[g] = embed[z[g >> 7] * FD + (g & 127)];
    if (g < FD * FD) {
        int r = g >> 7, c = g & 127;
        float w = W2[g];                         // W2[r][c]
        unsigned short hb = f2bf(w);
        unsigned short lb = f2bf(w - bf2f(hb));
        w2bh[g] = hb;                            // bwd B: native layout
        w2bl[g] = lb;
        w2fh[c * FD + r] = hb;                   // fwd B: w2f[c][k]=W2[k][c]
        w2fl[c * FD + r] = lb;
        W3T[c * FD + r] = W3[g];
        if (g < NRBF * FD) {                     // W1: NRBF x FD (r=k)
            float w1v = W1[g];
            unsigned short h1 = f2bf(w1v);
            w1fh[c * NRBF + r] = h1;             // [c][k], k contiguous
            w1fl[c * NRBF + r] = f2bf(w1v - bf2f(h1));
        }
    }
    if (g < 3 * N_ATOMS) f_acc[g] = 0.f;
}

// ---------------------------------------------------------------- fwd (768 blocks, per-atom)
// Build neighbor list -> persist -> per-32-pair pass: rbf stage -> A MFMA
// (+gate mask) -> B MFMA -> reg-accumulate (filt+b2)*h -> shuffle-reduce ->
// DIRECT m[i] store (no atomics).
__global__ __launch_bounds__(256) void fwd_kernel(
    const float* __restrict__ q,
    const unsigned short* __restrict__ w1fh, const unsigned short* __restrict__ w1fl,
    const float* __restrict__ b1,
    const unsigned short* __restrict__ w2fh, const unsigned short* __restrict__ w2fl,
    const float* __restrict__ b2, const float* __restrict__ h,
    float* __restrict__ m, unsigned short* __restrict__ gatem,
    int* __restrict__ nj_g, float* __restrict__ nd_g,
    float* __restrict__ ndx_g, float* __restrict__ ndy_g,
    float* __restrict__ ndz_g, int* __restrict__ cnt_g)
{
    __shared__ int   nj[MAXN];
    __shared__ float nd[MAXN], ndx[MAXN], ndy[MAXN], ndz[MAXN];
    __shared__ int   cnt_s;
    __shared__ __align__(16) unsigned short rbf_h[PPF * RSTU];  // 2560 B
    __shared__ __align__(16) unsigned short rbf_l[PPF * RSTU];  // 2560 B
    __shared__ __align__(16) unsigned short a1h[PPF * TST];     // 8704 B
    __shared__ __align__(16) unsigned short a1l[PPF * TST];     // 8704 B
    int i = blockIdx.x, t = threadIdx.x;
    if (t == 0) cnt_s = 0;
    __syncthreads();
    float qx = q[i*3], qy = q[i*3+1], qz = q[i*3+2];
    for (int j = t; j < N_ATOMS; j += 256) {
        if (j == i) continue;
        float dx = qx - q[j*3], dy = qy - q[j*3+1], dz = qz - q[j*3+2];
        float d2 = dx*dx + dy*dy + dz*dz;
        if (d2 < CUT2) {
            int p = atomicAdd(&cnt_s, 1);
            if (p < MAXN) { nj[p] = j; nd[p] = sqrtf(d2);
                            ndx[p] = dx; ndy[p] = dy; ndz[p] = dz; }
        }
    }
    __syncthreads();
    int cnt = min(cnt_s, MAXN);
    if (t == 0) cnt_g[i] = cnt;
    if (t < cnt) {                               // persist for bwd
        nj_g [i*MAXN + t] = nj[t];
        nd_g [i*MAXN + t] = nd[t];
        ndx_g[i*MAXN + t] = ndx[t];
        ndy_g[i*MAXN + t] = ndy[t];
        ndz_g[i*MAXN + t] = ndz[t];
    }

    int wid = t >> 6, lane = t & 63;
    int lr = lane & 15, lg = lane >> 4;
    int c0 = (2 * wid + 0) * 16 + lr;
    int c1 = (2 * wid + 1) * 16 + lr;
    float bb0 = b1[c0], bb1 = b1[c1];
    float b2c0 = b2[c0], b2c1 = b2[c1];
    float macc0 = 0.f, macc1 = 0.f;              // m[i][c0], m[i][c1] partials

    int npass = (cnt + PPF - 1) / PPF;           // 0..2
    for (int pass = 0; pass < npass; pass++) {
        int p0 = pass * PPF;
        // rbf staging (pass-local rows 0..31)
#pragma unroll
        for (int e = 0; e < 4; e++) {
            int idx = t + e * 256;
            int p = idx >> 5, k = idx & 31;
            int pp = p0 + p;
            float d = (pp < cnt) ? nd[pp] : 1.0f;
            float u = d - CSTEP * (float)k;
            float r = __expf(-GAMMA_ * u * u);
            unsigned short hb = f2bf(r);
            rbf_h[p * RSTU + k] = hb;
            rbf_l[p * RSTU + k] = f2bf(r - bf2f(hb));
        }
        __syncthreads();

        // h prefetch for this thread's 8 pairs (0 for invalid -> zero contrib)
        float h00[4], h01[4], h10[4], h11[4];
#pragma unroll
        for (int r = 0; r < 4; r++) {
            int pA = p0 + lg * 4 + r, pB = pA + 16;
            bool vA = pA < cnt, vB = pB < cnt;
            int jA = vA ? nj[pA] : 0, jB = vB ? nj[pB] : 0;
            h00[r] = vA ? h[jA * FD + c0] : 0.f;
            h01[r] = vA ? h[jA * FD + c1] : 0.f;
            h10[r] = vB ? h[jB * FD + c0] : 0.f;
            h11[r] = vB ? h[jB * FD + c1] : 0.f;
        }

        // Phase A (MFMA, 12): u = b1 + rbf@W1 split; relu+split; gate mask.
        {
            f32x4 u00 = {bb0,bb0,bb0,bb0}, u01 = {bb1,bb1,bb1,bb1};
            f32x4 u10 = {bb0,bb0,bb0,bb0}, u11 = {bb1,bb1,bb1,bb1};
            short8v rh0 = *(const short8v*)(rbf_h + lr * RSTU + lg * 8);
            short8v rh1 = *(const short8v*)(rbf_h + (16+lr) * RSTU + lg * 8);
            short8v rl0 = *(const short8v*)(rbf_l + lr * RSTU + lg * 8);
            short8v rl1 = *(const short8v*)(rbf_l + (16+lr) * RSTU + lg * 8);
            short8v bh0 = *(const short8v*)(w1fh + c0 * NRBF + lg * 8);
            short8v bh1 = *(const short8v*)(w1fh + c1 * NRBF + lg * 8);
            short8v bl0 = *(const short8v*)(w1fl + c0 * NRBF + lg * 8);
            short8v bl1 = *(const short8v*)(w1fl + c1 * NRBF + lg * 8);
            u00 = MFMA_B16(rh0, bh0, u00, 0,0,0); u01 = MFMA_B16(rh0, bh1, u01, 0,0,0);
            u10 = MFMA_B16(rh1, bh0, u10, 0,0,0); u11 = MFMA_B16(rh1, bh1, u11, 0,0,0);
            u00 = MFMA_B16(rh0, bl0, u00, 0,0,0); u01 = MFMA_B16(rh0, bl1, u01, 0,0,0);
            u10 = MFMA_B16(rh1, bl0, u10, 0,0,0); u11 = MFMA_B16(rh1, bl1, u11, 0,0,0);
            u00 = MFMA_B16(rl0, bh0, u00, 0,0,0); u01 = MFMA_B16(rl0, bh1, u01, 0,0,0);
            u10 = MFMA_B16(rl1, bh0, u10, 0,0,0); u11 = MFMA_B16(rl1, bh1, u11, 0,0,0);
            // C/D: col=lane&15, row=(lane>>4)*4+reg  [verified]
            unsigned int mk = 0;
#pragma unroll
            for (int r = 0; r < 4; r++) {
                int pA = lg * 4 + r, pB = 16 + lg * 4 + r;
                float v; unsigned short hb;
                if (u00[r] > 0.f) mk |= 1u << r;
                if (u01[r] > 0.f) mk |= 1u << (4 + r);
                if (u10[r] > 0.f) mk |= 1u << (8 + r);
                if (u11[r] > 0.f) mk |= 1u << (12 + r);
                v = fmaxf(u00[r], 0.f); hb = f2bf(v);
                a1h[pA * TST + c0] = hb; a1l[pA * TST + c0] = f2bf(v - bf2f(hb));
                v = fmaxf(u01[r], 0.f); hb = f2bf(v);
                a1h[pA * TST + c1] = hb; a1l[pA * TST + c1] = f2bf(v - bf2f(hb));
                v = fmaxf(u10[r], 0.f); hb = f2bf(v);
                a1h[pB * TST + c0] = hb; a1l[pB * TST + c0] = f2bf(v - bf2f(hb));
                v = fmaxf(u11[r], 0.f); hb = f2bf(v);
                a1h[pB * TST + c1] = hb; a1l[pB * TST + c1] = f2bf(v - bf2f(hb));
            }
            gatem[(i * 2 + pass) * 256 + t] = (unsigned short)mk;
        }
        __syncthreads();

        // Phase B (MFMA): filt = a1 @ W2 split; epilogue accumulates
        // (filt + b2) * h_j into macc registers (all pairs share atom i).
        {
            f32x4 acc00 = {0.f,0.f,0.f,0.f}, acc01 = {0.f,0.f,0.f,0.f};
            f32x4 acc10 = {0.f,0.f,0.f,0.f}, acc11 = {0.f,0.f,0.f,0.f};
#pragma unroll
            for (int ks = 0; ks < 4; ks++) {
                int kb = ks * 32 + lg * 8;
                short8v ah0 = *(const short8v*)(a1h + (lr     ) * TST + kb);
                short8v ah1 = *(const short8v*)(a1h + (16 + lr) * TST + kb);
                short8v al0 = *(const short8v*)(a1l + (lr     ) * TST + kb);
                short8v al1 = *(const short8v*)(a1l + (16 + lr) * TST + kb);
                short8v bh0 = *(const short8v*)(w2fh + c0 * FD + kb);
                short8v bh1 = *(const short8v*)(w2fh + c1 * FD + kb);
                short8v bl0 = *(const short8v*)(w2fl + c0 * FD + kb);
                short8v bl1 = *(const short8v*)(w2fl + c1 * FD + kb);
                acc00 = MFMA_B16(ah0, bh0, acc00, 0,0,0);
                acc01 = MFMA_B16(ah0, bh1, acc01, 0,0,0);
                acc10 = MFMA_B16(ah1, bh0, acc10, 0,0,0);
                acc11 = MFMA_B16(ah1, bh1, acc11, 0,0,0);
                acc00 = MFMA_B16(ah0, bl0, acc00, 0,0,0);
                acc01 = MFMA_B16(ah0, bl1, acc01, 0,0,0);
                acc10 = MFMA_B16(ah1, bl0, acc10, 0,0,0);
                acc11 = MFMA_B16(ah1, bl1, acc11, 0,0,0);
                acc00 = MFMA_B16(al0, bh0, acc00, 0,0,0);
                acc01 = MFMA_B16(al0, bh1, acc01, 0,0,0);
                acc10 = MFMA_B16(al1, bh0, acc10, 0,0,0);
                acc11 = MFMA_B16(al1, bh1, acc11, 0,0,0);
            }
#pragma unroll
            for (int r = 0; r < 4; r++) {
                macc0 += (acc00[r] + b2c0) * h00[r] + (acc10[r] + b2c0) * h10[r];
                macc1 += (acc01[r] + b2c1) * h01[r] + (acc11[r] + b2c1) * h11[r];
            }
        }
        __syncthreads();                   // rbf/a1 reuse next pass
    }

    // Reduce macc over the 4 k-groups (lanes lr, lr+16, lr+32, lr+48).
    macc0 += __shfl_xor(macc0, 16, 64);
    macc0 += __shfl_xor(macc0, 32, 64);
    macc1 += __shfl_xor(macc1, 16, 64);
    macc1 += __shfl_xor(macc1, 32, 64);
    if (lg == 0) {                         // direct store — block owns m[i]
        m[i * FD + c0] = macc0;
        m[i * FD + c1] = macc1;
    }
}

// ---------------------------------------------------------------- mbar (R20/R25)
__global__ __launch_bounds__(256) void mbar_kernel(
    const float* __restrict__ m, const float* __restrict__ W3,
    const float* __restrict__ W3T, const float* __restrict__ wout,
    float* __restrict__ mbar)
{
    __shared__ float mrow[FD];
    __shared__ float gb[FD];
    __shared__ float part[256];
    int i = blockIdx.x, t = threadIdx.x;
    if (t < FD) mrow[t] = m[i * FD + t];
    __syncthreads();
    int c = t & 127, hh = t >> 7;          // hh = 0/1 -> f half
    int f0 = hh * 64;
    float g = 0.f;
#pragma unroll 4
    for (int f4 = f0; f4 < f0 + 64; f4 += 4) {
        float4 w  = *(const float4*)(W3T + c * FD + f4);   // W3T[c][f]=W3[f][c]
        float4 mr = *(const float4*)(mrow + f4);
        g += mr.x*w.x + mr.y*w.y + mr.z*w.z + mr.w*w.w;
    }
    part[t] = g;
    __syncthreads();
    if (t < FD) gb[t] = (part[t] + part[t + 128] > 0.f) ? wout[t] : 0.f;
    __syncthreads();
    float mb = 0.f;
#pragma unroll 4
    for (int f4 = f0; f4 < f0 + 64; f4 += 4) {
        float4 w  = *(const float4*)(W3 + c * FD + f4);    // W3[c][f]=W3T[f][c]
        float4 gv = *(const float4*)(gb + f4);
        mb += gv.x*w.x + gv.y*w.y + gv.z*w.z + gv.w*w.w;
    }
    part[t] = mb;
    __syncthreads();
    if (t < FD) mbar[i * FD + t] = part[t] + part[t + 128];
}

// ---------------------------------------------------------------- bwd (768 blocks, per-atom)
// Load stored neighbor list + mbar[i] row -> per-pass: crbf stage + ts fill
// -> gef MFMA (gate mask) -> GEMM MFMA -> fold + shuffle reduce -> scatter.
__global__ __launch_bounds__(256) void bwd_kernel(
    const unsigned short* __restrict__ w1fh, const unsigned short* __restrict__ w1fl,
    const unsigned short* __restrict__ w2bh, const unsigned short* __restrict__ w2bl,
    const float* __restrict__ h, const float* __restrict__ mbar,
    const unsigned short* __restrict__ gatem,
    const int* __restrict__ nj_g, const float* __restrict__ nd_g,
    const float* __restrict__ ndx_g, const float* __restrict__ ndy_g,
    const float* __restrict__ ndz_g, const int* __restrict__ cnt_g,
    float* __restrict__ f_acc)
{
    __shared__ int   nj[MAXN];
    __shared__ float nd[MAXN], ndx[MAXN], ndy[MAXN], ndz[MAXN];
    __shared__ float mbrow[FD];
    __shared__ __align__(16) unsigned short crbf_h[PPF * RSTU];  // 2560 B
    __shared__ __align__(16) unsigned short crbf_l[PPF * RSTU];  // 2560 B
    __shared__ __align__(16) unsigned short ts_h[PPF * TST];     // 8704 B
    __shared__ __align__(16) unsigned short ts_l[PPF * TST];     // 8704 B
    __shared__ float sred[4 * PPF];                              // 512 B
    int i = blockIdx.x, t = threadIdx.x;
    int cnt = cnt_g[i];
    if (cnt == 0) return;

    if (t < cnt) {
        nj [t] = nj_g [i*MAXN + t];
        nd [t] = nd_g [i*MAXN + t];
        ndx[t] = ndx_g[i*MAXN + t];
        ndy[t] = ndy_g[i*MAXN + t];
        ndz[t] = ndz_g[i*MAXN + t];
    }
    if (t < FD) mbrow[t] = mbar[i * FD + t];
    __syncthreads();

    int wid = t >> 6, lane = t & 63;
    int lr = lane & 15, lg = lane >> 4;
    int c0 = (2 * wid + 0) * 16 + lr;
    int c1 = (2 * wid + 1) * 16 + lr;

    int npass = (cnt + PPF - 1) / PPF;           // 1..2
    for (int pass = 0; pass < npass; pass++) {
        int p0 = pass * PPF;
        // crbf staging
#pragma unroll
        for (int e = 0; e < 4; e++) {
            int idx = t + e * 256;
            int p = idx >> 5, k = idx & 31;
            int pp = p0 + p;
            float d = (pp < cnt) ? nd[pp] : 1.0f;
            float u = d - CSTEP * (float)k;
            float r = __expf(-GAMMA_ * u * u);
            float cd = -2.f * GAMMA_ * u * r;
            unsigned short hc = f2bf(cd);
            crbf_h[p * RSTU + k] = hc;
            crbf_l[p * RSTU + k] = f2bf(cd - bf2f(hc));
        }
        // ts fill: ts[p][c] = mbrow[c] * h[j_p][c]
#pragma unroll
        for (int e = 0; e < 4; e++) {
            int idx = t + e * 256;
            int p = idx >> 5, c4g = (idx & 31) * 4;
            int pp = p0 + p;
            ushort4 hv = {0,0,0,0}, lv = {0,0,0,0};
            if (pp < cnt) {
                float4 mb4 = *(const float4*)(mbrow + c4g);
                float4 hj4 = *(const float4*)(h + nj[pp] * FD + c4g);
                float v0 = mb4.x*hj4.x, v1 = mb4.y*hj4.y;
                float v2 = mb4.z*hj4.z, v3 = mb4.w*hj4.w;
                hv.x = f2bf(v0); lv.x = f2bf(v0 - bf2f(hv.x));
                hv.y = f2bf(v1); lv.y = f2bf(v1 - bf2f(hv.y));
                hv.z = f2bf(v2); lv.z = f2bf(v2 - bf2f(hv.z));
                hv.w = f2bf(v3); lv.w = f2bf(v3 - bf2f(hv.w));
            }
            *(ushort4*)(ts_h + p * TST + c4g) = hv;
            *(ushort4*)(ts_l + p * TST + c4g) = lv;
        }
        __syncthreads();                   // crbf + ts ready

        unsigned int mk = gatem[(i * 2 + pass) * 256 + t];

        // gef (12 MFMA, in registers): ef = crbf@W1 split; gate via mask.
        f32x4 e00 = {0.f,0.f,0.f,0.f}, e01 = {0.f,0.f,0.f,0.f};
        f32x4 e10 = {0.f,0.f,0.f,0.f}, e11 = {0.f,0.f,0.f,0.f};
        {
            short8v ch0 = *(const short8v*)(crbf_h + lr * RSTU + lg * 8);
            short8v ch1 = *(const short8v*)(crbf_h + (16+lr) * RSTU + lg * 8);
            short8v cl0 = *(const short8v*)(crbf_l + lr * RSTU + lg * 8);
            short8v cl1 = *(const short8v*)(crbf_l + (16+lr) * RSTU + lg * 8);
            short8v bh0 = *(const short8v*)(w1fh + c0 * NRBF + lg * 8);
            short8v bh1 = *(const short8v*)(w1fh + c1 * NRBF + lg * 8);
            short8v bl0 = *(const short8v*)(w1fl + c0 * NRBF + lg * 8);
            short8v bl1 = *(const short8v*)(w1fl + c1 * NRBF + lg * 8);
            e00 = MFMA_B16(ch0, bh0, e00, 0,0,0); e01 = MFMA_B16(ch0, bh1, e01, 0,0,0);
            e10 = MFMA_B16(ch1, bh0, e10, 0,0,0); e11 = MFMA_B16(ch1, bh1, e11, 0,0,0);
            e00 = MFMA_B16(ch0, bl0, e00, 0,0,0); e01 = MFMA_B16(ch0, bl1, e01, 0,0,0);
            e10 = MFMA_B16(ch1, bl0, e10, 0,0,0); e11 = MFMA_B16(ch1, bl1, e11, 0,0,0);
            e00 = MFMA_B16(cl0, bh0, e00, 0,0,0); e01 = MFMA_B16(cl0, bh1, e01, 0,0,0);
            e10 = MFMA_B16(cl1, bh0, e10, 0,0,0); e11 = MFMA_B16(cl1, bh1, e11, 0,0,0);
        }
#pragma unroll
        for (int r = 0; r < 4; r++) {
            e00[r] = (mk & (1u <<  r      )) ? e00[r] : 0.f;
            e01[r] = (mk & (1u << (4 + r))) ? e01[r] : 0.f;
            e10[r] = (mk & (1u << (8 + r))) ? e10[r] : 0.f;
            e11[r] = (mk & (1u << (12 + r))) ? e11[r] : 0.f;
        }

        // GEMM: du1 = ts @ W2T (B from native-layout w2b).
        f32x4 acc00 = {0.f,0.f,0.f,0.f}, acc01 = {0.f,0.f,0.f,0.f};
        f32x4 acc10 = {0.f,0.f,0.f,0.f}, acc11 = {0.f,0.f,0.f,0.f};
#pragma unroll
        for (int ks = 0; ks < 4; ks++) {
            int kb = ks * 32 + lg * 8;
            short8v ah0 = *(const short8v*)(ts_h + (lr     ) * TST + kb);
            short8v ah1 = *(const short8v*)(ts_h + (16 + lr) * TST + kb);
            short8v al0 = *(const short8v*)(ts_l + (lr     ) * TST + kb);
            short8v al1 = *(const short8v*)(ts_l + (16 + lr) * TST + kb);
            short8v bh0 = *(const short8v*)(w2bh + c0 * FD + kb);
            short8v bh1 = *(const short8v*)(w2bh + c1 * FD + kb);
            short8v bl0 = *(const short8v*)(w2bl + c0 * FD + kb);
            short8v bl1 = *(const short8v*)(w2bl + c1 * FD + kb);
            acc00 = MFMA_B16(ah0, bh0, acc00, 0,0,0);
            acc01 = MFMA_B16(ah0, bh1, acc01, 0,0,0);
            acc10 = MFMA_B16(ah1, bh0, acc10, 0,0,0);
            acc11 = MFMA_B16(ah1, bh1, acc11, 0,0,0);
            acc00 = MFMA_B16(ah0, bl0, acc00, 0,0,0);
            acc01 = MFMA_B16(ah0, bl1, acc01, 0,0,0);
            acc10 = MFMA_B16(ah1, bl0, acc10, 0,0,0);
            acc11 = MFMA_B16(ah1, bl1, acc11, 0,0,0);
            acc00 = MFMA_B16(al0, bh0, acc00, 0,0,0);
            acc01 = MFMA_B16(al0, bh1, acc01, 0,0,0);
            acc10 = MFMA_B16(al1, bh0, acc10, 0,0,0);
            acc11 = MFMA_B16(al1, bh1, acc11, 0,0,0);
        }

        // Fold gef, 16-lane shuffle reduce over cols.
        float part[8];
#pragma unroll
        for (int r = 0; r < 4; r++) {
            part[r]     = acc00[r] * e00[r] + acc01[r] * e01[r];
            part[4 + r] = acc10[r] * e10[r] + acc11[r] * e11[r];
        }
#pragma unroll
        for (int mask = 1; mask < 16; mask <<= 1) {
#pragma unroll
            for (int e = 0; e < 8; e++) part[e] += __shfl_xor(part[e], mask, 64);
        }
        if (lr == 0) {
#pragma unroll
            for (int r = 0; r < 4; r++) {
                sred[wid * PPF + lg * 4 + r]      = part[r];
                sred[wid * PPF + 16 + lg * 4 + r] = part[4 + r];
            }
        }
        __syncthreads();

        // Scatter this pass's pairs (threads 0..31)
        if (t < PPF && p0 + t < cnt) {
            float s = sred[t] + sred[PPF + t] + sred[2*PPF + t] + sred[3*PPF + t];
            int pp = p0 + t;
            float coef = s / nd[pp];
            float fx = coef * ndx[pp];
            float fy = coef * ndy[pp];
            float fz = coef * ndz[pp];
            atomicAdd(f_acc + i*3 + 0, -fx);
            atomicAdd(f_acc + i*3 + 1, -fy);
            atomicAdd(f_acc + i*3 + 2, -fz);
            atomicAdd(f_acc + nj[pp]*3 + 0, fx);
            atomicAdd(f_acc + nj[pp]*3 + 1, fy);
            atomicAdd(f_acc + nj[pp]*3 + 2, fz);
        }
        __syncthreads();                   // sred/crbf/ts reuse next pass
    }
}

// ---------------------------------------------------------------- finalize
__global__ __launch_bounds__(256) void fin_kernel(
    const float* __restrict__ v, const float* __restrict__ mass,
    const float* __restrict__ p_eta, const float* __restrict__ f_acc,
    float* __restrict__ out)
{
    __shared__ float red[256];
    int t = threadIdx.x;
    float ke = 0.f;
    float c = p_eta[0] / Q0_F;
    for (int idx = t; idx < 3 * N_ATOMS; idx += 256) {
        int a = idx / 3;
        float vv = v[idx], mi = mass[a];
        out[DVDT_OFF + idx] = (f_acc[idx] - c * vv * mi) / mi;
        out[V_OFF + idx] = vv;
        ke += 0.5f * mi * vv * vv;
    }
    red[t] = ke;
    __syncthreads();
    for (int s = 128; s > 0; s >>= 1) {
        if (t < s) red[t] += red[t + s];
        __syncthreads();
    }
    if (t == 0) {
        float k0 = red[0];
        float e0 = p_eta[0], e1 = p_eta[1], e2 = p_eta[2], e3 = p_eta[3];
        out[PETA_OFF + 0] = 2.f * (k0 - TARGET_KE) - e0 * e1 / QI_F;
        out[PETA_OFF + 1] = e0 * e0 / Q0_F - KT_F - e1 * e2 / QI_F;
        out[PETA_OFF + 2] = e1 * e1 / QI_F - KT_F - e2 * e3 / QI_F;
        out[PETA_OFF + 3] = e2 * e2 / QI_F - KT_F;
    }
}

// ---------------------------------------------------------------- launch
extern "C" void kernel_launch(void* const* d_in, const int* in_sizes, int n_in,
                              void* d_out, int out_size, void* d_ws, size_t ws_size,
                              hipStream_t stream)
{
    const float* v     = (const float*)d_in[0];
    const float* q     = (const float*)d_in[1];
    const float* p_eta = (const float*)d_in[2];
    const float* mass  = (const float*)d_in[3];
    const float* embed = (const float*)d_in[4];
    const float* W1    = (const float*)d_in[5];
    const float* b1    = (const float*)d_in[6];
    const float* W2    = (const float*)d_in[7];
    const float* b2    = (const float*)d_in[8];
    const float* W3    = (const float*)d_in[9];
    const float* wout  = (const float*)d_in[10];
    const int*   z     = (const int*)d_in[11];
    float* out = (float*)d_out;

    float* h     = (float*)d_ws;                    // 98304
    float* W3T   = h + N_ATOMS * FD;                // 16384
    float* m     = W3T + FD * FD;                   // 98304
    float* f_acc = m + N_ATOMS * FD;                // 2304
    float* mbar  = f_acc + 3 * N_ATOMS;             // 98304
    float* nd_g  = mbar + N_ATOMS * FD;             // 49152
    float* ndx_g = nd_g  + N_ATOMS * MAXN;
    float* ndy_g = ndx_g + N_ATOMS * MAXN;
    float* ndz_g = ndy_g + N_ATOMS * MAXN;
    int*   nj_g  = (int*)(ndz_g + N_ATOMS * MAXN);  // 49152
    int*   cnt_g = nj_g + N_ATOMS * MAXN;           // 768
    unsigned short* w2bh = (unsigned short*)(cnt_g + N_ATOMS);
    unsigned short* w2bl = w2bh + FD * FD;
    unsigned short* w2fh = w2bl + FD * FD;
    unsigned short* w2fl = w2fh + FD * FD;
    unsigned short* w1fh = w2fl + FD * FD;
    unsigned short* w1fl = w1fh + NRBF * FD;
    unsigned short* gatem = w1fl + NRBF * FD;       // 768*2*256

    prep_kernel<<<384, 256, 0, stream>>>(z, embed, W1, W2, W3, h, W3T,
                                         w1fh, w1fl, w2fh, w2fl, w2bh, w2bl,
                                         f_acc);
    fwd_kernel<<<N_ATOMS, 256, 0, stream>>>(q, w1fh, w1fl, b1, w2fh, w2fl,
                                            b2, h, m, gatem,
                                            nj_g, nd_g, ndx_g, ndy_g, ndz_g,
                                            cnt_g);
    mbar_kernel<<<N_ATOMS, 256, 0, stream>>>(m, W3, W3T, wout, mbar);
    bwd_kernel<<<N_ATOMS, 256, 0, stream>>>(w1fh, w1fl, w2bh, w2bl, h, mbar,
                                            gatem, nj_g, nd_g, ndx_g, ndy_g,
                                            ndz_g, cnt_g, f_acc);
    fin_kernel<<<1, 256, 0, stream>>>(v, mass, p_eta, f_acc, out);
}

// Round 11
// 131.118 us; speedup vs baseline: 1.1228x; 1.0748x over previous
//
#include <hip/hip_runtime.h>
#include <math.h>

// Problem constants (match reference)
#define N_ATOMS 768
#define FD 128          // feature width
#define NRBF 32
#define MAXN 64         // per-atom neighbor cap (mean ~26)
#define PPF 32          // pairs per MFMA pass (2 M-tiles of 16)
#define TST 136         // padded LDS stride for [*][128] bf16 (ushort) tiles
#define RSTU 40         // padded ushort stride for [*][32] bf16 rbf tiles (80B, 16B-aligned)

constexpr float  CUT2   = 25.0f;
constexpr float  GAMMA_ = 40.96f;            // 1/(5/32)^2
constexpr float  CSTEP  = 5.0f / 31.0f;      // linspace(0,5,32) step
constexpr double KB_D   = 8.617330337217213e-05;
constexpr double KT_D   = 300.0 * KB_D;
constexpr float  KT_F   = (float)KT_D;
constexpr float  TARGET_KE = (float)(0.5 * 2304.0 * KT_D);
constexpr float  Q0_F   = (float)(2.0 * 2304.0 * KT_D * 400.0);  // Q[0]
constexpr float  QI_F   = (float)(2.0 * KT_D * 400.0);           // Q[1..3]

#define DVDT_OFF 0
#define V_OFF    (3 * N_ATOMS)
#define PETA_OFF (6 * N_ATOMS)

using short8v = __attribute__((ext_vector_type(8))) short;
using f32x4   = __attribute__((ext_vector_type(4))) float;

#define MFMA_B16 __builtin_amdgcn_mfma_f32_16x16x32_bf16

__device__ __forceinline__ unsigned short f2bf(float x) {
    unsigned int u = __float_as_uint(x);
    u += 0x7FFF + ((u >> 16) & 1);           // round-to-nearest-even
    return (unsigned short)(u >> 16);
}
__device__ __forceinline__ float bf2f(unsigned short h) {
    return __uint_as_float(((unsigned int)h) << 16);
}

// Hard-won rules (27 rounds of counters):
// 1. NO __launch_bounds__ min-wave hints on GEMM kernels (spill cliff).
// 2. NEVER put __threadfence / completion counters on the hot grid (R14).
// 3. R18/R19 FAILED: wave-spread mbar, LDS weight staging.
// 4. R22-R24 WIN: MFMA split-bf16 (AhBh+AhBl+AlBh, err ~2^-17) for all dense
//    phases. Layouts: bwd w2b native; fwd w2f[c][k]=W2[k][c];
//    w1f[c][k]=W1[k][c]. C/D: col=lane&15, row=(lane>>4)*4+reg (verified).
// 5. R25/R27 WINs (small each): gate-mask reuse, in-reg gef, per-atom blocks,
//    direct m store. R26 REGRESSED (per-run atomics in fused epilogue).
// 6. R28: fwd+mbar+bwd FUSED into one per-atom kernel. Insight: m[i] is
//    complete at end of fwd block i; mbar[i] needs only m[i]; bwd block i
//    needs only mbar[i], h[j], own gate masks -> no cross-block dep.
//    m/mbar/gatem/neighbor-persist global buffers all eliminated; masks in
//    registers; neighbor list lives in LDS end-to-end. 5 -> 3 dispatches.
//    i-side scatter: register-accumulated, 3 atomics/block (R26 lesson:
//    don't multiply atomics; this DIVIDES them).

// ---------------------------------------------------------------- prep (fill only)
__global__ __launch_bounds__(256) void prep_kernel(
    const int* __restrict__ z, const float* __restrict__ embed,
    const float* __restrict__ W1, const float* __restrict__ W2,
    const float* __restrict__ W3,
    float* __restrict__ h, float* __restrict__ W3T,
    unsigned short* __restrict__ w1fh, unsigned short* __restrict__ w1fl,
    unsigned short* __restrict__ w2fh, unsigned short* __restrict__ w2fl,
    unsigned short* __restrict__ w2bh, unsigned short* __restrict__ w2bl,
    float* __restrict__ f_acc)
{
    int g = blockIdx.x * 256 + threadIdx.x;      // 98304 ids (384 blocks)
    if (g < N_ATOMS * FD) h[g] = embed[z[g >> 7] * FD + (g & 127)];
    if (g < FD * FD) {
        int r = g >> 7, c = g & 127;
        float w = W2[g];                         // W2[r][c]
        unsigned short hb = f2bf(w);
        unsigned short lb = f2bf(w - bf2f(hb));
        w2bh[g] = hb;                            // bwd B: native layout
        w2bl[g] = lb;
        w2fh[c * FD + r] = hb;                   // fwd B: w2f[c][k]=W2[k][c]
        w2fl[c * FD + r] = lb;
        W3T[c * FD + r] = W3[g];
        if (g < NRBF * FD) {                     // W1: NRBF x FD (r=k)
            float w1v = W1[g];
            unsigned short h1 = f2bf(w1v);
            w1fh[c * NRBF + r] = h1;             // [c][k], k contiguous
            w1fl[c * NRBF + r] = f2bf(w1v - bf2f(h1));
        }
    }
    if (g < 3 * N_ATOMS) f_acc[g] = 0.f;
}

// ---------------------------------------------------------------- atom (768 blocks)
// Per-atom megakernel: neighbor build -> fwd passes (A+B MFMA, m in regs,
// gate masks in regs) -> mbar (LDS only) -> bwd passes (gef+GEMM MFMA,
// scatter). No global m/mbar/gatem/neighbor traffic.
__global__ __launch_bounds__(256) void atom_kernel(
    const float* __restrict__ q,
    const unsigned short* __restrict__ w1fh, const unsigned short* __restrict__ w1fl,
    const float* __restrict__ b1,
    const unsigned short* __restrict__ w2fh, const unsigned short* __restrict__ w2fl,
    const unsigned short* __restrict__ w2bh, const unsigned short* __restrict__ w2bl,
    const float* __restrict__ b2, const float* __restrict__ h,
    const float* __restrict__ W3, const float* __restrict__ W3T,
    const float* __restrict__ wout,
    float* __restrict__ f_acc)
{
    __shared__ int   nj[MAXN];
    __shared__ float nd[MAXN], ndx[MAXN], ndy[MAXN], ndz[MAXN];
    __shared__ int   cnt_s;
    __shared__ __align__(16) unsigned short rbf_h[PPF * RSTU];   // 2560 B
    __shared__ __align__(16) unsigned short rbf_l[PPF * RSTU];   // 2560 B
    __shared__ __align__(16) unsigned short a1h[PPF * TST];      // 8704 B
    __shared__ __align__(16) unsigned short a1l[PPF * TST];      // 8704 B
    __shared__ __align__(16) unsigned short crbf_h[PPF * RSTU];  // 2560 B
    __shared__ __align__(16) unsigned short crbf_l[PPF * RSTU];  // 2560 B
    __shared__ __align__(16) unsigned short ts_h[PPF * TST];     // 8704 B
    __shared__ __align__(16) unsigned short ts_l[PPF * TST];     // 8704 B
    __shared__ float mrow[FD], gb[FD], mbrow[FD];                // 1536 B
    __shared__ float part[256];                                  // 1024 B
    __shared__ float sred[4 * PPF];                              //  512 B
    // total ~49.4 KB -> 3 blocks/CU (= 768/256 needed)

    int i = blockIdx.x, t = threadIdx.x;
    if (t == 0) cnt_s = 0;
    __syncthreads();
    float qx = q[i*3], qy = q[i*3+1], qz = q[i*3+2];
    for (int j = t; j < N_ATOMS; j += 256) {
        if (j == i) continue;
        float dx = qx - q[j*3], dy = qy - q[j*3+1], dz = qz - q[j*3+2];
        float d2 = dx*dx + dy*dy + dz*dz;
        if (d2 < CUT2) {
            int p = atomicAdd(&cnt_s, 1);
            if (p < MAXN) { nj[p] = j; nd[p] = sqrtf(d2);
                            ndx[p] = dx; ndy[p] = dy; ndz[p] = dz; }
        }
    }
    __syncthreads();
    int cnt = min(cnt_s, MAXN);
    if (cnt == 0) return;                        // no pairs, no forces

    int wid = t >> 6, lane = t & 63;
    int lr = lane & 15, lg = lane >> 4;
    int c0 = (2 * wid + 0) * 16 + lr;
    int c1 = (2 * wid + 1) * 16 + lr;
    float bb0 = b1[c0], bb1 = b1[c1];
    float b2c0 = b2[c0], b2c1 = b2[c1];
    float macc0 = 0.f, macc1 = 0.f;              // m[i][c0], m[i][c1] partials
    unsigned int mk0 = 0, mk1 = 0;               // per-pass relu gate masks

    // ---------------- fwd pass (A + B MFMA, accumulate m in regs) ----------
    auto fwd_pass = [&](int p0, unsigned int& mk_out) {
        // rbf staging (pass-local rows 0..31)
#pragma unroll
        for (int e = 0; e < 4; e++) {
            int idx = t + e * 256;
            int p = idx >> 5, k = idx & 31;
            int pp = p0 + p;
            float d = (pp < cnt) ? nd[pp] : 1.0f;
            float u = d - CSTEP * (float)k;
            float r = __expf(-GAMMA_ * u * u);
            unsigned short hb = f2bf(r);
            rbf_h[p * RSTU + k] = hb;
            rbf_l[p * RSTU + k] = f2bf(r - bf2f(hb));
        }
        __syncthreads();

        // h prefetch for this thread's 8 pairs (0 for invalid)
        float h00[4], h01[4], h10[4], h11[4];
#pragma unroll
        for (int r = 0; r < 4; r++) {
            int pA = p0 + lg * 4 + r, pB = pA + 16;
            bool vA = pA < cnt, vB = pB < cnt;
            int jA = vA ? nj[pA] : 0, jB = vB ? nj[pB] : 0;
            h00[r] = vA ? h[jA * FD + c0] : 0.f;
            h01[r] = vA ? h[jA * FD + c1] : 0.f;
            h10[r] = vB ? h[jB * FD + c0] : 0.f;
            h11[r] = vB ? h[jB * FD + c1] : 0.f;
        }

        // Phase A (MFMA, 12): u = b1 + rbf@W1 split; relu+split; gate mask.
        {
            f32x4 u00 = {bb0,bb0,bb0,bb0}, u01 = {bb1,bb1,bb1,bb1};
            f32x4 u10 = {bb0,bb0,bb0,bb0}, u11 = {bb1,bb1,bb1,bb1};
            short8v rh0 = *(const short8v*)(rbf_h + lr * RSTU + lg * 8);
            short8v rh1 = *(const short8v*)(rbf_h + (16+lr) * RSTU + lg * 8);
            short8v rl0 = *(const short8v*)(rbf_l + lr * RSTU + lg * 8);
            short8v rl1 = *(const short8v*)(rbf_l + (16+lr) * RSTU + lg * 8);
            short8v bh0 = *(const short8v*)(w1fh + c0 * NRBF + lg * 8);
            short8v bh1 = *(const short8v*)(w1fh + c1 * NRBF + lg * 8);
            short8v bl0 = *(const short8v*)(w1fl + c0 * NRBF + lg * 8);
            short8v bl1 = *(const short8v*)(w1fl + c1 * NRBF + lg * 8);
            u00 = MFMA_B16(rh0, bh0, u00, 0,0,0); u01 = MFMA_B16(rh0, bh1, u01, 0,0,0);
            u10 = MFMA_B16(rh1, bh0, u10, 0,0,0); u11 = MFMA_B16(rh1, bh1, u11, 0,0,0);
            u00 = MFMA_B16(rh0, bl0, u00, 0,0,0); u01 = MFMA_B16(rh0, bl1, u01, 0,0,0);
            u10 = MFMA_B16(rh1, bl0, u10, 0,0,0); u11 = MFMA_B16(rh1, bl1, u11, 0,0,0);
            u00 = MFMA_B16(rl0, bh0, u00, 0,0,0); u01 = MFMA_B16(rl0, bh1, u01, 0,0,0);
            u10 = MFMA_B16(rl1, bh0, u10, 0,0,0); u11 = MFMA_B16(rl1, bh1, u11, 0,0,0);
            // C/D: col=lane&15, row=(lane>>4)*4+reg  [verified]
            unsigned int mk = 0;
#pragma unroll
            for (int r = 0; r < 4; r++) {
                int pA = lg * 4 + r, pB = 16 + lg * 4 + r;
                float v; unsigned short hb;
                if (u00[r] > 0.f) mk |= 1u << r;
                if (u01[r] > 0.f) mk |= 1u << (4 + r);
                if (u10[r] > 0.f) mk |= 1u << (8 + r);
                if (u11[r] > 0.f) mk |= 1u << (12 + r);
                v = fmaxf(u00[r], 0.f); hb = f2bf(v);
                a1h[pA * TST + c0] = hb; a1l[pA * TST + c0] = f2bf(v - bf2f(hb));
                v = fmaxf(u01[r], 0.f); hb = f2bf(v);
                a1h[pA * TST + c1] = hb; a1l[pA * TST + c1] = f2bf(v - bf2f(hb));
                v = fmaxf(u10[r], 0.f); hb = f2bf(v);
                a1h[pB * TST + c0] = hb; a1l[pB * TST + c0] = f2bf(v - bf2f(hb));
                v = fmaxf(u11[r], 0.f); hb = f2bf(v);
                a1h[pB * TST + c1] = hb; a1l[pB * TST + c1] = f2bf(v - bf2f(hb));
            }
            mk_out = mk;
        }
        __syncthreads();

        // Phase B (MFMA): filt = a1 @ W2 split; accumulate (filt+b2)*h_j.
        {
            f32x4 acc00 = {0.f,0.f,0.f,0.f}, acc01 = {0.f,0.f,0.f,0.f};
            f32x4 acc10 = {0.f,0.f,0.f,0.f}, acc11 = {0.f,0.f,0.f,0.f};
#pragma unroll
            for (int ks = 0; ks < 4; ks++) {
                int kb = ks * 32 + lg * 8;
                short8v ah0 = *(const short8v*)(a1h + (lr     ) * TST + kb);
                short8v ah1 = *(const short8v*)(a1h + (16 + lr) * TST + kb);
                short8v al0 = *(const short8v*)(a1l + (lr     ) * TST + kb);
                short8v al1 = *(const short8v*)(a1l + (16 + lr) * TST + kb);
                short8v bh0 = *(const short8v*)(w2fh + c0 * FD + kb);
                short8v bh1 = *(const short8v*)(w2fh + c1 * FD + kb);
                short8v bl0 = *(const short8v*)(w2fl + c0 * FD + kb);
                short8v bl1 = *(const short8v*)(w2fl + c1 * FD + kb);
                acc00 = MFMA_B16(ah0, bh0, acc00, 0,0,0);
                acc01 = MFMA_B16(ah0, bh1, acc01, 0,0,0);
                acc10 = MFMA_B16(ah1, bh0, acc10, 0,0,0);
                acc11 = MFMA_B16(ah1, bh1, acc11, 0,0,0);
                acc00 = MFMA_B16(ah0, bl0, acc00, 0,0,0);
                acc01 = MFMA_B16(ah0, bl1, acc01, 0,0,0);
                acc10 = MFMA_B16(ah1, bl0, acc10, 0,0,0);
                acc11 = MFMA_B16(ah1, bl1, acc11, 0,0,0);
                acc00 = MFMA_B16(al0, bh0, acc00, 0,0,0);
                acc01 = MFMA_B16(al0, bh1, acc01, 0,0,0);
                acc10 = MFMA_B16(al1, bh0, acc10, 0,0,0);
                acc11 = MFMA_B16(al1, bh1, acc11, 0,0,0);
            }
#pragma unroll
            for (int r = 0; r < 4; r++) {
                macc0 += (acc00[r] + b2c0) * h00[r] + (acc10[r] + b2c0) * h10[r];
                macc1 += (acc01[r] + b2c1) * h01[r] + (acc11[r] + b2c1) * h11[r];
            }
        }
        __syncthreads();                   // rbf/a1 reuse next pass
    };

    fwd_pass(0, mk0);
    if (cnt > PPF) fwd_pass(PPF, mk1);

    // ---------------- m reduce -> LDS mrow (no global m) --------------------
    {
        float r0 = macc0 + __shfl_xor(macc0, 16, 64);
        r0 += __shfl_xor(r0, 32, 64);
        float r1 = macc1 + __shfl_xor(macc1, 16, 64);
        r1 += __shfl_xor(r1, 32, 64);
        if (lg == 0) { mrow[c0] = r0; mrow[c1] = r1; }
    }
    __syncthreads();

    // ---------------- mbar section (identical math to mbar_kernel) ---------
    {
        int c = t & 127, hh = t >> 7;
        int f0h = hh * 64;
        float g = 0.f;
#pragma unroll 4
        for (int f4 = f0h; f4 < f0h + 64; f4 += 4) {
            float4 w  = *(const float4*)(W3T + c * FD + f4);   // W3T[c][f]=W3[f][c]
            float4 mr = *(const float4*)(mrow + f4);
            g += mr.x*w.x + mr.y*w.y + mr.z*w.z + mr.w*w.w;
        }
        part[t] = g;
        __syncthreads();
        if (t < FD) gb[t] = (part[t] + part[t + 128] > 0.f) ? wout[t] : 0.f;
        __syncthreads();
        float mb = 0.f;
#pragma unroll 4
        for (int f4 = f0h; f4 < f0h + 64; f4 += 4) {
            float4 w  = *(const float4*)(W3 + c * FD + f4);    // W3[c][f]=W3T[f][c]
            float4 gv = *(const float4*)(gb + f4);
            mb += gv.x*w.x + gv.y*w.y + gv.z*w.z + gv.w*w.w;
        }
        part[t] = mb;
        __syncthreads();
        if (t < FD) mbrow[t] = part[t] + part[t + 128];
    }
    __syncthreads();

    // ---------------- bwd passes -------------------------------------------
    float iax = 0.f, iay = 0.f, iaz = 0.f;       // i-side force accumulator

    auto bwd_pass = [&](int p0, unsigned int mk) {
        // crbf staging
#pragma unroll
        for (int e = 0; e < 4; e++) {
            int idx = t + e * 256;
            int p = idx >> 5, k = idx & 31;
            int pp = p0 + p;
            float d = (pp < cnt) ? nd[pp] : 1.0f;
            float u = d - CSTEP * (float)k;
            float r = __expf(-GAMMA_ * u * u);
            float cd = -2.f * GAMMA_ * u * r;
            unsigned short hc = f2bf(cd);
            crbf_h[p * RSTU + k] = hc;
            crbf_l[p * RSTU + k] = f2bf(cd - bf2f(hc));
        }
        // ts fill: ts[p][c] = mbrow[c] * h[j_p][c]
#pragma unroll
        for (int e = 0; e < 4; e++) {
            int idx = t + e * 256;
            int p = idx >> 5, c4g = (idx & 31) * 4;
            int pp = p0 + p;
            ushort4 hv = {0,0,0,0}, lv = {0,0,0,0};
            if (pp < cnt) {
                float4 mb4 = *(const float4*)(mbrow + c4g);
                float4 hj4 = *(const float4*)(h + nj[pp] * FD + c4g);
                float v0 = mb4.x*hj4.x, v1 = mb4.y*hj4.y;
                float v2 = mb4.z*hj4.z, v3 = mb4.w*hj4.w;
                hv.x = f2bf(v0); lv.x = f2bf(v0 - bf2f(hv.x));
                hv.y = f2bf(v1); lv.y = f2bf(v1 - bf2f(hv.y));
                hv.z = f2bf(v2); lv.z = f2bf(v2 - bf2f(hv.z));
                hv.w = f2bf(v3); lv.w = f2bf(v3 - bf2f(hv.w));
            }
            *(ushort4*)(ts_h + p * TST + c4g) = hv;
            *(ushort4*)(ts_l + p * TST + c4g) = lv;
        }
        __syncthreads();                   // crbf + ts ready

        // gef (12 MFMA, in registers): ef = crbf@W1 split; gate via mask.
        f32x4 e00 = {0.f,0.f,0.f,0.f}, e01 = {0.f,0.f,0.f,0.f};
        f32x4 e10 = {0.f,0.f,0.f,0.f}, e11 = {0.f,0.f,0.f,0.f};
        {
            short8v ch0 = *(const short8v*)(crbf_h + lr * RSTU + lg * 8);
            short8v ch1 = *(const short8v*)(crbf_h + (16+lr) * RSTU + lg * 8);
            short8v cl0 = *(const short8v*)(crbf_l + lr * RSTU + lg * 8);
            short8v cl1 = *(const short8v*)(crbf_l + (16+lr) * RSTU + lg * 8);
            short8v bh0 = *(const short8v*)(w1fh + c0 * NRBF + lg * 8);
            short8v bh1 = *(const short8v*)(w1fh + c1 * NRBF + lg * 8);
            short8v bl0 = *(const short8v*)(w1fl + c0 * NRBF + lg * 8);
            short8v bl1 = *(const short8v*)(w1fl + c1 * NRBF + lg * 8);
            e00 = MFMA_B16(ch0, bh0, e00, 0,0,0); e01 = MFMA_B16(ch0, bh1, e01, 0,0,0);
            e10 = MFMA_B16(ch1, bh0, e10, 0,0,0); e11 = MFMA_B16(ch1, bh1, e11, 0,0,0);
            e00 = MFMA_B16(ch0, bl0, e00, 0,0,0); e01 = MFMA_B16(ch0, bl1, e01, 0,0,0);
            e10 = MFMA_B16(ch1, bl0, e10, 0,0,0); e11 = MFMA_B16(ch1, bl1, e11, 0,0,0);
            e00 = MFMA_B16(cl0, bh0, e00, 0,0,0); e01 = MFMA_B16(cl0, bh1, e01, 0,0,0);
            e10 = MFMA_B16(cl1, bh0, e10, 0,0,0); e11 = MFMA_B16(cl1, bh1, e11, 0,0,0);
        }
#pragma unroll
        for (int r = 0; r < 4; r++) {
            e00[r] = (mk & (1u <<  r      )) ? e00[r] : 0.f;
            e01[r] = (mk & (1u << (4 + r))) ? e01[r] : 0.f;
            e10[r] = (mk & (1u << (8 + r))) ? e10[r] : 0.f;
            e11[r] = (mk & (1u << (12 + r))) ? e11[r] : 0.f;
        }

        // GEMM: du1 = ts @ W2T (B from native-layout w2b).
        f32x4 acc00 = {0.f,0.f,0.f,0.f}, acc01 = {0.f,0.f,0.f,0.f};
        f32x4 acc10 = {0.f,0.f,0.f,0.f}, acc11 = {0.f,0.f,0.f,0.f};
#pragma unroll
        for (int ks = 0; ks < 4; ks++) {
            int kb = ks * 32 + lg * 8;
            short8v ah0 = *(const short8v*)(ts_h + (lr     ) * TST + kb);
            short8v ah1 = *(const short8v*)(ts_h + (16 + lr) * TST + kb);
            short8v al0 = *(const short8v*)(ts_l + (lr     ) * TST + kb);
            short8v al1 = *(const short8v*)(ts_l + (16 + lr) * TST + kb);
            short8v bh0 = *(const short8v*)(w2bh + c0 * FD + kb);
            short8v bh1 = *(const short8v*)(w2bh + c1 * FD + kb);
            short8v bl0 = *(const short8v*)(w2bl + c0 * FD + kb);
            short8v bl1 = *(const short8v*)(w2bl + c1 * FD + kb);
            acc00 = MFMA_B16(ah0, bh0, acc00, 0,0,0);
            acc01 = MFMA_B16(ah0, bh1, acc01, 0,0,0);
            acc10 = MFMA_B16(ah1, bh0, acc10, 0,0,0);
            acc11 = MFMA_B16(ah1, bh1, acc11, 0,0,0);
            acc00 = MFMA_B16(ah0, bl0, acc00, 0,0,0);
            acc01 = MFMA_B16(ah0, bl1, acc01, 0,0,0);
            acc10 = MFMA_B16(ah1, bl0, acc10, 0,0,0);
            acc11 = MFMA_B16(ah1, bl1, acc11, 0,0,0);
            acc00 = MFMA_B16(al0, bh0, acc00, 0,0,0);
            acc01 = MFMA_B16(al0, bh1, acc01, 0,0,0);
            acc10 = MFMA_B16(al1, bh0, acc10, 0,0,0);
            acc11 = MFMA_B16(al1, bh1, acc11, 0,0,0);
        }

        // Fold gef, 16-lane shuffle reduce over cols.
        float part8[8];
#pragma unroll
        for (int r = 0; r < 4; r++) {
            part8[r]     = acc00[r] * e00[r] + acc01[r] * e01[r];
            part8[4 + r] = acc10[r] * e10[r] + acc11[r] * e11[r];
        }
#pragma unroll
        for (int mask = 1; mask < 16; mask <<= 1) {
#pragma unroll
            for (int e = 0; e < 8; e++) part8[e] += __shfl_xor(part8[e], mask, 64);
        }
        if (lr == 0) {
#pragma unroll
            for (int r = 0; r < 4; r++) {
                sred[wid * PPF + lg * 4 + r]      = part8[r];
                sred[wid * PPF + 16 + lg * 4 + r] = part8[4 + r];
            }
        }
        __syncthreads();

        // Scatter this pass's pairs: i-side into registers, j-side atomic.
        if (t < PPF && p0 + t < cnt) {
            float s = sred[t] + sred[PPF + t] + sred[2*PPF + t] + sred[3*PPF + t];
            int pp = p0 + t;
            float coef = s / nd[pp];
            float fx = coef * ndx[pp];
            float fy = coef * ndy[pp];
            float fz = coef * ndz[pp];
            iax += fx; iay += fy; iaz += fz;
            atomicAdd(f_acc + nj[pp]*3 + 0, fx);
            atomicAdd(f_acc + nj[pp]*3 + 1, fy);
            atomicAdd(f_acc + nj[pp]*3 + 2, fz);
        }
        __syncthreads();                   // sred/crbf/ts reuse next pass
    };

    bwd_pass(0, mk0);
    if (cnt > PPF) bwd_pass(PPF, mk1);

    // i-side reduce across scatter lanes (t<32 = lanes 0..31 of wave 0),
    // then 3 atomics per block.
    if (t < PPF) {
#pragma unroll
        for (int mask = 1; mask < 32; mask <<= 1) {
            iax += __shfl_xor(iax, mask, 64);
            iay += __shfl_xor(iay, mask, 64);
            iaz += __shfl_xor(iaz, mask, 64);
        }
        if (t == 0) {
            atomicAdd(f_acc + i*3 + 0, -iax);
            atomicAdd(f_acc + i*3 + 1, -iay);
            atomicAdd(f_acc + i*3 + 2, -iaz);
        }
    }
}

// ---------------------------------------------------------------- finalize
__global__ __launch_bounds__(256) void fin_kernel(
    const float* __restrict__ v, const float* __restrict__ mass,
    const float* __restrict__ p_eta, const float* __restrict__ f_acc,
    float* __restrict__ out)
{
    __shared__ float red[256];
    int t = threadIdx.x;
    float ke = 0.f;
    float c = p_eta[0] / Q0_F;
    for (int idx = t; idx < 3 * N_ATOMS; idx += 256) {
        int a = idx / 3;
        float vv = v[idx], mi = mass[a];
        out[DVDT_OFF + idx] = (f_acc[idx] - c * vv * mi) / mi;
        out[V_OFF + idx] = vv;
        ke += 0.5f * mi * vv * vv;
    }
    red[t] = ke;
    __syncthreads();
    for (int s = 128; s > 0; s >>= 1) {
        if (t < s) red[t] += red[t + s];
        __syncthreads();
    }
    if (t == 0) {
        float k0 = red[0];
        float e0 = p_eta[0], e1 = p_eta[1], e2 = p_eta[2], e3 = p_eta[3];
        out[PETA_OFF + 0] = 2.f * (k0 - TARGET_KE) - e0 * e1 / QI_F;
        out[PETA_OFF + 1] = e0 * e0 / Q0_F - KT_F - e1 * e2 / QI_F;
        out[PETA_OFF + 2] = e1 * e1 / QI_F - KT_F - e2 * e3 / QI_F;
        out[PETA_OFF + 3] = e2 * e2 / QI_F - KT_F;
    }
}

// ---------------------------------------------------------------- launch
extern "C" void kernel_launch(void* const* d_in, const int* in_sizes, int n_in,
                              void* d_out, int out_size, void* d_ws, size_t ws_size,
                              hipStream_t stream)
{
    const float* v     = (const float*)d_in[0];
    const float* q     = (const float*)d_in[1];
    const float* p_eta = (const float*)d_in[2];
    const float* mass  = (const float*)d_in[3];
    const float* embed = (const float*)d_in[4];
    const float* W1    = (const float*)d_in[5];
    const float* b1    = (const float*)d_in[6];
    const float* W2    = (const float*)d_in[7];
    const float* b2    = (const float*)d_in[8];
    const float* W3    = (const float*)d_in[9];
    const float* wout  = (const float*)d_in[10];
    const int*   z     = (const int*)d_in[11];
    float* out = (float*)d_out;

    float* h     = (float*)d_ws;                    // 98304
    float* W3T   = h + N_ATOMS * FD;                // 16384
    float* f_acc = W3T + FD * FD;                   // 2304
    unsigned short* w2bh = (unsigned short*)(f_acc + 3 * N_ATOMS);
    unsigned short* w2bl = w2bh + FD * FD;
    unsigned short* w2fh = w2bl + FD * FD;
    unsigned short* w2fl = w2fh + FD * FD;
    unsigned short* w1fh = w2fl + FD * FD;
    unsigned short* w1fl = w1fh + NRBF * FD;

    prep_kernel<<<384, 256, 0, stream>>>(z, embed, W1, W2, W3, h, W3T,
                                         w1fh, w1fl, w2fh, w2fl, w2bh, w2bl,
                                         f_acc);
    atom_kernel<<<N_ATOMS, 256, 0, stream>>>(q, w1fh, w1fl, b1, w2fh, w2fl,
                                             w2bh, w2bl, b2, h, W3, W3T, wout,
                                             f_acc);
    fin_kernel<<<1, 256, 0, stream>>>(v, mass, p_eta, f_acc, out);
}

// Round 12
// 131.102 us; speedup vs baseline: 1.1230x; 1.0001x over previous
//
#include <hip/hip_runtime.h>
#include <math.h>

// Problem constants (match reference)
#define N_ATOMS 768
#define FD 128          // feature width
#define NRBF 32
#define MAXN 64         // per-atom neighbor cap (mean ~26)
#define PPF 32          // pairs per MFMA pass (2 M-tiles of 16)
#define NTHREADS 512    // R29: 8 waves/block (was 4)
#define TST 136         // padded LDS stride for [*][128] bf16 (ushort) tiles
#define RSTU 40         // padded ushort stride for [*][32] bf16 rbf tiles (80B, 16B-aligned)

constexpr float  CUT2   = 25.0f;
constexpr float  GAMMA_ = 40.96f;            // 1/(5/32)^2
constexpr float  CSTEP  = 5.0f / 31.0f;      // linspace(0,5,32) step
constexpr double KB_D   = 8.617330337217213e-05;
constexpr double KT_D   = 300.0 * KB_D;
constexpr float  KT_F   = (float)KT_D;
constexpr float  TARGET_KE = (float)(0.5 * 2304.0 * KT_D);
constexpr float  Q0_F   = (float)(2.0 * 2304.0 * KT_D * 400.0);  // Q[0]
constexpr float  QI_F   = (float)(2.0 * KT_D * 400.0);           // Q[1..3]

#define DVDT_OFF 0
#define V_OFF    (3 * N_ATOMS)
#define PETA_OFF (6 * N_ATOMS)

using short8v = __attribute__((ext_vector_type(8))) short;
using f32x4   = __attribute__((ext_vector_type(4))) float;

#define MFMA_B16 __builtin_amdgcn_mfma_f32_16x16x32_bf16

__device__ __forceinline__ unsigned short f2bf(float x) {
    unsigned int u = __float_as_uint(x);
    u += 0x7FFF + ((u >> 16) & 1);           // round-to-nearest-even
    return (unsigned short)(u >> 16);
}
__device__ __forceinline__ float bf2f(unsigned short h) {
    return __uint_as_float(((unsigned int)h) << 16);
}

// Hard-won rules (28 rounds of counters):
// 1. NO __launch_bounds__ min-wave hints on GEMM kernels (spill cliff).
// 2. NEVER put __threadfence / completion counters on the hot grid (R14).
// 3. R22-R24 WIN: MFMA split-bf16 (AhBh+AhBl+AlBh, err ~2^-17) for all dense
//    phases. Layouts: bwd w2b native; fwd w2f[c][k]=W2[k][c];
//    w1f[c][k]=W1[k][c]. C/D: col=lane&15, row=(lane>>4)*4+reg (verified).
// 4. R26 REGRESSED: per-run atomics in fused epilogue (don't multiply
//    atomics). R25/R27 small wins: gate-mask reuse, in-reg gef, per-atom.
// 5. R28 WIN (-9.8us): fwd+mbar+bwd fused per-atom megakernel; m/mbar/gatem
//    global buffers gone; 3 dispatches. Counters on atom_kernel: MfmaUtil
//    4.2%, VALUBusy 11%, Occ 11.7% -> latency-bound, wave-starved (12
//    waves/CU, all barrier-phased together).
// 6. R29: 512 threads/block (8 waves), one 16-col tile per wave (was two).
//    Waves/CU 12->24; per-wave MFMA chains halve; staging/neighbor loops
//    halve. LDS ~51KB -> still 3 blocks/CU.

// ---------------------------------------------------------------- prep (fill only)
__global__ __launch_bounds__(256) void prep_kernel(
    const int* __restrict__ z, const float* __restrict__ embed,
    const float* __restrict__ W1, const float* __restrict__ W2,
    const float* __restrict__ W3,
    float* __restrict__ h, float* __restrict__ W3T,
    unsigned short* __restrict__ w1fh, unsigned short* __restrict__ w1fl,
    unsigned short* __restrict__ w2fh, unsigned short* __restrict__ w2fl,
    unsigned short* __restrict__ w2bh, unsigned short* __restrict__ w2bl,
    float* __restrict__ f_acc)
{
    int g = blockIdx.x * 256 + threadIdx.x;      // 98304 ids (384 blocks)
    if (g < N_ATOMS * FD) h[g] = embed[z[g >> 7] * FD + (g & 127)];
    if (g < FD * FD) {
        int r = g >> 7, c = g & 127;
        float w = W2[g];                         // W2[r][c]
        unsigned short hb = f2bf(w);
        unsigned short lb = f2bf(w - bf2f(hb));
        w2bh[g] = hb;                            // bwd B: native layout
        w2bl[g] = lb;
        w2fh[c * FD + r] = hb;                   // fwd B: w2f[c][k]=W2[k][c]
        w2fl[c * FD + r] = lb;
        W3T[c * FD + r] = W3[g];
        if (g < NRBF * FD) {                     // W1: NRBF x FD (r=k)
            float w1v = W1[g];
            unsigned short h1 = f2bf(w1v);
            w1fh[c * NRBF + r] = h1;             // [c][k], k contiguous
            w1fl[c * NRBF + r] = f2bf(w1v - bf2f(h1));
        }
    }
    if (g < 3 * N_ATOMS) f_acc[g] = 0.f;
}

// ---------------------------------------------------------------- atom (768 blocks x 512)
// Per-atom megakernel, 8 waves, one 16-col tile per wave.
__global__ __launch_bounds__(NTHREADS) void atom_kernel(
    const float* __restrict__ q,
    const unsigned short* __restrict__ w1fh, const unsigned short* __restrict__ w1fl,
    const float* __restrict__ b1,
    const unsigned short* __restrict__ w2fh, const unsigned short* __restrict__ w2fl,
    const unsigned short* __restrict__ w2bh, const unsigned short* __restrict__ w2bl,
    const float* __restrict__ b2, const float* __restrict__ h,
    const float* __restrict__ W3, const float* __restrict__ W3T,
    const float* __restrict__ wout,
    float* __restrict__ f_acc)
{
    __shared__ int   nj[MAXN];
    __shared__ float nd[MAXN], ndx[MAXN], ndy[MAXN], ndz[MAXN];
    __shared__ int   cnt_s;
    __shared__ __align__(16) unsigned short rbf_h[PPF * RSTU];   // 2560 B
    __shared__ __align__(16) unsigned short rbf_l[PPF * RSTU];   // 2560 B
    __shared__ __align__(16) unsigned short a1h[PPF * TST];      // 8704 B
    __shared__ __align__(16) unsigned short a1l[PPF * TST];      // 8704 B
    __shared__ __align__(16) unsigned short crbf_h[PPF * RSTU];  // 2560 B
    __shared__ __align__(16) unsigned short crbf_l[PPF * RSTU];  // 2560 B
    __shared__ __align__(16) unsigned short ts_h[PPF * TST];     // 8704 B
    __shared__ __align__(16) unsigned short ts_l[PPF * TST];     // 8704 B
    __shared__ float mrow[FD], gb[FD], mbrow[FD];                // 1536 B
    __shared__ float part[NTHREADS];                             // 2048 B
    __shared__ float sred[8 * PPF];                              // 1024 B
    // total ~50.9 KB -> 3 blocks/CU, 24 waves/CU

    int i = blockIdx.x, t = threadIdx.x;
    if (t == 0) cnt_s = 0;
    __syncthreads();
    float qx = q[i*3], qy = q[i*3+1], qz = q[i*3+2];
    for (int j = t; j < N_ATOMS; j += NTHREADS) {
        if (j == i) continue;
        float dx = qx - q[j*3], dy = qy - q[j*3+1], dz = qz - q[j*3+2];
        float d2 = dx*dx + dy*dy + dz*dz;
        if (d2 < CUT2) {
            int p = atomicAdd(&cnt_s, 1);
            if (p < MAXN) { nj[p] = j; nd[p] = sqrtf(d2);
                            ndx[p] = dx; ndy[p] = dy; ndz[p] = dz; }
        }
    }
    __syncthreads();
    int cnt = min(cnt_s, MAXN);
    if (cnt == 0) return;                        // no pairs, no forces

    int wid = t >> 6, lane = t & 63;             // wid 0..7
    int lr = lane & 15, lg = lane >> 4;
    int c0 = wid * 16 + lr;                      // this wave's single col-tile
    float bb0 = b1[c0];
    float b2c0 = b2[c0];
    float macc0 = 0.f;                           // m[i][c0] partial
    unsigned int mk0 = 0, mk1 = 0;               // per-pass relu gate masks (8b)

    // ---------------- fwd pass (A + B MFMA, accumulate m in regs) ----------
    auto fwd_pass = [&](int p0, unsigned int& mk_out) {
        // rbf staging (1024 items over 512 threads)
#pragma unroll
        for (int e = 0; e < 2; e++) {
            int idx = t + e * NTHREADS;
            int p = idx >> 5, k = idx & 31;
            int pp = p0 + p;
            float d = (pp < cnt) ? nd[pp] : 1.0f;
            float u = d - CSTEP * (float)k;
            float r = __expf(-GAMMA_ * u * u);
            unsigned short hb = f2bf(r);
            rbf_h[p * RSTU + k] = hb;
            rbf_l[p * RSTU + k] = f2bf(r - bf2f(hb));
        }
        __syncthreads();

        // h prefetch for this thread's 8 (pair, c0) elements
        float h00[4], h10[4];
#pragma unroll
        for (int r = 0; r < 4; r++) {
            int pA = p0 + lg * 4 + r, pB = pA + 16;
            bool vA = pA < cnt, vB = pB < cnt;
            int jA = vA ? nj[pA] : 0, jB = vB ? nj[pB] : 0;
            h00[r] = vA ? h[jA * FD + c0] : 0.f;
            h10[r] = vB ? h[jB * FD + c0] : 0.f;
        }

        // Phase A (MFMA, 6): u = b1 + rbf@W1 split; relu+split; gate mask.
        {
            f32x4 u00 = {bb0,bb0,bb0,bb0};
            f32x4 u10 = {bb0,bb0,bb0,bb0};
            short8v rh0 = *(const short8v*)(rbf_h + lr * RSTU + lg * 8);
            short8v rh1 = *(const short8v*)(rbf_h + (16+lr) * RSTU + lg * 8);
            short8v rl0 = *(const short8v*)(rbf_l + lr * RSTU + lg * 8);
            short8v rl1 = *(const short8v*)(rbf_l + (16+lr) * RSTU + lg * 8);
            short8v bh0 = *(const short8v*)(w1fh + c0 * NRBF + lg * 8);
            short8v bl0 = *(const short8v*)(w1fl + c0 * NRBF + lg * 8);
            u00 = MFMA_B16(rh0, bh0, u00, 0,0,0);
            u10 = MFMA_B16(rh1, bh0, u10, 0,0,0);
            u00 = MFMA_B16(rh0, bl0, u00, 0,0,0);
            u10 = MFMA_B16(rh1, bl0, u10, 0,0,0);
            u00 = MFMA_B16(rl0, bh0, u00, 0,0,0);
            u10 = MFMA_B16(rl1, bh0, u10, 0,0,0);
            // C/D: col=lane&15, row=(lane>>4)*4+reg  [verified]
            unsigned int mk = 0;
#pragma unroll
            for (int r = 0; r < 4; r++) {
                int pA = lg * 4 + r, pB = 16 + lg * 4 + r;
                float v; unsigned short hb;
                if (u00[r] > 0.f) mk |= 1u << r;
                if (u10[r] > 0.f) mk |= 1u << (4 + r);
                v = fmaxf(u00[r], 0.f); hb = f2bf(v);
                a1h[pA * TST + c0] = hb; a1l[pA * TST + c0] = f2bf(v - bf2f(hb));
                v = fmaxf(u10[r], 0.f); hb = f2bf(v);
                a1h[pB * TST + c0] = hb; a1l[pB * TST + c0] = f2bf(v - bf2f(hb));
            }
            mk_out = mk;
        }
        __syncthreads();

        // Phase B (MFMA, 24): filt = a1 @ W2 split; accumulate (filt+b2)*h_j.
        {
            f32x4 acc00 = {0.f,0.f,0.f,0.f};
            f32x4 acc10 = {0.f,0.f,0.f,0.f};
#pragma unroll
            for (int ks = 0; ks < 4; ks++) {
                int kb = ks * 32 + lg * 8;
                short8v ah0 = *(const short8v*)(a1h + (lr     ) * TST + kb);
                short8v ah1 = *(const short8v*)(a1h + (16 + lr) * TST + kb);
                short8v al0 = *(const short8v*)(a1l + (lr     ) * TST + kb);
                short8v al1 = *(const short8v*)(a1l + (16 + lr) * TST + kb);
                short8v bh0 = *(const short8v*)(w2fh + c0 * FD + kb);
                short8v bl0 = *(const short8v*)(w2fl + c0 * FD + kb);
                acc00 = MFMA_B16(ah0, bh0, acc00, 0,0,0);
                acc10 = MFMA_B16(ah1, bh0, acc10, 0,0,0);
                acc00 = MFMA_B16(ah0, bl0, acc00, 0,0,0);
                acc10 = MFMA_B16(ah1, bl0, acc10, 0,0,0);
                acc00 = MFMA_B16(al0, bh0, acc00, 0,0,0);
                acc10 = MFMA_B16(al1, bh0, acc10, 0,0,0);
            }
#pragma unroll
            for (int r = 0; r < 4; r++) {
                macc0 += (acc00[r] + b2c0) * h00[r] + (acc10[r] + b2c0) * h10[r];
            }
        }
        __syncthreads();                   // rbf/a1 reuse next pass
    };

    fwd_pass(0, mk0);
    if (cnt > PPF) fwd_pass(PPF, mk1);

    // ---------------- m reduce -> LDS mrow (no global m) --------------------
    {
        float r0 = macc0 + __shfl_xor(macc0, 16, 64);
        r0 += __shfl_xor(r0, 32, 64);
        if (lg == 0) mrow[c0] = r0;        // 8 waves x 16 lr cover 0..127
    }
    __syncthreads();

    // ---------------- mbar section (4-way f-split over 512 threads) --------
    {
        int c = t & 127, hh = t >> 7;      // hh = 0..3 -> f quarter
        int f0h = hh * 32;
        float g = 0.f;
#pragma unroll 4
        for (int f4 = f0h; f4 < f0h + 32; f4 += 4) {
            float4 w  = *(const float4*)(W3T + c * FD + f4);   // W3T[c][f]=W3[f][c]
            float4 mr = *(const float4*)(mrow + f4);
            g += mr.x*w.x + mr.y*w.y + mr.z*w.z + mr.w*w.w;
        }
        part[t] = g;
        __syncthreads();
        if (t < FD)
            gb[t] = (part[t] + part[t + 128] + part[t + 256] + part[t + 384] > 0.f)
                    ? wout[t] : 0.f;
        __syncthreads();
        float mb = 0.f;
#pragma unroll 4
        for (int f4 = f0h; f4 < f0h + 32; f4 += 4) {
            float4 w  = *(const float4*)(W3 + c * FD + f4);    // W3[c][f]=W3T[f][c]
            float4 gv = *(const float4*)(gb + f4);
            mb += gv.x*w.x + gv.y*w.y + gv.z*w.z + gv.w*w.w;
        }
        part[t] = mb;
        __syncthreads();
        if (t < FD) mbrow[t] = part[t] + part[t + 128] + part[t + 256] + part[t + 384];
    }
    __syncthreads();

    // ---------------- bwd passes -------------------------------------------
    float iax = 0.f, iay = 0.f, iaz = 0.f;       // i-side force accumulator

    auto bwd_pass = [&](int p0, unsigned int mk) {
        // crbf staging (1024 items)
#pragma unroll
        for (int e = 0; e < 2; e++) {
            int idx = t + e * NTHREADS;
            int p = idx >> 5, k = idx & 31;
            int pp = p0 + p;
            float d = (pp < cnt) ? nd[pp] : 1.0f;
            float u = d - CSTEP * (float)k;
            float r = __expf(-GAMMA_ * u * u);
            float cd = -2.f * GAMMA_ * u * r;
            unsigned short hc = f2bf(cd);
            crbf_h[p * RSTU + k] = hc;
            crbf_l[p * RSTU + k] = f2bf(cd - bf2f(hc));
        }
        // ts fill: ts[p][c] = mbrow[c] * h[j_p][c]  (1024 ushort4 items)
#pragma unroll
        for (int e = 0; e < 2; e++) {
            int idx = t + e * NTHREADS;
            int p = idx >> 5, c4g = (idx & 31) * 4;
            int pp = p0 + p;
            ushort4 hv = {0,0,0,0}, lv = {0,0,0,0};
            if (pp < cnt) {
                float4 mb4 = *(const float4*)(mbrow + c4g);
                float4 hj4 = *(const float4*)(h + nj[pp] * FD + c4g);
                float v0 = mb4.x*hj4.x, v1 = mb4.y*hj4.y;
                float v2 = mb4.z*hj4.z, v3 = mb4.w*hj4.w;
                hv.x = f2bf(v0); lv.x = f2bf(v0 - bf2f(hv.x));
                hv.y = f2bf(v1); lv.y = f2bf(v1 - bf2f(hv.y));
                hv.z = f2bf(v2); lv.z = f2bf(v2 - bf2f(hv.z));
                hv.w = f2bf(v3); lv.w = f2bf(v3 - bf2f(hv.w));
            }
            *(ushort4*)(ts_h + p * TST + c4g) = hv;
            *(ushort4*)(ts_l + p * TST + c4g) = lv;
        }
        __syncthreads();                   // crbf + ts ready

        // gef (6 MFMA, in registers): ef = crbf@W1 split; gate via mask.
        f32x4 e00 = {0.f,0.f,0.f,0.f};
        f32x4 e10 = {0.f,0.f,0.f,0.f};
        {
            short8v ch0 = *(const short8v*)(crbf_h + lr * RSTU + lg * 8);
            short8v ch1 = *(const short8v*)(crbf_h + (16+lr) * RSTU + lg * 8);
            short8v cl0 = *(const short8v*)(crbf_l + lr * RSTU + lg * 8);
            short8v cl1 = *(const short8v*)(crbf_l + (16+lr) * RSTU + lg * 8);
            short8v bh0 = *(const short8v*)(w1fh + c0 * NRBF + lg * 8);
            short8v bl0 = *(const short8v*)(w1fl + c0 * NRBF + lg * 8);
            e00 = MFMA_B16(ch0, bh0, e00, 0,0,0);
            e10 = MFMA_B16(ch1, bh0, e10, 0,0,0);
            e00 = MFMA_B16(ch0, bl0, e00, 0,0,0);
            e10 = MFMA_B16(ch1, bl0, e10, 0,0,0);
            e00 = MFMA_B16(cl0, bh0, e00, 0,0,0);
            e10 = MFMA_B16(cl1, bh0, e10, 0,0,0);
        }
#pragma unroll
        for (int r = 0; r < 4; r++) {
            e00[r] = (mk & (1u <<  r      )) ? e00[r] : 0.f;
            e10[r] = (mk & (1u << (4 + r))) ? e10[r] : 0.f;
        }

        // GEMM (24 MFMA): du1 = ts @ W2T (B from native-layout w2b).
        f32x4 acc00 = {0.f,0.f,0.f,0.f};
        f32x4 acc10 = {0.f,0.f,0.f,0.f};
#pragma unroll
        for (int ks = 0; ks < 4; ks++) {
            int kb = ks * 32 + lg * 8;
            short8v ah0 = *(const short8v*)(ts_h + (lr     ) * TST + kb);
            short8v ah1 = *(const short8v*)(ts_h + (16 + lr) * TST + kb);
            short8v al0 = *(const short8v*)(ts_l + (lr     ) * TST + kb);
            short8v al1 = *(const short8v*)(ts_l + (16 + lr) * TST + kb);
            short8v bh0 = *(const short8v*)(w2bh + c0 * FD + kb);
            short8v bl0 = *(const short8v*)(w2bl + c0 * FD + kb);
            acc00 = MFMA_B16(ah0, bh0, acc00, 0,0,0);
            acc10 = MFMA_B16(ah1, bh0, acc10, 0,0,0);
            acc00 = MFMA_B16(ah0, bl0, acc00, 0,0,0);
            acc10 = MFMA_B16(ah1, bl0, acc10, 0,0,0);
            acc00 = MFMA_B16(al0, bh0, acc00, 0,0,0);
            acc10 = MFMA_B16(al1, bh0, acc10, 0,0,0);
        }

        // Fold gef, reduce over the 16 col-lanes (lr bits), stash per wave.
        float part8[8];
#pragma unroll
        for (int r = 0; r < 4; r++) {
            part8[r]     = acc00[r] * e00[r];
            part8[4 + r] = acc10[r] * e10[r];
        }
#pragma unroll
        for (int mask = 1; mask < 16; mask <<= 1) {
#pragma unroll
            for (int e = 0; e < 8; e++) part8[e] += __shfl_xor(part8[e], mask, 64);
        }
        if (lr == 0) {
#pragma unroll
            for (int r = 0; r < 4; r++) {
                sred[wid * PPF + lg * 4 + r]      = part8[r];
                sred[wid * PPF + 16 + lg * 4 + r] = part8[4 + r];
            }
        }
        __syncthreads();

        // Scatter this pass's pairs: i-side into registers, j-side atomic.
        if (t < PPF && p0 + t < cnt) {
            float s = 0.f;
#pragma unroll
            for (int w = 0; w < 8; w++) s += sred[w * PPF + t];
            int pp = p0 + t;
            float coef = s / nd[pp];
            float fx = coef * ndx[pp];
            float fy = coef * ndy[pp];
            float fz = coef * ndz[pp];
            iax += fx; iay += fy; iaz += fz;
            atomicAdd(f_acc + nj[pp]*3 + 0, fx);
            atomicAdd(f_acc + nj[pp]*3 + 1, fy);
            atomicAdd(f_acc + nj[pp]*3 + 2, fz);
        }
        __syncthreads();                   // sred/crbf/ts reuse next pass
    };

    bwd_pass(0, mk0);
    if (cnt > PPF) bwd_pass(PPF, mk1);

    // i-side reduce across scatter lanes (t<32 = lanes 0..31 of wave 0),
    // then 3 atomics per block.
    if (t < PPF) {
#pragma unroll
        for (int mask = 1; mask < 32; mask <<= 1) {
            iax += __shfl_xor(iax, mask, 64);
            iay += __shfl_xor(iay, mask, 64);
            iaz += __shfl_xor(iaz, mask, 64);
        }
        if (t == 0) {
            atomicAdd(f_acc + i*3 + 0, -iax);
            atomicAdd(f_acc + i*3 + 1, -iay);
            atomicAdd(f_acc + i*3 + 2, -iaz);
        }
    }
}

// ---------------------------------------------------------------- finalize
__global__ __launch_bounds__(256) void fin_kernel(
    const float* __restrict__ v, const float* __restrict__ mass,
    const float* __restrict__ p_eta, const float* __restrict__ f_acc,
    float* __restrict__ out)
{
    __shared__ float red[256];
    int t = threadIdx.x;
    float ke = 0.f;
    float c = p_eta[0] / Q0_F;
    for (int idx = t; idx < 3 * N_ATOMS; idx += 256) {
        int a = idx / 3;
        float vv = v[idx], mi = mass[a];
        out[DVDT_OFF + idx] = (f_acc[idx] - c * vv * mi) / mi;
        out[V_OFF + idx] = vv;
        ke += 0.5f * mi * vv * vv;
    }
    red[t] = ke;
    __syncthreads();
    for (int s = 128; s > 0; s >>= 1) {
        if (t < s) red[t] += red[t + s];
        __syncthreads();
    }
    if (t == 0) {
        float k0 = red[0];
        float e0 = p_eta[0], e1 = p_eta[1], e2 = p_eta[2], e3 = p_eta[3];
        out[PETA_OFF + 0] = 2.f * (k0 - TARGET_KE) - e0 * e1 / QI_F;
        out[PETA_OFF + 1] = e0 * e0 / Q0_F - KT_F - e1 * e2 / QI_F;
        out[PETA_OFF + 2] = e1 * e1 / QI_F - KT_F - e2 * e3 / QI_F;
        out[PETA_OFF + 3] = e2 * e2 / QI_F - KT_F;
    }
}

// ---------------------------------------------------------------- launch
extern "C" void kernel_launch(void* const* d_in, const int* in_sizes, int n_in,
                              void* d_out, int out_size, void* d_ws, size_t ws_size,
                              hipStream_t stream)
{
    const float* v     = (const float*)d_in[0];
    const float* q     = (const float*)d_in[1];
    const float* p_eta = (const float*)d_in[2];
    const float* mass  = (const float*)d_in[3];
    const float* embed = (const float*)d_in[4];
    const float* W1    = (const float*)d_in[5];
    const float* b1    = (const float*)d_in[6];
    const float* W2    = (const float*)d_in[7];
    const float* b2    = (const float*)d_in[8];
    const float* W3    = (const float*)d_in[9];
    const float* wout  = (const float*)d_in[10];
    const int*   z     = (const int*)d_in[11];
    float* out = (float*)d_out;

    float* h     = (float*)d_ws;                    // 98304
    float* W3T   = h + N_ATOMS * FD;                // 16384
    float* f_acc = W3T + FD * FD;                   // 2304
    unsigned short* w2bh = (unsigned short*)(f_acc + 3 * N_ATOMS);
    unsigned short* w2bl = w2bh + FD * FD;
    unsigned short* w2fh = w2bl + FD * FD;
    unsigned short* w2fl = w2fh + FD * FD;
    unsigned short* w1fh = w2fl + FD * FD;
    unsigned short* w1fl = w1fh + NRBF * FD;

    prep_kernel<<<384, 256, 0, stream>>>(z, embed, W1, W2, W3, h, W3T,
                                         w1fh, w1fl, w2fh, w2fl, w2bh, w2bl,
                                         f_acc);
    atom_kernel<<<N_ATOMS, NTHREADS, 0, stream>>>(q, w1fh, w1fl, b1, w2fh, w2fl,
                                                  w2bh, w2bl, b2, h, W3, W3T, wout,
                                                  f_acc);
    fin_kernel<<<1, 256, 0, stream>>>(v, mass, p_eta, f_acc, out);
}

// Round 13
// 128.498 us; speedup vs baseline: 1.1457x; 1.0203x over previous
//
#include <hip/hip_runtime.h>
#include <math.h>

// Problem constants (match reference)
#define N_ATOMS 768
#define FD 128          // feature width
#define NRBF 32
#define MAXN 64         // per-atom neighbor cap (mean ~26)
#define PPF 32          // pairs per MFMA pass (2 M-tiles of 16)
#define NTHREADS 512    // 8 waves/block
#define TST 136         // padded LDS stride for [*][128] bf16 (ushort) tiles
#define RSTU 40         // padded ushort stride for [*][32] bf16 rbf tiles (80B, 16B-aligned)

constexpr float  CUT2   = 25.0f;
constexpr float  GAMMA_ = 40.96f;            // 1/(5/32)^2
constexpr float  CSTEP  = 5.0f / 31.0f;      // linspace(0,5,32) step
constexpr double KB_D   = 8.617330337217213e-05;
constexpr double KT_D   = 300.0 * KB_D;
constexpr float  KT_F   = (float)KT_D;
constexpr float  TARGET_KE = (float)(0.5 * 2304.0 * KT_D);
constexpr float  Q0_F   = (float)(2.0 * 2304.0 * KT_D * 400.0);  // Q[0]
constexpr float  QI_F   = (float)(2.0 * KT_D * 400.0);           // Q[1..3]

#define DVDT_OFF 0
#define V_OFF    (3 * N_ATOMS)
#define PETA_OFF (6 * N_ATOMS)

using short8v = __attribute__((ext_vector_type(8))) short;
using f32x4   = __attribute__((ext_vector_type(4))) float;

#define MFMA_B16 __builtin_amdgcn_mfma_f32_16x16x32_bf16

__device__ __forceinline__ unsigned short f2bf(float x) {
    unsigned int u = __float_as_uint(x);
    u += 0x7FFF + ((u >> 16) & 1);           // round-to-nearest-even
    return (unsigned short)(u >> 16);
}
__device__ __forceinline__ float bf2f(unsigned short h) {
    return __uint_as_float(((unsigned int)h) << 16);
}

// Hard-won rules (29 rounds of counters):
// 1. NO __launch_bounds__ min-wave hints on GEMM kernels (spill cliff).
// 2. NEVER put __threadfence / completion counters on the hot grid (R14).
// 3. R22-R24 WIN: MFMA split-bf16 (AhBh+AhBl+AlBh, err ~2^-17) for all dense
//    phases. Layouts: bwd w2b native; fwd w2f[c][k]=W2[k][c];
//    w1f[c][k]=W1[k][c]. C/D: col=lane&15, row=(lane>>4)*4+reg (verified).
// 4. R26 REGRESSED: multiplying atomics in fused epilogues.
// 5. R28 WIN (-9.8us): fwd+mbar+bwd fused per-atom megakernel, 3 dispatches.
// 6. R29 NULL (diagnostic): doubling waves/CU (12->24) with halved per-wave
//    work left duration unchanged -> atom kernel is bound by the PER-BLOCK
//    SERIAL CRITICAL PATH (~13 barrier phases x exposed L2 latency), with
//    only 3 independent barrier domains (blocks) per CU to overlap.
// 7. R30: (a) LDS overlay of temporally-disjoint fwd/bwd buffers
//    ({rbf,a1} U {crbf,ts}): 51.2->26.5KB -> 4 blocks/CU (wave-cap, full
//    occupancy); (b) mbar GEMVs in-wave (lg-split + shuffle reduce): 5->3
//    barriers, part[] deleted; (c) bwd pass-0 h-gathers prefetched right
//    after neighbor build (latency hides under fwd+mbar, T14); (d) inter-
//    pass barriers conditional (cnt<=32 majority skips 2).

// ---------------------------------------------------------------- prep (fill only)
__global__ __launch_bounds__(256) void prep_kernel(
    const int* __restrict__ z, const float* __restrict__ embed,
    const float* __restrict__ W1, const float* __restrict__ W2,
    const float* __restrict__ W3,
    float* __restrict__ h, float* __restrict__ W3T,
    unsigned short* __restrict__ w1fh, unsigned short* __restrict__ w1fl,
    unsigned short* __restrict__ w2fh, unsigned short* __restrict__ w2fl,
    unsigned short* __restrict__ w2bh, unsigned short* __restrict__ w2bl,
    float* __restrict__ f_acc)
{
    int g = blockIdx.x * 256 + threadIdx.x;      // 98304 ids (384 blocks)
    if (g < N_ATOMS * FD) h[g] = embed[z[g >> 7] * FD + (g & 127)];
    if (g < FD * FD) {
        int r = g >> 7, c = g & 127;
        float w = W2[g];                         // W2[r][c]
        unsigned short hb = f2bf(w);
        unsigned short lb = f2bf(w - bf2f(hb));
        w2bh[g] = hb;                            // bwd B: native layout
        w2bl[g] = lb;
        w2fh[c * FD + r] = hb;                   // fwd B: w2f[c][k]=W2[k][c]
        w2fl[c * FD + r] = lb;
        W3T[c * FD + r] = W3[g];
        if (g < NRBF * FD) {                     // W1: NRBF x FD (r=k)
            float w1v = W1[g];
            unsigned short h1 = f2bf(w1v);
            w1fh[c * NRBF + r] = h1;             // [c][k], k contiguous
            w1fl[c * NRBF + r] = f2bf(w1v - bf2f(h1));
        }
    }
    if (g < 3 * N_ATOMS) f_acc[g] = 0.f;
}

// ---------------------------------------------------------------- atom (768 blocks x 512)
__global__ __launch_bounds__(NTHREADS) void atom_kernel(
    const float* __restrict__ q,
    const unsigned short* __restrict__ w1fh, const unsigned short* __restrict__ w1fl,
    const float* __restrict__ b1,
    const unsigned short* __restrict__ w2fh, const unsigned short* __restrict__ w2fl,
    const unsigned short* __restrict__ w2bh, const unsigned short* __restrict__ w2bl,
    const float* __restrict__ b2, const float* __restrict__ h,
    const float* __restrict__ W3, const float* __restrict__ W3T,
    const float* __restrict__ wout,
    float* __restrict__ f_acc)
{
    __shared__ int   nj[MAXN];
    __shared__ float nd[MAXN], ndx[MAXN], ndy[MAXN], ndz[MAXN];
    __shared__ int   cnt_s;
    // Overlaid pools: fwd {rbf,a1} and bwd {crbf,ts} are temporally disjoint.
    __shared__ __align__(16) unsigned short poolR[2 * PPF * RSTU];  // 5120 B
    __shared__ __align__(16) unsigned short poolA[2 * PPF * TST];   // 17408 B
    __shared__ float mrow[FD], gb[FD], mbrow[FD];                   // 1536 B
    __shared__ float sred[8 * PPF];                                 // 1024 B
    // total ~26.5 KB -> 4 blocks/CU (wave-capped at 32 waves/CU)

    unsigned short* rbf_h  = poolR;
    unsigned short* rbf_l  = poolR + PPF * RSTU;
    unsigned short* crbf_h = poolR;                // overlay (bwd)
    unsigned short* crbf_l = poolR + PPF * RSTU;
    unsigned short* a1h  = poolA;
    unsigned short* a1l  = poolA + PPF * TST;
    unsigned short* ts_h = poolA;                  // overlay (bwd)
    unsigned short* ts_l = poolA + PPF * TST;

    int i = blockIdx.x, t = threadIdx.x;
    if (t == 0) cnt_s = 0;
    __syncthreads();
    float qx = q[i*3], qy = q[i*3+1], qz = q[i*3+2];
    for (int j = t; j < N_ATOMS; j += NTHREADS) {
        if (j == i) continue;
        float dx = qx - q[j*3], dy = qy - q[j*3+1], dz = qz - q[j*3+2];
        float d2 = dx*dx + dy*dy + dz*dz;
        if (d2 < CUT2) {
            int p = atomicAdd(&cnt_s, 1);
            if (p < MAXN) { nj[p] = j; nd[p] = sqrtf(d2);
                            ndx[p] = dx; ndy[p] = dy; ndz[p] = dz; }
        }
    }
    __syncthreads();
    int cnt = min(cnt_s, MAXN);
    if (cnt == 0) return;                        // no pairs, no forces

    int wid = t >> 6, lane = t & 63;             // wid 0..7
    int lr = lane & 15, lg = lane >> 4;
    int c0 = wid * 16 + lr;                      // this wave's single col-tile
    float bb0 = b1[c0];
    float b2c0 = b2[c0];
    float macc0 = 0.f;                           // m[i][c0] partial
    unsigned int mk0 = 0, mk1 = 0;               // per-pass relu gate masks (8b)

    // T14 prefetch: pass-0 ts-fill h gathers issued NOW; latency hides under
    // the entire fwd + mbar section. (ts-fill thread t handles idx = t,
    // t+512 -> (p, c4g) fixed.)
    float4 hj0[2];
#pragma unroll
    for (int e = 0; e < 2; e++) {
        int idx = t + e * NTHREADS;
        int p = idx >> 5, c4g = (idx & 31) * 4;
        hj0[e] = (p < cnt) ? *(const float4*)(h + nj[p] * FD + c4g)
                           : make_float4(0.f, 0.f, 0.f, 0.f);
    }

    // ---------------- fwd pass (A + B MFMA, accumulate m in regs) ----------
    auto fwd_pass = [&](int p0, unsigned int& mk_out) {
        // rbf staging (1024 items over 512 threads)
#pragma unroll
        for (int e = 0; e < 2; e++) {
            int idx = t + e * NTHREADS;
            int p = idx >> 5, k = idx & 31;
            int pp = p0 + p;
            float d = (pp < cnt) ? nd[pp] : 1.0f;
            float u = d - CSTEP * (float)k;
            float r = __expf(-GAMMA_ * u * u);
            unsigned short hb = f2bf(r);
            rbf_h[p * RSTU + k] = hb;
            rbf_l[p * RSTU + k] = f2bf(r - bf2f(hb));
        }
        __syncthreads();

        // h prefetch for this thread's 8 (pair, c0) elements
        float h00[4], h10[4];
#pragma unroll
        for (int r = 0; r < 4; r++) {
            int pA = p0 + lg * 4 + r, pB = pA + 16;
            bool vA = pA < cnt, vB = pB < cnt;
            int jA = vA ? nj[pA] : 0, jB = vB ? nj[pB] : 0;
            h00[r] = vA ? h[jA * FD + c0] : 0.f;
            h10[r] = vB ? h[jB * FD + c0] : 0.f;
        }

        // Phase A (MFMA, 6): u = b1 + rbf@W1 split; relu+split; gate mask.
        {
            f32x4 u00 = {bb0,bb0,bb0,bb0};
            f32x4 u10 = {bb0,bb0,bb0,bb0};
            short8v rh0 = *(const short8v*)(rbf_h + lr * RSTU + lg * 8);
            short8v rh1 = *(const short8v*)(rbf_h + (16+lr) * RSTU + lg * 8);
            short8v rl0 = *(const short8v*)(rbf_l + lr * RSTU + lg * 8);
            short8v rl1 = *(const short8v*)(rbf_l + (16+lr) * RSTU + lg * 8);
            short8v bh0 = *(const short8v*)(w1fh + c0 * NRBF + lg * 8);
            short8v bl0 = *(const short8v*)(w1fl + c0 * NRBF + lg * 8);
            u00 = MFMA_B16(rh0, bh0, u00, 0,0,0);
            u10 = MFMA_B16(rh1, bh0, u10, 0,0,0);
            u00 = MFMA_B16(rh0, bl0, u00, 0,0,0);
            u10 = MFMA_B16(rh1, bl0, u10, 0,0,0);
            u00 = MFMA_B16(rl0, bh0, u00, 0,0,0);
            u10 = MFMA_B16(rl1, bh0, u10, 0,0,0);
            // C/D: col=lane&15, row=(lane>>4)*4+reg  [verified]
            unsigned int mk = 0;
#pragma unroll
            for (int r = 0; r < 4; r++) {
                int pA = lg * 4 + r, pB = 16 + lg * 4 + r;
                float v; unsigned short hb;
                if (u00[r] > 0.f) mk |= 1u << r;
                if (u10[r] > 0.f) mk |= 1u << (4 + r);
                v = fmaxf(u00[r], 0.f); hb = f2bf(v);
                a1h[pA * TST + c0] = hb; a1l[pA * TST + c0] = f2bf(v - bf2f(hb));
                v = fmaxf(u10[r], 0.f); hb = f2bf(v);
                a1h[pB * TST + c0] = hb; a1l[pB * TST + c0] = f2bf(v - bf2f(hb));
            }
            mk_out = mk;
        }
        __syncthreads();

        // Phase B (MFMA, 24): filt = a1 @ W2 split; accumulate (filt+b2)*h_j.
        {
            f32x4 acc00 = {0.f,0.f,0.f,0.f};
            f32x4 acc10 = {0.f,0.f,0.f,0.f};
#pragma unroll
            for (int ks = 0; ks < 4; ks++) {
                int kb = ks * 32 + lg * 8;
                short8v ah0 = *(const short8v*)(a1h + (lr     ) * TST + kb);
                short8v ah1 = *(const short8v*)(a1h + (16 + lr) * TST + kb);
                short8v al0 = *(const short8v*)(a1l + (lr     ) * TST + kb);
                short8v al1 = *(const short8v*)(a1l + (16 + lr) * TST + kb);
                short8v bh0 = *(const short8v*)(w2fh + c0 * FD + kb);
                short8v bl0 = *(const short8v*)(w2fl + c0 * FD + kb);
                acc00 = MFMA_B16(ah0, bh0, acc00, 0,0,0);
                acc10 = MFMA_B16(ah1, bh0, acc10, 0,0,0);
                acc00 = MFMA_B16(ah0, bl0, acc00, 0,0,0);
                acc10 = MFMA_B16(ah1, bl0, acc10, 0,0,0);
                acc00 = MFMA_B16(al0, bh0, acc00, 0,0,0);
                acc10 = MFMA_B16(al1, bh0, acc10, 0,0,0);
            }
#pragma unroll
            for (int r = 0; r < 4; r++) {
                macc0 += (acc00[r] + b2c0) * h00[r] + (acc10[r] + b2c0) * h10[r];
            }
        }
        // (no trailing barrier — caller inserts one only between passes)
    };

    fwd_pass(0, mk0);
    if (cnt > PPF) { __syncthreads(); fwd_pass(PPF, mk1); }

    // ---------------- m reduce -> LDS mrow ---------------------------------
    {
        float r0 = macc0 + __shfl_xor(macc0, 16, 64);
        r0 += __shfl_xor(r0, 32, 64);
        if (lg == 0) mrow[c0] = r0;        // 8 waves x 16 lr cover 0..127
    }
    __syncthreads();

    // ---------------- mbar: in-wave GEMVs (lg = f-quarter), 2 barriers -----
    {
        int f0h = lg * 32;
        float g = 0.f;
#pragma unroll
        for (int f4 = 0; f4 < 32; f4 += 4) {
            float4 w  = *(const float4*)(W3T + c0 * FD + f0h + f4);  // W3T[c][f]
            float4 mr = *(const float4*)(mrow + f0h + f4);
            g += mr.x*w.x + mr.y*w.y + mr.z*w.z + mr.w*w.w;
        }
        g += __shfl_xor(g, 16, 64);
        g += __shfl_xor(g, 32, 64);
        if (lg == 0) gb[c0] = (g > 0.f) ? wout[c0] : 0.f;
    }
    __syncthreads();
    {
        int f0h = lg * 32;
        float mb = 0.f;
#pragma unroll
        for (int f4 = 0; f4 < 32; f4 += 4) {
            float4 w  = *(const float4*)(W3 + c0 * FD + f0h + f4);   // W3[c][f]
            float4 gv = *(const float4*)(gb + f0h + f4);
            mb += gv.x*w.x + gv.y*w.y + gv.z*w.z + gv.w*w.w;
        }
        mb += __shfl_xor(mb, 16, 64);
        mb += __shfl_xor(mb, 32, 64);
        if (lg == 0) mbrow[c0] = mb;
    }
    __syncthreads();

    // ---------------- bwd passes -------------------------------------------
    float iax = 0.f, iay = 0.f, iaz = 0.f;       // i-side force accumulator

    auto bwd_pass = [&](int p0, unsigned int mk, bool first) {
        // crbf staging (1024 items)
#pragma unroll
        for (int e = 0; e < 2; e++) {
            int idx = t + e * NTHREADS;
            int p = idx >> 5, k = idx & 31;
            int pp = p0 + p;
            float d = (pp < cnt) ? nd[pp] : 1.0f;
            float u = d - CSTEP * (float)k;
            float r = __expf(-GAMMA_ * u * u);
            float cd = -2.f * GAMMA_ * u * r;
            unsigned short hc = f2bf(cd);
            crbf_h[p * RSTU + k] = hc;
            crbf_l[p * RSTU + k] = f2bf(cd - bf2f(hc));
        }
        // ts fill: ts[p][c] = mbrow[c] * h[j_p][c]  (pass-0 h prefetched)
#pragma unroll
        for (int e = 0; e < 2; e++) {
            int idx = t + e * NTHREADS;
            int p = idx >> 5, c4g = (idx & 31) * 4;
            int pp = p0 + p;
            ushort4 hv = {0,0,0,0}, lv = {0,0,0,0};
            if (pp < cnt) {
                float4 mb4 = *(const float4*)(mbrow + c4g);
                float4 hj4 = first ? hj0[e]
                                   : *(const float4*)(h + nj[pp] * FD + c4g);
                float v0 = mb4.x*hj4.x, v1 = mb4.y*hj4.y;
                float v2 = mb4.z*hj4.z, v3 = mb4.w*hj4.w;
                hv.x = f2bf(v0); lv.x = f2bf(v0 - bf2f(hv.x));
                hv.y = f2bf(v1); lv.y = f2bf(v1 - bf2f(hv.y));
                hv.z = f2bf(v2); lv.z = f2bf(v2 - bf2f(hv.z));
                hv.w = f2bf(v3); lv.w = f2bf(v3 - bf2f(hv.w));
            }
            *(ushort4*)(ts_h + p * TST + c4g) = hv;
            *(ushort4*)(ts_l + p * TST + c4g) = lv;
        }
        __syncthreads();                   // crbf + ts ready

        // gef (6 MFMA, in registers): ef = crbf@W1 split; gate via mask.
        f32x4 e00 = {0.f,0.f,0.f,0.f};
        f32x4 e10 = {0.f,0.f,0.f,0.f};
        {
            short8v ch0 = *(const short8v*)(crbf_h + lr * RSTU + lg * 8);
            short8v ch1 = *(const short8v*)(crbf_h + (16+lr) * RSTU + lg * 8);
            short8v cl0 = *(const short8v*)(crbf_l + lr * RSTU + lg * 8);
            short8v cl1 = *(const short8v*)(crbf_l + (16+lr) * RSTU + lg * 8);
            short8v bh0 = *(const short8v*)(w1fh + c0 * NRBF + lg * 8);
            short8v bl0 = *(const short8v*)(w1fl + c0 * NRBF + lg * 8);
            e00 = MFMA_B16(ch0, bh0, e00, 0,0,0);
            e10 = MFMA_B16(ch1, bh0, e10, 0,0,0);
            e00 = MFMA_B16(ch0, bl0, e00, 0,0,0);
            e10 = MFMA_B16(ch1, bl0, e10, 0,0,0);
            e00 = MFMA_B16(cl0, bh0, e00, 0,0,0);
            e10 = MFMA_B16(cl1, bh0, e10, 0,0,0);
        }
#pragma unroll
        for (int r = 0; r < 4; r++) {
            e00[r] = (mk & (1u <<  r      )) ? e00[r] : 0.f;
            e10[r] = (mk & (1u << (4 + r))) ? e10[r] : 0.f;
        }

        // GEMM (24 MFMA): du1 = ts @ W2T (B from native-layout w2b).
        f32x4 acc00 = {0.f,0.f,0.f,0.f};
        f32x4 acc10 = {0.f,0.f,0.f,0.f};
#pragma unroll
        for (int ks = 0; ks < 4; ks++) {
            int kb = ks * 32 + lg * 8;
            short8v ah0 = *(const short8v*)(ts_h + (lr     ) * TST + kb);
            short8v ah1 = *(const short8v*)(ts_h + (16 + lr) * TST + kb);
            short8v al0 = *(const short8v*)(ts_l + (lr     ) * TST + kb);
            short8v al1 = *(const short8v*)(ts_l + (16 + lr) * TST + kb);
            short8v bh0 = *(const short8v*)(w2bh + c0 * FD + kb);
            short8v bl0 = *(const short8v*)(w2bl + c0 * FD + kb);
            acc00 = MFMA_B16(ah0, bh0, acc00, 0,0,0);
            acc10 = MFMA_B16(ah1, bh0, acc10, 0,0,0);
            acc00 = MFMA_B16(ah0, bl0, acc00, 0,0,0);
            acc10 = MFMA_B16(ah1, bl0, acc10, 0,0,0);
            acc00 = MFMA_B16(al0, bh0, acc00, 0,0,0);
            acc10 = MFMA_B16(al1, bh0, acc10, 0,0,0);
        }

        // Fold gef, reduce over the 16 col-lanes, stash per wave.
        float part8[8];
#pragma unroll
        for (int r = 0; r < 4; r++) {
            part8[r]     = acc00[r] * e00[r];
            part8[4 + r] = acc10[r] * e10[r];
        }
#pragma unroll
        for (int mask = 1; mask < 16; mask <<= 1) {
#pragma unroll
            for (int e = 0; e < 8; e++) part8[e] += __shfl_xor(part8[e], mask, 64);
        }
        if (lr == 0) {
#pragma unroll
            for (int r = 0; r < 4; r++) {
                sred[wid * PPF + lg * 4 + r]      = part8[r];
                sred[wid * PPF + 16 + lg * 4 + r] = part8[4 + r];
            }
        }
        __syncthreads();

        // Scatter this pass's pairs: i-side into registers, j-side atomic.
        if (t < PPF && p0 + t < cnt) {
            float s = 0.f;
#pragma unroll
            for (int w = 0; w < 8; w++) s += sred[w * PPF + t];
            int pp = p0 + t;
            float coef = s / nd[pp];
            float fx = coef * ndx[pp];
            float fy = coef * ndy[pp];
            float fz = coef * ndz[pp];
            iax += fx; iay += fy; iaz += fz;
            atomicAdd(f_acc + nj[pp]*3 + 0, fx);
            atomicAdd(f_acc + nj[pp]*3 + 1, fy);
            atomicAdd(f_acc + nj[pp]*3 + 2, fz);
        }
        // (no trailing barrier — caller inserts one only between passes)
    };

    bwd_pass(0, mk0, true);
    if (cnt > PPF) { __syncthreads(); bwd_pass(PPF, mk1, false); }

    // i-side reduce across scatter lanes (t<32 = lanes 0..31 of wave 0),
    // then 3 atomics per block.
    if (t < PPF) {
#pragma unroll
        for (int mask = 1; mask < 32; mask <<= 1) {
            iax += __shfl_xor(iax, mask, 64);
            iay += __shfl_xor(iay, mask, 64);
            iaz += __shfl_xor(iaz, mask, 64);
        }
        if (t == 0) {
            atomicAdd(f_acc + i*3 + 0, -iax);
            atomicAdd(f_acc + i*3 + 1, -iay);
            atomicAdd(f_acc + i*3 + 2, -iaz);
        }
    }
}

// ---------------------------------------------------------------- finalize
__global__ __launch_bounds__(256) void fin_kernel(
    const float* __restrict__ v, const float* __restrict__ mass,
    const float* __restrict__ p_eta, const float* __restrict__ f_acc,
    float* __restrict__ out)
{
    __shared__ float red[256];
    int t = threadIdx.x;
    float ke = 0.f;
    float c = p_eta[0] / Q0_F;
    for (int idx = t; idx < 3 * N_ATOMS; idx += 256) {
        int a = idx / 3;
        float vv = v[idx], mi = mass[a];
        out[DVDT_OFF + idx] = (f_acc[idx] - c * vv * mi) / mi;
        out[V_OFF + idx] = vv;
        ke += 0.5f * mi * vv * vv;
    }
    red[t] = ke;
    __syncthreads();
    for (int s = 128; s > 0; s >>= 1) {
        if (t < s) red[t] += red[t + s];
        __syncthreads();
    }
    if (t == 0) {
        float k0 = red[0];
        float e0 = p_eta[0], e1 = p_eta[1], e2 = p_eta[2], e3 = p_eta[3];
        out[PETA_OFF + 0] = 2.f * (k0 - TARGET_KE) - e0 * e1 / QI_F;
        out[PETA_OFF + 1] = e0 * e0 / Q0_F - KT_F - e1 * e2 / QI_F;
        out[PETA_OFF + 2] = e1 * e1 / QI_F - KT_F - e2 * e3 / QI_F;
        out[PETA_OFF + 3] = e2 * e2 / QI_F - KT_F;
    }
}

// ---------------------------------------------------------------- launch
extern "C" void kernel_launch(void* const* d_in, const int* in_sizes, int n_in,
                              void* d_out, int out_size, void* d_ws, size_t ws_size,
                              hipStream_t stream)
{
    const float* v     = (const float*)d_in[0];
    const float* q     = (const float*)d_in[1];
    const float* p_eta = (const float*)d_in[2];
    const float* mass  = (const float*)d_in[3];
    const float* embed = (const float*)d_in[4];
    const float* W1    = (const float*)d_in[5];
    const float* b1    = (const float*)d_in[6];
    const float* W2    = (const float*)d_in[7];
    const float* b2    = (const float*)d_in[8];
    const float* W3    = (const float*)d_in[9];
    const float* wout  = (const float*)d_in[10];
    const int*   z     = (const int*)d_in[11];
    float* out = (float*)d_out;

    float* h     = (float*)d_ws;                    // 98304
    float* W3T   = h + N_ATOMS * FD;                // 16384
    float* f_acc = W3T + FD * FD;                   // 2304
    unsigned short* w2bh = (unsigned short*)(f_acc + 3 * N_ATOMS);
    unsigned short* w2bl = w2bh + FD * FD;
    unsigned short* w2fh = w2bl + FD * FD;
    unsigned short* w2fl = w2fh + FD * FD;
    unsigned short* w1fh = w2fl + FD * FD;
    unsigned short* w1fl = w1fh + NRBF * FD;

    prep_kernel<<<384, 256, 0, stream>>>(z, embed, W1, W2, W3, h, W3T,
                                         w1fh, w1fl, w2fh, w2fl, w2bh, w2bl,
                                         f_acc);
    atom_kernel<<<N_ATOMS, NTHREADS, 0, stream>>>(q, w1fh, w1fl, b1, w2fh, w2fl,
                                                  w2bh, w2bl, b2, h, W3, W3T, wout,
                                                  f_acc);
    fin_kernel<<<1, 256, 0, stream>>>(v, mass, p_eta, f_acc, out);
}

// Round 14
// 127.806 us; speedup vs baseline: 1.1519x; 1.0054x over previous
//
#include <hip/hip_runtime.h>
#include <math.h>

// Problem constants (match reference)
#define N_ATOMS 768
#define FD 128          // feature width
#define NRBF 32
#define MAXN 64         // per-atom neighbor cap (mean ~26)
#define PPF 32          // pairs per MFMA pass (2 M-tiles of 16)
#define NTHREADS 512    // 8 waves/block
#define TST 136         // padded LDS stride for [*][128] bf16 (ushort) tiles
#define RSTU 40         // padded ushort stride for [*][32] bf16 rbf tiles (80B, 16B-aligned)

constexpr float  CUT2   = 25.0f;
constexpr float  GAMMA_ = 40.96f;            // 1/(5/32)^2
constexpr float  CSTEP  = 5.0f / 31.0f;      // linspace(0,5,32) step
constexpr double KB_D   = 8.617330337217213e-05;
constexpr double KT_D   = 300.0 * KB_D;
constexpr float  KT_F   = (float)KT_D;
constexpr float  TARGET_KE = (float)(0.5 * 2304.0 * KT_D);
constexpr float  Q0_F   = (float)(2.0 * 2304.0 * KT_D * 400.0);  // Q[0]
constexpr float  QI_F   = (float)(2.0 * KT_D * 400.0);           // Q[1..3]

#define DVDT_OFF 0
#define V_OFF    (3 * N_ATOMS)
#define PETA_OFF (6 * N_ATOMS)

using short8v = __attribute__((ext_vector_type(8))) short;
using f32x4   = __attribute__((ext_vector_type(4))) float;

#define MFMA_B16 __builtin_amdgcn_mfma_f32_16x16x32_bf16

__device__ __forceinline__ unsigned short f2bf(float x) {
    unsigned int u = __float_as_uint(x);
    u += 0x7FFF + ((u >> 16) & 1);           // round-to-nearest-even
    return (unsigned short)(u >> 16);
}
__device__ __forceinline__ float bf2f(unsigned short h) {
    return __uint_as_float(((unsigned int)h) << 16);
}

// Hard-won rules (30 rounds of counters):
// 1. NO __launch_bounds__ min-wave hints on GEMM kernels (spill cliff).
// 2. NEVER put __threadfence / completion counters on the hot grid (R14).
// 3. R22-R24 WIN: MFMA split-bf16 (AhBh+AhBl+AlBh, err ~2^-17) for all dense
//    phases. Layouts: bwd w2b native; fwd w2f[c][k]=W2[k][c];
//    w1f[c][k]=W1[k][c]. C/D: col=lane&15, row=(lane>>4)*4+reg (verified).
// 4. R26 REGRESSED: multiplying atomics in fused epilogues.
// 5. R28 WIN (-9.8us): fwd+mbar+bwd fused per-atom megakernel, 3 dispatches.
// 6. R29/R30 ~NULL: waves x2, LDS /2, barriers -4 all moved atom <=2%.
//    Occupancy counter reads ~1 resident block/CU regardless -> extra
//    parallelism not materializing; only lever left is the per-block path.
// 7. R31: block-invariant weight fragments hoisted to REGISTERS with
//    liveness phasing: W1+W2f loaded at top (latency covered by neighbor
//    build), W2b loaded after fwd (covered by m-reduce+mbar; w2f regs dead
//    -> budget reused). All MFMA phases now pure LDS+register. VGPR
//    60 -> ~100 (peak not sum).

// ---------------------------------------------------------------- prep (fill only)
__global__ __launch_bounds__(256) void prep_kernel(
    const int* __restrict__ z, const float* __restrict__ embed,
    const float* __restrict__ W1, const float* __restrict__ W2,
    const float* __restrict__ W3,
    float* __restrict__ h, float* __restrict__ W3T,
    unsigned short* __restrict__ w1fh, unsigned short* __restrict__ w1fl,
    unsigned short* __restrict__ w2fh, unsigned short* __restrict__ w2fl,
    unsigned short* __restrict__ w2bh, unsigned short* __restrict__ w2bl,
    float* __restrict__ f_acc)
{
    int g = blockIdx.x * 256 + threadIdx.x;      // 98304 ids (384 blocks)
    if (g < N_ATOMS * FD) h[g] = embed[z[g >> 7] * FD + (g & 127)];
    if (g < FD * FD) {
        int r = g >> 7, c = g & 127;
        float w = W2[g];                         // W2[r][c]
        unsigned short hb = f2bf(w);
        unsigned short lb = f2bf(w - bf2f(hb));
        w2bh[g] = hb;                            // bwd B: native layout
        w2bl[g] = lb;
        w2fh[c * FD + r] = hb;                   // fwd B: w2f[c][k]=W2[k][c]
        w2fl[c * FD + r] = lb;
        W3T[c * FD + r] = W3[g];
        if (g < NRBF * FD) {                     // W1: NRBF x FD (r=k)
            float w1v = W1[g];
            unsigned short h1 = f2bf(w1v);
            w1fh[c * NRBF + r] = h1;             // [c][k], k contiguous
            w1fl[c * NRBF + r] = f2bf(w1v - bf2f(h1));
        }
    }
    if (g < 3 * N_ATOMS) f_acc[g] = 0.f;
}

// ---------------------------------------------------------------- atom (768 blocks x 512)
__global__ __launch_bounds__(NTHREADS) void atom_kernel(
    const float* __restrict__ q,
    const unsigned short* __restrict__ w1fh, const unsigned short* __restrict__ w1fl,
    const float* __restrict__ b1,
    const unsigned short* __restrict__ w2fh, const unsigned short* __restrict__ w2fl,
    const unsigned short* __restrict__ w2bh, const unsigned short* __restrict__ w2bl,
    const float* __restrict__ b2, const float* __restrict__ h,
    const float* __restrict__ W3, const float* __restrict__ W3T,
    const float* __restrict__ wout,
    float* __restrict__ f_acc)
{
    __shared__ int   nj[MAXN];
    __shared__ float nd[MAXN], ndx[MAXN], ndy[MAXN], ndz[MAXN];
    __shared__ int   cnt_s;
    // Overlaid pools: fwd {rbf,a1} and bwd {crbf,ts} are temporally disjoint.
    __shared__ __align__(16) unsigned short poolR[2 * PPF * RSTU];  // 5120 B
    __shared__ __align__(16) unsigned short poolA[2 * PPF * TST];   // 17408 B
    __shared__ float mrow[FD], gb[FD], mbrow[FD];                   // 1536 B
    __shared__ float sred[8 * PPF];                                 // 1024 B
    // total ~26.5 KB

    unsigned short* rbf_h  = poolR;
    unsigned short* rbf_l  = poolR + PPF * RSTU;
    unsigned short* crbf_h = poolR;                // overlay (bwd)
    unsigned short* crbf_l = poolR + PPF * RSTU;
    unsigned short* a1h  = poolA;
    unsigned short* a1l  = poolA + PPF * TST;
    unsigned short* ts_h = poolA;                  // overlay (bwd)
    unsigned short* ts_l = poolA + PPF * TST;

    int i = blockIdx.x, t = threadIdx.x;
    int wid = t >> 6, lane = t & 63;             // wid 0..7
    int lr = lane & 15, lg = lane >> 4;
    int c0 = wid * 16 + lr;                      // this wave's single col-tile

    if (t == 0) cnt_s = 0;
    __syncthreads();

    // R31: block-invariant fwd weights into registers NOW — latency covered
    // by the neighbor-build loop below.
    short8v w1h_r = *(const short8v*)(w1fh + c0 * NRBF + lg * 8);
    short8v w1l_r = *(const short8v*)(w1fl + c0 * NRBF + lg * 8);
    short8v w2f_h[4], w2f_l[4];
#pragma unroll
    for (int ks = 0; ks < 4; ks++) {
        int kb = ks * 32 + lg * 8;
        w2f_h[ks] = *(const short8v*)(w2fh + c0 * FD + kb);
        w2f_l[ks] = *(const short8v*)(w2fl + c0 * FD + kb);
    }
    float bb0  = b1[c0];
    float b2c0 = b2[c0];

    float qx = q[i*3], qy = q[i*3+1], qz = q[i*3+2];
    for (int j = t; j < N_ATOMS; j += NTHREADS) {
        if (j == i) continue;
        float dx = qx - q[j*3], dy = qy - q[j*3+1], dz = qz - q[j*3+2];
        float d2 = dx*dx + dy*dy + dz*dz;
        if (d2 < CUT2) {
            int p = atomicAdd(&cnt_s, 1);
            if (p < MAXN) { nj[p] = j; nd[p] = sqrtf(d2);
                            ndx[p] = dx; ndy[p] = dy; ndz[p] = dz; }
        }
    }
    __syncthreads();
    int cnt = min(cnt_s, MAXN);
    if (cnt == 0) return;                        // no pairs, no forces

    float macc0 = 0.f;                           // m[i][c0] partial
    unsigned int mk0 = 0, mk1 = 0;               // per-pass relu gate masks (8b)

    // T14 prefetch: pass-0 ts-fill h gathers issued NOW; latency hides under
    // the entire fwd + mbar section.
    float4 hj0[2];
#pragma unroll
    for (int e = 0; e < 2; e++) {
        int idx = t + e * NTHREADS;
        int p = idx >> 5, c4g = (idx & 31) * 4;
        hj0[e] = (p < cnt) ? *(const float4*)(h + nj[p] * FD + c4g)
                           : make_float4(0.f, 0.f, 0.f, 0.f);
    }

    // ---------------- fwd pass (A + B MFMA, pure LDS+register) -------------
    auto fwd_pass = [&](int p0, unsigned int& mk_out) {
        // rbf staging (1024 items over 512 threads)
#pragma unroll
        for (int e = 0; e < 2; e++) {
            int idx = t + e * NTHREADS;
            int p = idx >> 5, k = idx & 31;
            int pp = p0 + p;
            float d = (pp < cnt) ? nd[pp] : 1.0f;
            float u = d - CSTEP * (float)k;
            float r = __expf(-GAMMA_ * u * u);
            unsigned short hb = f2bf(r);
            rbf_h[p * RSTU + k] = hb;
            rbf_l[p * RSTU + k] = f2bf(r - bf2f(hb));
        }
        __syncthreads();

        // h prefetch for this thread's 8 (pair, c0) elements
        float h00[4], h10[4];
#pragma unroll
        for (int r = 0; r < 4; r++) {
            int pA = p0 + lg * 4 + r, pB = pA + 16;
            bool vA = pA < cnt, vB = pB < cnt;
            int jA = vA ? nj[pA] : 0, jB = vB ? nj[pB] : 0;
            h00[r] = vA ? h[jA * FD + c0] : 0.f;
            h10[r] = vB ? h[jB * FD + c0] : 0.f;
        }

        // Phase A (MFMA, 6): u = b1 + rbf@W1 split; relu+split; gate mask.
        {
            f32x4 u00 = {bb0,bb0,bb0,bb0};
            f32x4 u10 = {bb0,bb0,bb0,bb0};
            short8v rh0 = *(const short8v*)(rbf_h + lr * RSTU + lg * 8);
            short8v rh1 = *(const short8v*)(rbf_h + (16+lr) * RSTU + lg * 8);
            short8v rl0 = *(const short8v*)(rbf_l + lr * RSTU + lg * 8);
            short8v rl1 = *(const short8v*)(rbf_l + (16+lr) * RSTU + lg * 8);
            u00 = MFMA_B16(rh0, w1h_r, u00, 0,0,0);
            u10 = MFMA_B16(rh1, w1h_r, u10, 0,0,0);
            u00 = MFMA_B16(rh0, w1l_r, u00, 0,0,0);
            u10 = MFMA_B16(rh1, w1l_r, u10, 0,0,0);
            u00 = MFMA_B16(rl0, w1h_r, u00, 0,0,0);
            u10 = MFMA_B16(rl1, w1h_r, u10, 0,0,0);
            // C/D: col=lane&15, row=(lane>>4)*4+reg  [verified]
            unsigned int mk = 0;
#pragma unroll
            for (int r = 0; r < 4; r++) {
                int pA = lg * 4 + r, pB = 16 + lg * 4 + r;
                float v; unsigned short hb;
                if (u00[r] > 0.f) mk |= 1u << r;
                if (u10[r] > 0.f) mk |= 1u << (4 + r);
                v = fmaxf(u00[r], 0.f); hb = f2bf(v);
                a1h[pA * TST + c0] = hb; a1l[pA * TST + c0] = f2bf(v - bf2f(hb));
                v = fmaxf(u10[r], 0.f); hb = f2bf(v);
                a1h[pB * TST + c0] = hb; a1l[pB * TST + c0] = f2bf(v - bf2f(hb));
            }
            mk_out = mk;
        }
        __syncthreads();

        // Phase B (MFMA, 24): filt = a1 @ W2 split; accumulate (filt+b2)*h_j.
        {
            f32x4 acc00 = {0.f,0.f,0.f,0.f};
            f32x4 acc10 = {0.f,0.f,0.f,0.f};
#pragma unroll
            for (int ks = 0; ks < 4; ks++) {
                int kb = ks * 32 + lg * 8;
                short8v ah0 = *(const short8v*)(a1h + (lr     ) * TST + kb);
                short8v ah1 = *(const short8v*)(a1h + (16 + lr) * TST + kb);
                short8v al0 = *(const short8v*)(a1l + (lr     ) * TST + kb);
                short8v al1 = *(const short8v*)(a1l + (16 + lr) * TST + kb);
                acc00 = MFMA_B16(ah0, w2f_h[ks], acc00, 0,0,0);
                acc10 = MFMA_B16(ah1, w2f_h[ks], acc10, 0,0,0);
                acc00 = MFMA_B16(ah0, w2f_l[ks], acc00, 0,0,0);
                acc10 = MFMA_B16(ah1, w2f_l[ks], acc10, 0,0,0);
                acc00 = MFMA_B16(al0, w2f_h[ks], acc00, 0,0,0);
                acc10 = MFMA_B16(al1, w2f_h[ks], acc10, 0,0,0);
            }
#pragma unroll
            for (int r = 0; r < 4; r++) {
                macc0 += (acc00[r] + b2c0) * h00[r] + (acc10[r] + b2c0) * h10[r];
            }
        }
        // (no trailing barrier — caller inserts one only between passes)
    };

    fwd_pass(0, mk0);
    if (cnt > PPF) { __syncthreads(); fwd_pass(PPF, mk1); }

    // R31: bwd weights into registers NOW — w2f regs dead, budget reused;
    // latency covered by m-reduce + mbar GEMVs.
    short8v w2b_h[4], w2b_l[4];
#pragma unroll
    for (int ks = 0; ks < 4; ks++) {
        int kb = ks * 32 + lg * 8;
        w2b_h[ks] = *(const short8v*)(w2bh + c0 * FD + kb);
        w2b_l[ks] = *(const short8v*)(w2bl + c0 * FD + kb);
    }

    // ---------------- m reduce -> LDS mrow ---------------------------------
    {
        float r0 = macc0 + __shfl_xor(macc0, 16, 64);
        r0 += __shfl_xor(r0, 32, 64);
        if (lg == 0) mrow[c0] = r0;        // 8 waves x 16 lr cover 0..127
    }
    __syncthreads();

    // ---------------- mbar: in-wave GEMVs (lg = f-quarter), 2 barriers -----
    {
        int f0h = lg * 32;
        float g = 0.f;
#pragma unroll
        for (int f4 = 0; f4 < 32; f4 += 4) {
            float4 w  = *(const float4*)(W3T + c0 * FD + f0h + f4);  // W3T[c][f]
            float4 mr = *(const float4*)(mrow + f0h + f4);
            g += mr.x*w.x + mr.y*w.y + mr.z*w.z + mr.w*w.w;
        }
        g += __shfl_xor(g, 16, 64);
        g += __shfl_xor(g, 32, 64);
        if (lg == 0) gb[c0] = (g > 0.f) ? wout[c0] : 0.f;
    }
    __syncthreads();
    {
        int f0h = lg * 32;
        float mb = 0.f;
#pragma unroll
        for (int f4 = 0; f4 < 32; f4 += 4) {
            float4 w  = *(const float4*)(W3 + c0 * FD + f0h + f4);   // W3[c][f]
            float4 gv = *(const float4*)(gb + f0h + f4);
            mb += gv.x*w.x + gv.y*w.y + gv.z*w.z + gv.w*w.w;
        }
        mb += __shfl_xor(mb, 16, 64);
        mb += __shfl_xor(mb, 32, 64);
        if (lg == 0) mbrow[c0] = mb;
    }
    __syncthreads();

    // ---------------- bwd passes -------------------------------------------
    float iax = 0.f, iay = 0.f, iaz = 0.f;       // i-side force accumulator

    auto bwd_pass = [&](int p0, unsigned int mk, bool first) {
        // crbf staging (1024 items)
#pragma unroll
        for (int e = 0; e < 2; e++) {
            int idx = t + e * NTHREADS;
            int p = idx >> 5, k = idx & 31;
            int pp = p0 + p;
            float d = (pp < cnt) ? nd[pp] : 1.0f;
            float u = d - CSTEP * (float)k;
            float r = __expf(-GAMMA_ * u * u);
            float cd = -2.f * GAMMA_ * u * r;
            unsigned short hc = f2bf(cd);
            crbf_h[p * RSTU + k] = hc;
            crbf_l[p * RSTU + k] = f2bf(cd - bf2f(hc));
        }
        // ts fill: ts[p][c] = mbrow[c] * h[j_p][c]  (pass-0 h prefetched)
#pragma unroll
        for (int e = 0; e < 2; e++) {
            int idx = t + e * NTHREADS;
            int p = idx >> 5, c4g = (idx & 31) * 4;
            int pp = p0 + p;
            ushort4 hv = {0,0,0,0}, lv = {0,0,0,0};
            if (pp < cnt) {
                float4 mb4 = *(const float4*)(mbrow + c4g);
                float4 hj4 = first ? hj0[e]
                                   : *(const float4*)(h + nj[pp] * FD + c4g);
                float v0 = mb4.x*hj4.x, v1 = mb4.y*hj4.y;
                float v2 = mb4.z*hj4.z, v3 = mb4.w*hj4.w;
                hv.x = f2bf(v0); lv.x = f2bf(v0 - bf2f(hv.x));
                hv.y = f2bf(v1); lv.y = f2bf(v1 - bf2f(hv.y));
                hv.z = f2bf(v2); lv.z = f2bf(v2 - bf2f(hv.z));
                hv.w = f2bf(v3); lv.w = f2bf(v3 - bf2f(hv.w));
            }
            *(ushort4*)(ts_h + p * TST + c4g) = hv;
            *(ushort4*)(ts_l + p * TST + c4g) = lv;
        }
        __syncthreads();                   // crbf + ts ready

        // gef (6 MFMA, in registers): ef = crbf@W1 split; gate via mask.
        f32x4 e00 = {0.f,0.f,0.f,0.f};
        f32x4 e10 = {0.f,0.f,0.f,0.f};
        {
            short8v ch0 = *(const short8v*)(crbf_h + lr * RSTU + lg * 8);
            short8v ch1 = *(const short8v*)(crbf_h + (16+lr) * RSTU + lg * 8);
            short8v cl0 = *(const short8v*)(crbf_l + lr * RSTU + lg * 8);
            short8v cl1 = *(const short8v*)(crbf_l + (16+lr) * RSTU + lg * 8);
            e00 = MFMA_B16(ch0, w1h_r, e00, 0,0,0);
            e10 = MFMA_B16(ch1, w1h_r, e10, 0,0,0);
            e00 = MFMA_B16(ch0, w1l_r, e00, 0,0,0);
            e10 = MFMA_B16(ch1, w1l_r, e10, 0,0,0);
            e00 = MFMA_B16(cl0, w1h_r, e00, 0,0,0);
            e10 = MFMA_B16(cl1, w1h_r, e10, 0,0,0);
        }
#pragma unroll
        for (int r = 0; r < 4; r++) {
            e00[r] = (mk & (1u <<  r      )) ? e00[r] : 0.f;
            e10[r] = (mk & (1u << (4 + r))) ? e10[r] : 0.f;
        }

        // GEMM (24 MFMA): du1 = ts @ W2T (register B operands).
        f32x4 acc00 = {0.f,0.f,0.f,0.f};
        f32x4 acc10 = {0.f,0.f,0.f,0.f};
#pragma unroll
        for (int ks = 0; ks < 4; ks++) {
            int kb = ks * 32 + lg * 8;
            short8v ah0 = *(const short8v*)(ts_h + (lr     ) * TST + kb);
            short8v ah1 = *(const short8v*)(ts_h + (16 + lr) * TST + kb);
            short8v al0 = *(const short8v*)(ts_l + (lr     ) * TST + kb);
            short8v al1 = *(const short8v*)(ts_l + (16 + lr) * TST + kb);
            acc00 = MFMA_B16(ah0, w2b_h[ks], acc00, 0,0,0);
            acc10 = MFMA_B16(ah1, w2b_h[ks], acc10, 0,0,0);
            acc00 = MFMA_B16(ah0, w2b_l[ks], acc00, 0,0,0);
            acc10 = MFMA_B16(ah1, w2b_l[ks], acc10, 0,0,0);
            acc00 = MFMA_B16(al0, w2b_h[ks], acc00, 0,0,0);
            acc10 = MFMA_B16(al1, w2b_h[ks], acc10, 0,0,0);
        }

        // Fold gef, reduce over the 16 col-lanes, stash per wave.
        float part8[8];
#pragma unroll
        for (int r = 0; r < 4; r++) {
            part8[r]     = acc00[r] * e00[r];
            part8[4 + r] = acc10[r] * e10[r];
        }
#pragma unroll
        for (int mask = 1; mask < 16; mask <<= 1) {
#pragma unroll
            for (int e = 0; e < 8; e++) part8[e] += __shfl_xor(part8[e], mask, 64);
        }
        if (lr == 0) {
#pragma unroll
            for (int r = 0; r < 4; r++) {
                sred[wid * PPF + lg * 4 + r]      = part8[r];
                sred[wid * PPF + 16 + lg * 4 + r] = part8[4 + r];
            }
        }
        __syncthreads();

        // Scatter this pass's pairs: i-side into registers, j-side atomic.
        if (t < PPF && p0 + t < cnt) {
            float s = 0.f;
#pragma unroll
            for (int w = 0; w < 8; w++) s += sred[w * PPF + t];
            int pp = p0 + t;
            float coef = s / nd[pp];
            float fx = coef * ndx[pp];
            float fy = coef * ndy[pp];
            float fz = coef * ndz[pp];
            iax += fx; iay += fy; iaz += fz;
            atomicAdd(f_acc + nj[pp]*3 + 0, fx);
            atomicAdd(f_acc + nj[pp]*3 + 1, fy);
            atomicAdd(f_acc + nj[pp]*3 + 2, fz);
        }
        // (no trailing barrier — caller inserts one only between passes)
    };

    bwd_pass(0, mk0, true);
    if (cnt > PPF) { __syncthreads(); bwd_pass(PPF, mk1, false); }

    // i-side reduce across scatter lanes (t<32 = lanes 0..31 of wave 0),
    // then 3 atomics per block.
    if (t < PPF) {
#pragma unroll
        for (int mask = 1; mask < 32; mask <<= 1) {
            iax += __shfl_xor(iax, mask, 64);
            iay += __shfl_xor(iay, mask, 64);
            iaz += __shfl_xor(iaz, mask, 64);
        }
        if (t == 0) {
            atomicAdd(f_acc + i*3 + 0, -iax);
            atomicAdd(f_acc + i*3 + 1, -iay);
            atomicAdd(f_acc + i*3 + 2, -iaz);
        }
    }
}

// ---------------------------------------------------------------- finalize
__global__ __launch_bounds__(256) void fin_kernel(
    const float* __restrict__ v, const float* __restrict__ mass,
    const float* __restrict__ p_eta, const float* __restrict__ f_acc,
    float* __restrict__ out)
{
    __shared__ float red[256];
    int t = threadIdx.x;
    float ke = 0.f;
    float c = p_eta[0] / Q0_F;
    for (int idx = t; idx < 3 * N_ATOMS; idx += 256) {
        int a = idx / 3;
        float vv = v[idx], mi = mass[a];
        out[DVDT_OFF + idx] = (f_acc[idx] - c * vv * mi) / mi;
        out[V_OFF + idx] = vv;
        ke += 0.5f * mi * vv * vv;
    }
    red[t] = ke;
    __syncthreads();
    for (int s = 128; s > 0; s >>= 1) {
        if (t < s) red[t] += red[t + s];
        __syncthreads();
    }
    if (t == 0) {
        float k0 = red[0];
        float e0 = p_eta[0], e1 = p_eta[1], e2 = p_eta[2], e3 = p_eta[3];
        out[PETA_OFF + 0] = 2.f * (k0 - TARGET_KE) - e0 * e1 / QI_F;
        out[PETA_OFF + 1] = e0 * e0 / Q0_F - KT_F - e1 * e2 / QI_F;
        out[PETA_OFF + 2] = e1 * e1 / QI_F - KT_F - e2 * e3 / QI_F;
        out[PETA_OFF + 3] = e2 * e2 / QI_F - KT_F;
    }
}

// ---------------------------------------------------------------- launch
extern "C" void kernel_launch(void* const* d_in, const int* in_sizes, int n_in,
                              void* d_out, int out_size, void* d_ws, size_t ws_size,
                              hipStream_t stream)
{
    const float* v     = (const float*)d_in[0];
    const float* q     = (const float*)d_in[1];
    const float* p_eta = (const float*)d_in[2];
    const float* mass  = (const float*)d_in[3];
    const float* embed = (const float*)d_in[4];
    const float* W1    = (const float*)d_in[5];
    const float* b1    = (const float*)d_in[6];
    const float* W2    = (const float*)d_in[7];
    const float* b2    = (const float*)d_in[8];
    const float* W3    = (const float*)d_in[9];
    const float* wout  = (const float*)d_in[10];
    const int*   z     = (const int*)d_in[11];
    float* out = (float*)d_out;

    float* h     = (float*)d_ws;                    // 98304
    float* W3T   = h + N_ATOMS * FD;                // 16384
    float* f_acc = W3T + FD * FD;                   // 2304
    unsigned short* w2bh = (unsigned short*)(f_acc + 3 * N_ATOMS);
    unsigned short* w2bl = w2bh + FD * FD;
    unsigned short* w2fh = w2bl + FD * FD;
    unsigned short* w2fl = w2fh + FD * FD;
    unsigned short* w1fh = w2fl + FD * FD;
    unsigned short* w1fl = w1fh + NRBF * FD;

    prep_kernel<<<384, 256, 0, stream>>>(z, embed, W1, W2, W3, h, W3T,
                                         w1fh, w1fl, w2fh, w2fl, w2bh, w2bl,
                                         f_acc);
    atom_kernel<<<N_ATOMS, NTHREADS, 0, stream>>>(q, w1fh, w1fl, b1, w2fh, w2fl,
                                                  w2bh, w2bl, b2, h, W3, W3T, wout,
                                                  f_acc);
    fin_kernel<<<1, 256, 0, stream>>>(v, mass, p_eta, f_acc, out);
}

// Round 15
// 126.993 us; speedup vs baseline: 1.1593x; 1.0064x over previous
//
#include <hip/hip_runtime.h>
#include <math.h>

// Problem constants (match reference)
#define N_ATOMS 768
#define FD 128          // feature width
#define NRBF 32
#define MAXN 64         // per-atom neighbor cap (mean ~26)
#define NTHREADS 512    // 8 waves/block
#define TST 136         // padded LDS stride for [*][128] bf16 (ushort) tiles
#define RSTU 40         // padded ushort stride for [*][32] bf16 rbf tiles (80B, 16B-aligned)

constexpr float  CUT2   = 25.0f;
constexpr float  GAMMA_ = 40.96f;            // 1/(5/32)^2
constexpr float  CSTEP  = 5.0f / 31.0f;      // linspace(0,5,32) step
constexpr double KB_D   = 8.617330337217213e-05;
constexpr double KT_D   = 300.0 * KB_D;
constexpr float  KT_F   = (float)KT_D;
constexpr float  TARGET_KE = (float)(0.5 * 2304.0 * KT_D);
constexpr float  Q0_F   = (float)(2.0 * 2304.0 * KT_D * 400.0);  // Q[0]
constexpr float  QI_F   = (float)(2.0 * KT_D * 400.0);           // Q[1..3]

#define DVDT_OFF 0
#define V_OFF    (3 * N_ATOMS)
#define PETA_OFF (6 * N_ATOMS)

using short8v = __attribute__((ext_vector_type(8))) short;
using f32x4   = __attribute__((ext_vector_type(4))) float;

#define MFMA_B16 __builtin_amdgcn_mfma_f32_16x16x32_bf16

__device__ __forceinline__ unsigned short f2bf(float x) {
    unsigned int u = __float_as_uint(x);
    u += 0x7FFF + ((u >> 16) & 1);           // round-to-nearest-even
    return (unsigned short)(u >> 16);
}
__device__ __forceinline__ float bf2f(unsigned short h) {
    return __uint_as_float(((unsigned int)h) << 16);
}

// Hard-won rules (31 rounds of counters):
// 1. NO __launch_bounds__ min-wave hints on GEMM kernels (spill cliff).
// 2. NEVER put __threadfence / completion counters on the hot grid (R14).
// 3. R22-R24 WIN: MFMA split-bf16 (AhBh+AhBl+AlBh, err ~2^-17) for all dense
//    phases. Layouts: bwd w2b native; fwd w2f[c][k]=W2[k][c];
//    w1f[c][k]=W1[k][c]. C/D: col=lane&15, row=(lane>>4)*4+reg (verified).
// 4. R26 REGRESSED: multiplying atomics in fused epilogues.
// 5. R28 WIN (-9.8us): fwd+mbar+bwd fused per-atom megakernel, 3 dispatches.
// 6. R29-R31 ~NULL: waves x2, LDS /2, barriers -4, weights->regs each <=2%.
//    Ledger model: dur ~ 80us harness restore-fills + our kernels; atom
//    (~50us) is the whole controllable budget and is STRAGGLER-bound
//    (cnt>32 blocks run the barrier chain twice; duration = max block path).
// 7. R32: single flattened phase chain for up to 64 pairs (4 M-tiles/wave);
//    extra tiles under block-uniform branches (cnt uniform -> no divergence;
//    light blocks skip tiles 2-3 entirely -> no NaN from unstaged LDS).
//    Straggler path 16 -> 9 barrier-phases.

// ---------------------------------------------------------------- prep (fill only)
__global__ __launch_bounds__(256) void prep_kernel(
    const int* __restrict__ z, const float* __restrict__ embed,
    const float* __restrict__ W1, const float* __restrict__ W2,
    const float* __restrict__ W3,
    float* __restrict__ h, float* __restrict__ W3T,
    unsigned short* __restrict__ w1fh, unsigned short* __restrict__ w1fl,
    unsigned short* __restrict__ w2fh, unsigned short* __restrict__ w2fl,
    unsigned short* __restrict__ w2bh, unsigned short* __restrict__ w2bl,
    float* __restrict__ f_acc)
{
    int g = blockIdx.x * 256 + threadIdx.x;      // 98304 ids (384 blocks)
    if (g < N_ATOMS * FD) h[g] = embed[z[g >> 7] * FD + (g & 127)];
    if (g < FD * FD) {
        int r = g >> 7, c = g & 127;
        float w = W2[g];                         // W2[r][c]
        unsigned short hb = f2bf(w);
        unsigned short lb = f2bf(w - bf2f(hb));
        w2bh[g] = hb;                            // bwd B: native layout
        w2bl[g] = lb;
        w2fh[c * FD + r] = hb;                   // fwd B: w2f[c][k]=W2[k][c]
        w2fl[c * FD + r] = lb;
        W3T[c * FD + r] = W3[g];
        if (g < NRBF * FD) {                     // W1: NRBF x FD (r=k)
            float w1v = W1[g];
            unsigned short h1 = f2bf(w1v);
            w1fh[c * NRBF + r] = h1;             // [c][k], k contiguous
            w1fl[c * NRBF + r] = f2bf(w1v - bf2f(h1));
        }
    }
    if (g < 3 * N_ATOMS) f_acc[g] = 0.f;
}

// ---------------------------------------------------------------- atom (768 blocks x 512)
// Flattened single phase chain for up to MAXN=64 pairs.
__global__ __launch_bounds__(NTHREADS) void atom_kernel(
    const float* __restrict__ q,
    const unsigned short* __restrict__ w1fh, const unsigned short* __restrict__ w1fl,
    const float* __restrict__ b1,
    const unsigned short* __restrict__ w2fh, const unsigned short* __restrict__ w2fl,
    const unsigned short* __restrict__ w2bh, const unsigned short* __restrict__ w2bl,
    const float* __restrict__ b2, const float* __restrict__ h,
    const float* __restrict__ W3, const float* __restrict__ W3T,
    const float* __restrict__ wout,
    float* __restrict__ f_acc)
{
    __shared__ int   nj[MAXN];
    __shared__ float nd[MAXN], ndx[MAXN], ndy[MAXN], ndz[MAXN];
    __shared__ int   cnt_s;
    // Overlaid pools: fwd {rbf,a1} and bwd {crbf,ts} are temporally disjoint.
    __shared__ __align__(16) unsigned short poolR[2 * MAXN * RSTU];  // 10240 B
    __shared__ __align__(16) unsigned short poolA[2 * MAXN * TST];   // 34816 B
    __shared__ float mrow[FD], gb[FD], mbrow[FD];                    // 1536 B
    __shared__ float sred[8 * MAXN];                                 // 2048 B
    // total ~50.2 KB

    unsigned short* rbf_h  = poolR;
    unsigned short* rbf_l  = poolR + MAXN * RSTU;
    unsigned short* crbf_h = poolR;                // overlay (bwd)
    unsigned short* crbf_l = poolR + MAXN * RSTU;
    unsigned short* a1h  = poolA;
    unsigned short* a1l  = poolA + MAXN * TST;
    unsigned short* ts_h = poolA;                  // overlay (bwd)
    unsigned short* ts_l = poolA + MAXN * TST;

    int i = blockIdx.x, t = threadIdx.x;
    int wid = t >> 6, lane = t & 63;             // wid 0..7
    int lr = lane & 15, lg = lane >> 4;
    int c0 = wid * 16 + lr;                      // this wave's single col-tile

    if (t == 0) cnt_s = 0;
    __syncthreads();

    // Block-invariant fwd weights into registers — latency covered by the
    // neighbor-build loop below (R31).
    short8v w1h_r = *(const short8v*)(w1fh + c0 * NRBF + lg * 8);
    short8v w1l_r = *(const short8v*)(w1fl + c0 * NRBF + lg * 8);
    short8v w2f_h[4], w2f_l[4];
#pragma unroll
    for (int ks = 0; ks < 4; ks++) {
        int kb = ks * 32 + lg * 8;
        w2f_h[ks] = *(const short8v*)(w2fh + c0 * FD + kb);
        w2f_l[ks] = *(const short8v*)(w2fl + c0 * FD + kb);
    }
    float bb0  = b1[c0];
    float b2c0 = b2[c0];

    float qx = q[i*3], qy = q[i*3+1], qz = q[i*3+2];
    for (int j = t; j < N_ATOMS; j += NTHREADS) {
        if (j == i) continue;
        float dx = qx - q[j*3], dy = qy - q[j*3+1], dz = qz - q[j*3+2];
        float d2 = dx*dx + dy*dy + dz*dz;
        if (d2 < CUT2) {
            int p = atomicAdd(&cnt_s, 1);
            if (p < MAXN) { nj[p] = j; nd[p] = sqrtf(d2);
                            ndx[p] = dx; ndy[p] = dy; ndz[p] = dz; }
        }
    }
    __syncthreads();
    int cnt = min(cnt_s, MAXN);
    if (cnt == 0) return;                        // no pairs, no forces
    bool heavy = cnt > 32;                       // block-uniform

    float macc0 = 0.f;                           // m[i][c0] partial
    unsigned int mk = 0;                         // relu gate mask (16b: 4 tiles)

    // T14 prefetch: ts-fill h gathers for rows 0-31 issued NOW; latency
    // hides under the entire fwd + mbar section.
    float4 hj0[2];
#pragma unroll
    for (int e = 0; e < 2; e++) {
        int idx = t + e * NTHREADS;
        int p = idx >> 5, c4g = (idx & 31) * 4;
        hj0[e] = (p < cnt) ? *(const float4*)(h + nj[p] * FD + c4g)
                           : make_float4(0.f, 0.f, 0.f, 0.f);
    }

    // ---------------- rbf staging (all pairs at once) ----------------------
    {
        int nit = heavy ? 4 : 2;                 // 2048 or 1024 items
        for (int e = 0; e < nit; e++) {
            int idx = t + e * NTHREADS;
            int p = idx >> 5, k = idx & 31;
            float d = (p < cnt) ? nd[p] : 1.0f;
            float u = d - CSTEP * (float)k;
            float r = __expf(-GAMMA_ * u * u);
            unsigned short hb = f2bf(r);
            rbf_h[p * RSTU + k] = hb;
            rbf_l[p * RSTU + k] = f2bf(r - bf2f(hb));
        }
    }
    __syncthreads();

    // h prefetch for phase-B epilogue (tiles 0-1 always, 2-3 if heavy)
    float h00[4], h10[4], h20[4], h30[4];
#pragma unroll
    for (int r = 0; r < 4; r++) {
        int pA = lg * 4 + r, pB = pA + 16;
        bool vA = pA < cnt, vB = pB < cnt;
        h00[r] = vA ? h[nj[pA] * FD + c0] : 0.f;
        h10[r] = vB ? h[nj[pB] * FD + c0] : 0.f;
        h20[r] = 0.f; h30[r] = 0.f;
    }
    if (heavy) {
#pragma unroll
        for (int r = 0; r < 4; r++) {
            int pC = 32 + lg * 4 + r, pD = pC + 16;
            bool vC = pC < cnt, vD = pD < cnt;
            h20[r] = vC ? h[nj[pC] * FD + c0] : 0.f;
            h30[r] = vD ? h[nj[pD] * FD + c0] : 0.f;
        }
    }

    // ---------------- Phase A: u = b1 + rbf@W1 (split); relu; gate mask ----
    {
        f32x4 u00 = {bb0,bb0,bb0,bb0};
        f32x4 u10 = {bb0,bb0,bb0,bb0};
        short8v rh0 = *(const short8v*)(rbf_h + lr * RSTU + lg * 8);
        short8v rh1 = *(const short8v*)(rbf_h + (16+lr) * RSTU + lg * 8);
        short8v rl0 = *(const short8v*)(rbf_l + lr * RSTU + lg * 8);
        short8v rl1 = *(const short8v*)(rbf_l + (16+lr) * RSTU + lg * 8);
        u00 = MFMA_B16(rh0, w1h_r, u00, 0,0,0);
        u10 = MFMA_B16(rh1, w1h_r, u10, 0,0,0);
        u00 = MFMA_B16(rh0, w1l_r, u00, 0,0,0);
        u10 = MFMA_B16(rh1, w1l_r, u10, 0,0,0);
        u00 = MFMA_B16(rl0, w1h_r, u00, 0,0,0);
        u10 = MFMA_B16(rl1, w1h_r, u10, 0,0,0);
        // C/D: col=lane&15, row=(lane>>4)*4+reg  [verified]
#pragma unroll
        for (int r = 0; r < 4; r++) {
            int pA = lg * 4 + r, pB = 16 + lg * 4 + r;
            float v; unsigned short hb;
            if (u00[r] > 0.f) mk |= 1u << r;
            if (u10[r] > 0.f) mk |= 1u << (4 + r);
            v = fmaxf(u00[r], 0.f); hb = f2bf(v);
            a1h[pA * TST + c0] = hb; a1l[pA * TST + c0] = f2bf(v - bf2f(hb));
            v = fmaxf(u10[r], 0.f); hb = f2bf(v);
            a1h[pB * TST + c0] = hb; a1l[pB * TST + c0] = f2bf(v - bf2f(hb));
        }
        if (heavy) {
            f32x4 u20 = {bb0,bb0,bb0,bb0};
            f32x4 u30 = {bb0,bb0,bb0,bb0};
            short8v rh2 = *(const short8v*)(rbf_h + (32+lr) * RSTU + lg * 8);
            short8v rh3 = *(const short8v*)(rbf_h + (48+lr) * RSTU + lg * 8);
            short8v rl2 = *(const short8v*)(rbf_l + (32+lr) * RSTU + lg * 8);
            short8v rl3 = *(const short8v*)(rbf_l + (48+lr) * RSTU + lg * 8);
            u20 = MFMA_B16(rh2, w1h_r, u20, 0,0,0);
            u30 = MFMA_B16(rh3, w1h_r, u30, 0,0,0);
            u20 = MFMA_B16(rh2, w1l_r, u20, 0,0,0);
            u30 = MFMA_B16(rh3, w1l_r, u30, 0,0,0);
            u20 = MFMA_B16(rl2, w1h_r, u20, 0,0,0);
            u30 = MFMA_B16(rl3, w1h_r, u30, 0,0,0);
#pragma unroll
            for (int r = 0; r < 4; r++) {
                int pC = 32 + lg * 4 + r, pD = 48 + lg * 4 + r;
                float v; unsigned short hb;
                if (u20[r] > 0.f) mk |= 1u << (8 + r);
                if (u30[r] > 0.f) mk |= 1u << (12 + r);
                v = fmaxf(u20[r], 0.f); hb = f2bf(v);
                a1h[pC * TST + c0] = hb; a1l[pC * TST + c0] = f2bf(v - bf2f(hb));
                v = fmaxf(u30[r], 0.f); hb = f2bf(v);
                a1h[pD * TST + c0] = hb; a1l[pD * TST + c0] = f2bf(v - bf2f(hb));
            }
        }
    }
    __syncthreads();

    // ---------------- Phase B: filt = a1 @ W2 (split); accumulate m --------
    {
        f32x4 acc00 = {0.f,0.f,0.f,0.f};
        f32x4 acc10 = {0.f,0.f,0.f,0.f};
#pragma unroll
        for (int ks = 0; ks < 4; ks++) {
            int kb = ks * 32 + lg * 8;
            short8v ah0 = *(const short8v*)(a1h + (lr     ) * TST + kb);
            short8v ah1 = *(const short8v*)(a1h + (16 + lr) * TST + kb);
            short8v al0 = *(const short8v*)(a1l + (lr     ) * TST + kb);
            short8v al1 = *(const short8v*)(a1l + (16 + lr) * TST + kb);
            acc00 = MFMA_B16(ah0, w2f_h[ks], acc00, 0,0,0);
            acc10 = MFMA_B16(ah1, w2f_h[ks], acc10, 0,0,0);
            acc00 = MFMA_B16(ah0, w2f_l[ks], acc00, 0,0,0);
            acc10 = MFMA_B16(ah1, w2f_l[ks], acc10, 0,0,0);
            acc00 = MFMA_B16(al0, w2f_h[ks], acc00, 0,0,0);
            acc10 = MFMA_B16(al1, w2f_h[ks], acc10, 0,0,0);
        }
#pragma unroll
        for (int r = 0; r < 4; r++) {
            macc0 += (acc00[r] + b2c0) * h00[r] + (acc10[r] + b2c0) * h10[r];
        }
        if (heavy) {
            f32x4 acc20 = {0.f,0.f,0.f,0.f};
            f32x4 acc30 = {0.f,0.f,0.f,0.f};
#pragma unroll
            for (int ks = 0; ks < 4; ks++) {
                int kb = ks * 32 + lg * 8;
                short8v ah2 = *(const short8v*)(a1h + (32 + lr) * TST + kb);
                short8v ah3 = *(const short8v*)(a1h + (48 + lr) * TST + kb);
                short8v al2 = *(const short8v*)(a1l + (32 + lr) * TST + kb);
                short8v al3 = *(const short8v*)(a1l + (48 + lr) * TST + kb);
                acc20 = MFMA_B16(ah2, w2f_h[ks], acc20, 0,0,0);
                acc30 = MFMA_B16(ah3, w2f_h[ks], acc30, 0,0,0);
                acc20 = MFMA_B16(ah2, w2f_l[ks], acc20, 0,0,0);
                acc30 = MFMA_B16(ah3, w2f_l[ks], acc30, 0,0,0);
                acc20 = MFMA_B16(al2, w2f_h[ks], acc20, 0,0,0);
                acc30 = MFMA_B16(al3, w2f_h[ks], acc30, 0,0,0);
            }
#pragma unroll
            for (int r = 0; r < 4; r++) {
                macc0 += (acc20[r] + b2c0) * h20[r] + (acc30[r] + b2c0) * h30[r];
            }
        }
    }

    // R31: bwd weights into registers NOW — latency covered by m-reduce+mbar.
    short8v w2b_h[4], w2b_l[4];
#pragma unroll
    for (int ks = 0; ks < 4; ks++) {
        int kb = ks * 32 + lg * 8;
        w2b_h[ks] = *(const short8v*)(w2bh + c0 * FD + kb);
        w2b_l[ks] = *(const short8v*)(w2bl + c0 * FD + kb);
    }

    // ---------------- m reduce -> LDS mrow ---------------------------------
    {
        float r0 = macc0 + __shfl_xor(macc0, 16, 64);
        r0 += __shfl_xor(r0, 32, 64);
        if (lg == 0) mrow[c0] = r0;        // 8 waves x 16 lr cover 0..127
    }
    __syncthreads();

    // ---------------- mbar: in-wave GEMVs (lg = f-quarter) -----------------
    {
        int f0h = lg * 32;
        float g = 0.f;
#pragma unroll
        for (int f4 = 0; f4 < 32; f4 += 4) {
            float4 w  = *(const float4*)(W3T + c0 * FD + f0h + f4);  // W3T[c][f]
            float4 mr = *(const float4*)(mrow + f0h + f4);
            g += mr.x*w.x + mr.y*w.y + mr.z*w.z + mr.w*w.w;
        }
        g += __shfl_xor(g, 16, 64);
        g += __shfl_xor(g, 32, 64);
        if (lg == 0) gb[c0] = (g > 0.f) ? wout[c0] : 0.f;
    }
    __syncthreads();
    {
        int f0h = lg * 32;
        float mb = 0.f;
#pragma unroll
        for (int f4 = 0; f4 < 32; f4 += 4) {
            float4 w  = *(const float4*)(W3 + c0 * FD + f0h + f4);   // W3[c][f]
            float4 gv = *(const float4*)(gb + f0h + f4);
            mb += gv.x*w.x + gv.y*w.y + gv.z*w.z + gv.w*w.w;
        }
        mb += __shfl_xor(mb, 16, 64);
        mb += __shfl_xor(mb, 32, 64);
        if (lg == 0) mbrow[c0] = mb;
    }
    __syncthreads();

    // ---------------- bwd: crbf + ts staging (all pairs) -------------------
    {
        int nit = heavy ? 4 : 2;
        for (int e = 0; e < nit; e++) {
            int idx = t + e * NTHREADS;
            int p = idx >> 5, k = idx & 31;
            float d = (p < cnt) ? nd[p] : 1.0f;
            float u = d - CSTEP * (float)k;
            float r = __expf(-GAMMA_ * u * u);
            float cd = -2.f * GAMMA_ * u * r;
            unsigned short hc = f2bf(cd);
            crbf_h[p * RSTU + k] = hc;
            crbf_l[p * RSTU + k] = f2bf(cd - bf2f(hc));
        }
        for (int e = 0; e < nit; e++) {
            int idx = t + e * NTHREADS;
            int p = idx >> 5, c4g = (idx & 31) * 4;
            ushort4 hv = {0,0,0,0}, lv = {0,0,0,0};
            if (p < cnt) {
                float4 mb4 = *(const float4*)(mbrow + c4g);
                float4 hj4 = (e < 2) ? hj0[e]
                                     : *(const float4*)(h + nj[p] * FD + c4g);
                float v0 = mb4.x*hj4.x, v1 = mb4.y*hj4.y;
                float v2 = mb4.z*hj4.z, v3 = mb4.w*hj4.w;
                hv.x = f2bf(v0); lv.x = f2bf(v0 - bf2f(hv.x));
                hv.y = f2bf(v1); lv.y = f2bf(v1 - bf2f(hv.y));
                hv.z = f2bf(v2); lv.z = f2bf(v2 - bf2f(hv.z));
                hv.w = f2bf(v3); lv.w = f2bf(v3 - bf2f(hv.w));
            }
            *(ushort4*)(ts_h + p * TST + c4g) = hv;
            *(ushort4*)(ts_l + p * TST + c4g) = lv;
        }
    }
    __syncthreads();                       // crbf + ts ready

    // ---------------- bwd: gef + GEMM + fold + reduce ----------------------
    {
        // gef: ef = crbf@W1 split; gate via mask.
        f32x4 e00 = {0.f,0.f,0.f,0.f};
        f32x4 e10 = {0.f,0.f,0.f,0.f};
        {
            short8v ch0 = *(const short8v*)(crbf_h + lr * RSTU + lg * 8);
            short8v ch1 = *(const short8v*)(crbf_h + (16+lr) * RSTU + lg * 8);
            short8v cl0 = *(const short8v*)(crbf_l + lr * RSTU + lg * 8);
            short8v cl1 = *(const short8v*)(crbf_l + (16+lr) * RSTU + lg * 8);
            e00 = MFMA_B16(ch0, w1h_r, e00, 0,0,0);
            e10 = MFMA_B16(ch1, w1h_r, e10, 0,0,0);
            e00 = MFMA_B16(ch0, w1l_r, e00, 0,0,0);
            e10 = MFMA_B16(ch1, w1l_r, e10, 0,0,0);
            e00 = MFMA_B16(cl0, w1h_r, e00, 0,0,0);
            e10 = MFMA_B16(cl1, w1h_r, e10, 0,0,0);
        }
#pragma unroll
        for (int r = 0; r < 4; r++) {
            e00[r] = (mk & (1u <<  r      )) ? e00[r] : 0.f;
            e10[r] = (mk & (1u << (4 + r))) ? e10[r] : 0.f;
        }

        // GEMM tiles 0-1: du1 = ts @ W2T (register B operands).
        f32x4 acc00 = {0.f,0.f,0.f,0.f};
        f32x4 acc10 = {0.f,0.f,0.f,0.f};
#pragma unroll
        for (int ks = 0; ks < 4; ks++) {
            int kb = ks * 32 + lg * 8;
            short8v ah0 = *(const short8v*)(ts_h + (lr     ) * TST + kb);
            short8v ah1 = *(const short8v*)(ts_h + (16 + lr) * TST + kb);
            short8v al0 = *(const short8v*)(ts_l + (lr     ) * TST + kb);
            short8v al1 = *(const short8v*)(ts_l + (16 + lr) * TST + kb);
            acc00 = MFMA_B16(ah0, w2b_h[ks], acc00, 0,0,0);
            acc10 = MFMA_B16(ah1, w2b_h[ks], acc10, 0,0,0);
            acc00 = MFMA_B16(ah0, w2b_l[ks], acc00, 0,0,0);
            acc10 = MFMA_B16(ah1, w2b_l[ks], acc10, 0,0,0);
            acc00 = MFMA_B16(al0, w2b_h[ks], acc00, 0,0,0);
            acc10 = MFMA_B16(al1, w2b_h[ks], acc10, 0,0,0);
        }

        float part8[8];
#pragma unroll
        for (int r = 0; r < 4; r++) {
            part8[r]     = acc00[r] * e00[r];
            part8[4 + r] = acc10[r] * e10[r];
        }
#pragma unroll
        for (int mask = 1; mask < 16; mask <<= 1) {
#pragma unroll
            for (int e = 0; e < 8; e++) part8[e] += __shfl_xor(part8[e], mask, 64);
        }
        if (lr == 0) {
#pragma unroll
            for (int r = 0; r < 4; r++) {
                sred[wid * MAXN + lg * 4 + r]      = part8[r];
                sred[wid * MAXN + 16 + lg * 4 + r] = part8[4 + r];
            }
        }

        if (heavy) {                        // tiles 2-3 (block-uniform)
            f32x4 e20 = {0.f,0.f,0.f,0.f};
            f32x4 e30 = {0.f,0.f,0.f,0.f};
            {
                short8v ch2 = *(const short8v*)(crbf_h + (32+lr) * RSTU + lg * 8);
                short8v ch3 = *(const short8v*)(crbf_h + (48+lr) * RSTU + lg * 8);
                short8v cl2 = *(const short8v*)(crbf_l + (32+lr) * RSTU + lg * 8);
                short8v cl3 = *(const short8v*)(crbf_l + (48+lr) * RSTU + lg * 8);
                e20 = MFMA_B16(ch2, w1h_r, e20, 0,0,0);
                e30 = MFMA_B16(ch3, w1h_r, e30, 0,0,0);
                e20 = MFMA_B16(ch2, w1l_r, e20, 0,0,0);
                e30 = MFMA_B16(ch3, w1l_r, e30, 0,0,0);
                e20 = MFMA_B16(cl2, w1h_r, e20, 0,0,0);
                e30 = MFMA_B16(cl3, w1h_r, e30, 0,0,0);
            }
#pragma unroll
            for (int r = 0; r < 4; r++) {
                e20[r] = (mk & (1u << (8 + r)))  ? e20[r] : 0.f;
                e30[r] = (mk & (1u << (12 + r))) ? e30[r] : 0.f;
            }
            f32x4 acc20 = {0.f,0.f,0.f,0.f};
            f32x4 acc30 = {0.f,0.f,0.f,0.f};
#pragma unroll
            for (int ks = 0; ks < 4; ks++) {
                int kb = ks * 32 + lg * 8;
                short8v ah2 = *(const short8v*)(ts_h + (32 + lr) * TST + kb);
                short8v ah3 = *(const short8v*)(ts_h + (48 + lr) * TST + kb);
                short8v al2 = *(const short8v*)(ts_l + (32 + lr) * TST + kb);
                short8v al3 = *(const short8v*)(ts_l + (48 + lr) * TST + kb);
                acc20 = MFMA_B16(ah2, w2b_h[ks], acc20, 0,0,0);
                acc30 = MFMA_B16(ah3, w2b_h[ks], acc30, 0,0,0);
                acc20 = MFMA_B16(ah2, w2b_l[ks], acc20, 0,0,0);
                acc30 = MFMA_B16(ah3, w2b_l[ks], acc30, 0,0,0);
                acc20 = MFMA_B16(al2, w2b_h[ks], acc20, 0,0,0);
                acc30 = MFMA_B16(al3, w2b_h[ks], acc30, 0,0,0);
            }
            float p8[8];
#pragma unroll
            for (int r = 0; r < 4; r++) {
                p8[r]     = acc20[r] * e20[r];
                p8[4 + r] = acc30[r] * e30[r];
            }
#pragma unroll
            for (int mask = 1; mask < 16; mask <<= 1) {
#pragma unroll
                for (int e = 0; e < 8; e++) p8[e] += __shfl_xor(p8[e], mask, 64);
            }
            if (lr == 0) {
#pragma unroll
                for (int r = 0; r < 4; r++) {
                    sred[wid * MAXN + 32 + lg * 4 + r] = p8[r];
                    sred[wid * MAXN + 48 + lg * 4 + r] = p8[4 + r];
                }
            }
        }
    }
    __syncthreads();

    // ---------------- scatter (single pass over up to 64 pairs) ------------
    float iax = 0.f, iay = 0.f, iaz = 0.f;
    if (t < MAXN && t < cnt) {
        float s = 0.f;
#pragma unroll
        for (int w = 0; w < 8; w++) s += sred[w * MAXN + t];
        float coef = s / nd[t];
        float fx = coef * ndx[t];
        float fy = coef * ndy[t];
        float fz = coef * ndz[t];
        iax = fx; iay = fy; iaz = fz;
        atomicAdd(f_acc + nj[t]*3 + 0, fx);
        atomicAdd(f_acc + nj[t]*3 + 1, fy);
        atomicAdd(f_acc + nj[t]*3 + 2, fz);
    }

    // i-side reduce across wave 0 (full 64 lanes), then 3 atomics per block.
    if (t < MAXN) {
#pragma unroll
        for (int mask = 1; mask < 64; mask <<= 1) {
            iax += __shfl_xor(iax, mask, 64);
            iay += __shfl_xor(iay, mask, 64);
            iaz += __shfl_xor(iaz, mask, 64);
        }
        if (t == 0) {
            atomicAdd(f_acc + i*3 + 0, -iax);
            atomicAdd(f_acc + i*3 + 1, -iay);
            atomicAdd(f_acc + i*3 + 2, -iaz);
        }
    }
}

// ---------------------------------------------------------------- finalize
__global__ __launch_bounds__(256) void fin_kernel(
    const float* __restrict__ v, const float* __restrict__ mass,
    const float* __restrict__ p_eta, const float* __restrict__ f_acc,
    float* __restrict__ out)
{
    __shared__ float red[256];
    int t = threadIdx.x;
    float ke = 0.f;
    float c = p_eta[0] / Q0_F;
    for (int idx = t; idx < 3 * N_ATOMS; idx += 256) {
        int a = idx / 3;
        float vv = v[idx], mi = mass[a];
        out[DVDT_OFF + idx] = (f_acc[idx] - c * vv * mi) / mi;
        out[V_OFF + idx] = vv;
        ke += 0.5f * mi * vv * vv;
    }
    red[t] = ke;
    __syncthreads();
    for (int s = 128; s > 0; s >>= 1) {
        if (t < s) red[t] += red[t + s];
        __syncthreads();
    }
    if (t == 0) {
        float k0 = red[0];
        float e0 = p_eta[0], e1 = p_eta[1], e2 = p_eta[2], e3 = p_eta[3];
        out[PETA_OFF + 0] = 2.f * (k0 - TARGET_KE) - e0 * e1 / QI_F;
        out[PETA_OFF + 1] = e0 * e0 / Q0_F - KT_F - e1 * e2 / QI_F;
        out[PETA_OFF + 2] = e1 * e1 / QI_F - KT_F - e2 * e3 / QI_F;
        out[PETA_OFF + 3] = e2 * e2 / QI_F - KT_F;
    }
}

// ---------------------------------------------------------------- launch
extern "C" void kernel_launch(void* const* d_in, const int* in_sizes, int n_in,
                              void* d_out, int out_size, void* d_ws, size_t ws_size,
                              hipStream_t stream)
{
    const float* v     = (const float*)d_in[0];
    const float* q     = (const float*)d_in[1];
    const float* p_eta = (const float*)d_in[2];
    const float* mass  = (const float*)d_in[3];
    const float* embed = (const float*)d_in[4];
    const float* W1    = (const float*)d_in[5];
    const float* b1    = (const float*)d_in[6];
    const float* W2    = (const float*)d_in[7];
    const float* b2    = (const float*)d_in[8];
    const float* W3    = (const float*)d_in[9];
    const float* wout  = (const float*)d_in[10];
    const int*   z     = (const int*)d_in[11];
    float* out = (float*)d_out;

    float* h     = (float*)d_ws;                    // 98304
    float* W3T   = h + N_ATOMS * FD;                // 16384
    float* f_acc = W3T + FD * FD;                   // 2304
    unsigned short* w2bh = (unsigned short*)(f_acc + 3 * N_ATOMS);
    unsigned short* w2bl = w2bh + FD * FD;
    unsigned short* w2fh = w2bl + FD * FD;
    unsigned short* w2fl = w2fh + FD * FD;
    unsigned short* w1fh = w2fl + FD * FD;
    unsigned short* w1fl = w1fh + NRBF * FD;

    prep_kernel<<<384, 256, 0, stream>>>(z, embed, W1, W2, W3, h, W3T,
                                         w1fh, w1fl, w2fh, w2fl, w2bh, w2bl,
                                         f_acc);
    atom_kernel<<<N_ATOMS, NTHREADS, 0, stream>>>(q, w1fh, w1fl, b1, w2fh, w2fl,
                                                  w2bh, w2bl, b2, h, W3, W3T, wout,
                                                  f_acc);
    fin_kernel<<<1, 256, 0, stream>>>(v, mass, p_eta, f_acc, out);
}

// Round 17
// 122.893 us; speedup vs baseline: 1.1980x; 1.0334x over previous
//
#include <hip/hip_runtime.h>
#include <math.h>

// Problem constants (match reference)
#define N_ATOMS 768
#define FD 128          // feature width
#define NRBF 32
#define MAXN 64         // per-atom neighbor cap (mean ~26)
#define NTHREADS 512    // 8 waves/block
#define TST 136         // padded LDS stride for [*][128] bf16 (ushort) tiles
#define RSTU 40         // padded ushort stride for [*][32] bf16 rbf tiles (80B, 16B-aligned)

constexpr float  CUT2   = 25.0f;
constexpr float  GAMMA_ = 40.96f;            // 1/(5/32)^2
constexpr float  CSTEP  = 5.0f / 31.0f;      // linspace(0,5,32) step
constexpr double KB_D   = 8.617330337217213e-05;
constexpr double KT_D   = 300.0 * KB_D;
constexpr float  KT_F   = (float)KT_D;
constexpr float  TARGET_KE = (float)(0.5 * 2304.0 * KT_D);
constexpr float  Q0_F   = (float)(2.0 * 2304.0 * KT_D * 400.0);  // Q[0]
constexpr float  QI_F   = (float)(2.0 * KT_D * 400.0);           // Q[1..3]

#define DVDT_OFF 0
#define V_OFF    (3 * N_ATOMS)
#define PETA_OFF (6 * N_ATOMS)

using short8v = __attribute__((ext_vector_type(8))) short;
using f32x4   = __attribute__((ext_vector_type(4))) float;

#define MFMA_B16 __builtin_amdgcn_mfma_f32_16x16x32_bf16

__device__ __forceinline__ unsigned short f2bf(float x) {
    unsigned int u = __float_as_uint(x);
    u += 0x7FFF + ((u >> 16) & 1);           // round-to-nearest-even
    return (unsigned short)(u >> 16);
}
__device__ __forceinline__ float bf2f(unsigned short h) {
    return __uint_as_float(((unsigned int)h) << 16);
}

// Hard-won rules (32 rounds of counters):
// 1. NO __launch_bounds__ min-wave hints on GEMM kernels (spill cliff).
// 2. NEVER put __threadfence / completion counters on the hot grid (R14).
// 3. R22-R24 WIN: MFMA split-bf16 (AhBh+AhBl+AlBh, err ~2^-17) for all dense
//    phases. Layouts: bwd w2b native; fwd w2f[c][k]=W2[k][c];
//    w1f[c][k]=W1[k][c]. C/D: col=lane&15, row=(lane>>4)*4+reg (verified).
// 4. R26 REGRESSED: multiplying atomics in fused epilogues.
// 5. R28 WIN: fwd+mbar+bwd fused per-atom megakernel, 3 dispatches.
// 6. R29-R32: waves x2, LDS /2, barriers -4, weights->regs, straggler
//    flattening — each <=7%. All 768 blocks are CO-RESIDENT (3/CU exactly),
//    so atom dur ~ one block's path = ~112K cycles for ~9 phases: NOT
//    explicable by data latency. All counters low; every dataflow fix null.
// 7. R33 theory: INSTRUCTION-FETCH bound. Fully-unrolled 4-tile body is
//    tens of KB of ISA vs 32KB I$; 24 waves/CU stream it -> front-end
//    serializes on L2 I-fetch. Fix: runtime tile loops (ntl=ceil(cnt/16),
//    block-uniform), code ~2-3x smaller; mid-weight atoms also save a tile.
//    Falsifiable: if null, declare structural limit.
//    (R16 bench was an infra failure — this is the unchanged R33 resubmit.)

// ---------------------------------------------------------------- prep (fill only)
__global__ __launch_bounds__(256) void prep_kernel(
    const int* __restrict__ z, const float* __restrict__ embed,
    const float* __restrict__ W1, const float* __restrict__ W2,
    const float* __restrict__ W3,
    float* __restrict__ h, float* __restrict__ W3T,
    unsigned short* __restrict__ w1fh, unsigned short* __restrict__ w1fl,
    unsigned short* __restrict__ w2fh, unsigned short* __restrict__ w2fl,
    unsigned short* __restrict__ w2bh, unsigned short* __restrict__ w2bl,
    float* __restrict__ f_acc)
{
    int g = blockIdx.x * 256 + threadIdx.x;      // 98304 ids (384 blocks)
    if (g < N_ATOMS * FD) h[g] = embed[z[g >> 7] * FD + (g & 127)];
    if (g < FD * FD) {
        int r = g >> 7, c = g & 127;
        float w = W2[g];                         // W2[r][c]
        unsigned short hb = f2bf(w);
        unsigned short lb = f2bf(w - bf2f(hb));
        w2bh[g] = hb;                            // bwd B: native layout
        w2bl[g] = lb;
        w2fh[c * FD + r] = hb;                   // fwd B: w2f[c][k]=W2[k][c]
        w2fl[c * FD + r] = lb;
        W3T[c * FD + r] = W3[g];
        if (g < NRBF * FD) {                     // W1: NRBF x FD (r=k)
            float w1v = W1[g];
            unsigned short h1 = f2bf(w1v);
            w1fh[c * NRBF + r] = h1;             // [c][k], k contiguous
            w1fl[c * NRBF + r] = f2bf(w1v - bf2f(h1));
        }
    }
    if (g < 3 * N_ATOMS) f_acc[g] = 0.f;
}

// ---------------------------------------------------------------- atom (768 blocks x 512)
// Runtime tile loops (code-size diet): ntl = ceil(cnt/16) M-tiles per wave.
__global__ __launch_bounds__(NTHREADS) void atom_kernel(
    const float* __restrict__ q,
    const unsigned short* __restrict__ w1fh, const unsigned short* __restrict__ w1fl,
    const float* __restrict__ b1,
    const unsigned short* __restrict__ w2fh, const unsigned short* __restrict__ w2fl,
    const unsigned short* __restrict__ w2bh, const unsigned short* __restrict__ w2bl,
    const float* __restrict__ b2, const float* __restrict__ h,
    const float* __restrict__ W3, const float* __restrict__ W3T,
    const float* __restrict__ wout,
    float* __restrict__ f_acc)
{
    __shared__ int   nj[MAXN];
    __shared__ float nd[MAXN], ndx[MAXN], ndy[MAXN], ndz[MAXN];
    __shared__ int   cnt_s;
    // Overlaid pools: fwd {rbf,a1} and bwd {crbf,ts} are temporally disjoint.
    __shared__ __align__(16) unsigned short poolR[2 * MAXN * RSTU];  // 10240 B
    __shared__ __align__(16) unsigned short poolA[2 * MAXN * TST];   // 34816 B
    __shared__ float mrow[FD], gb[FD], mbrow[FD];                    // 1536 B
    __shared__ float sred[8 * MAXN];                                 // 2048 B
    // total ~50.2 KB -> 3 blocks/CU (768 all co-resident)

    unsigned short* rbf_h  = poolR;
    unsigned short* rbf_l  = poolR + MAXN * RSTU;
    unsigned short* crbf_h = poolR;                // overlay (bwd)
    unsigned short* crbf_l = poolR + MAXN * RSTU;
    unsigned short* a1h  = poolA;
    unsigned short* a1l  = poolA + MAXN * TST;
    unsigned short* ts_h = poolA;                  // overlay (bwd)
    unsigned short* ts_l = poolA + MAXN * TST;

    int i = blockIdx.x, t = threadIdx.x;
    int wid = t >> 6, lane = t & 63;             // wid 0..7
    int lr = lane & 15, lg = lane >> 4;
    int c0 = wid * 16 + lr;                      // this wave's single col-tile

    if (t == 0) cnt_s = 0;
    __syncthreads();

    // Block-invariant fwd weights into registers — latency covered by the
    // neighbor-build loop below (R31).
    short8v w1h_r = *(const short8v*)(w1fh + c0 * NRBF + lg * 8);
    short8v w1l_r = *(const short8v*)(w1fl + c0 * NRBF + lg * 8);
    short8v w2f_h[4], w2f_l[4];
#pragma unroll
    for (int ks = 0; ks < 4; ks++) {
        int kb = ks * 32 + lg * 8;
        w2f_h[ks] = *(const short8v*)(w2fh + c0 * FD + kb);
        w2f_l[ks] = *(const short8v*)(w2fl + c0 * FD + kb);
    }
    float bb0  = b1[c0];
    float b2c0 = b2[c0];

    float qx = q[i*3], qy = q[i*3+1], qz = q[i*3+2];
    for (int j = t; j < N_ATOMS; j += NTHREADS) {
        if (j == i) continue;
        float dx = qx - q[j*3], dy = qy - q[j*3+1], dz = qz - q[j*3+2];
        float d2 = dx*dx + dy*dy + dz*dz;
        if (d2 < CUT2) {
            int p = atomicAdd(&cnt_s, 1);
            if (p < MAXN) { nj[p] = j; nd[p] = sqrtf(d2);
                            ndx[p] = dx; ndy[p] = dy; ndz[p] = dz; }
        }
    }
    __syncthreads();
    int cnt = min(cnt_s, MAXN);
    if (cnt == 0) return;                        // no pairs, no forces
    int ntl = (cnt + 15) >> 4;                   // 1..4 M-tiles (block-uniform)

    float macc0 = 0.f;                           // m[i][c0] partial
    unsigned int mk = 0;                         // relu gate mask (4b/tile)

    // T14 prefetch: ts-fill h gathers for rows 0-31 issued NOW; latency
    // hides under the entire fwd + mbar section.
    float4 hj0[2];
#pragma unroll
    for (int e = 0; e < 2; e++) {
        int idx = t + e * NTHREADS;
        int p = idx >> 5, c4g = (idx & 31) * 4;
        hj0[e] = (p < cnt) ? *(const float4*)(h + nj[p] * FD + c4g)
                           : make_float4(0.f, 0.f, 0.f, 0.f);
    }

    // ---------------- rbf staging (ntl*512 items) --------------------------
    for (int e = 0; e < ntl; e++) {
        int idx = t + e * NTHREADS;
        int p = idx >> 5, k = idx & 31;
        float d = (p < cnt) ? nd[p] : 1.0f;
        float u = d - CSTEP * (float)k;
        float r = __expf(-GAMMA_ * u * u);
        unsigned short hb = f2bf(r);
        rbf_h[p * RSTU + k] = hb;
        rbf_l[p * RSTU + k] = f2bf(r - bf2f(hb));
    }
    __syncthreads();

    // ---------------- Phase A (tile loop): u = b1 + rbf@W1; relu; mask -----
    for (int tl = 0; tl < ntl; tl++) {
        int rb = tl * 16;
        f32x4 u0 = {bb0, bb0, bb0, bb0};
        short8v rh = *(const short8v*)(rbf_h + (rb + lr) * RSTU + lg * 8);
        short8v rl = *(const short8v*)(rbf_l + (rb + lr) * RSTU + lg * 8);
        u0 = MFMA_B16(rh, w1h_r, u0, 0,0,0);
        u0 = MFMA_B16(rh, w1l_r, u0, 0,0,0);
        u0 = MFMA_B16(rl, w1h_r, u0, 0,0,0);
        // C/D: col=lane&15, row=(lane>>4)*4+reg  [verified]
#pragma unroll
        for (int r = 0; r < 4; r++) {
            int p = rb + lg * 4 + r;
            if (u0[r] > 0.f) mk |= 1u << (4 * tl + r);
            float v = fmaxf(u0[r], 0.f);
            unsigned short hb = f2bf(v);
            a1h[p * TST + c0] = hb;
            a1l[p * TST + c0] = f2bf(v - bf2f(hb));
        }
    }
    __syncthreads();

    // ---------------- Phase B (tile loop): filt = a1@W2; accumulate m ------
    for (int tl = 0; tl < ntl; tl++) {
        int rb = tl * 16;
        float hv[4];
#pragma unroll
        for (int r = 0; r < 4; r++) {
            int p = rb + lg * 4 + r;
            hv[r] = (p < cnt) ? h[nj[p] * FD + c0] : 0.f;
        }
        f32x4 acc = {0.f, 0.f, 0.f, 0.f};
#pragma unroll
        for (int ks = 0; ks < 4; ks++) {
            int kb = ks * 32 + lg * 8;
            short8v ah = *(const short8v*)(a1h + (rb + lr) * TST + kb);
            short8v al = *(const short8v*)(a1l + (rb + lr) * TST + kb);
            acc = MFMA_B16(ah, w2f_h[ks], acc, 0,0,0);
            acc = MFMA_B16(ah, w2f_l[ks], acc, 0,0,0);
            acc = MFMA_B16(al, w2f_h[ks], acc, 0,0,0);
        }
#pragma unroll
        for (int r = 0; r < 4; r++) macc0 += (acc[r] + b2c0) * hv[r];
    }

    // bwd weights into registers NOW — latency covered by m-reduce + mbar.
    short8v w2b_h[4], w2b_l[4];
#pragma unroll
    for (int ks = 0; ks < 4; ks++) {
        int kb = ks * 32 + lg * 8;
        w2b_h[ks] = *(const short8v*)(w2bh + c0 * FD + kb);
        w2b_l[ks] = *(const short8v*)(w2bl + c0 * FD + kb);
    }

    // ---------------- m reduce -> LDS mrow ---------------------------------
    {
        float r0 = macc0 + __shfl_xor(macc0, 16, 64);
        r0 += __shfl_xor(r0, 32, 64);
        if (lg == 0) mrow[c0] = r0;        // 8 waves x 16 lr cover 0..127
    }
    __syncthreads();

    // ---------------- mbar: in-wave GEMVs (lg = f-quarter) -----------------
    {
        int f0h = lg * 32;
        float g = 0.f;
#pragma unroll
        for (int f4 = 0; f4 < 32; f4 += 4) {
            float4 w  = *(const float4*)(W3T + c0 * FD + f0h + f4);  // W3T[c][f]
            float4 mr = *(const float4*)(mrow + f0h + f4);
            g += mr.x*w.x + mr.y*w.y + mr.z*w.z + mr.w*w.w;
        }
        g += __shfl_xor(g, 16, 64);
        g += __shfl_xor(g, 32, 64);
        if (lg == 0) gb[c0] = (g > 0.f) ? wout[c0] : 0.f;
    }
    __syncthreads();
    {
        int f0h = lg * 32;
        float mb = 0.f;
#pragma unroll
        for (int f4 = 0; f4 < 32; f4 += 4) {
            float4 w  = *(const float4*)(W3 + c0 * FD + f0h + f4);   // W3[c][f]
            float4 gv = *(const float4*)(gb + f0h + f4);
            mb += gv.x*w.x + gv.y*w.y + gv.z*w.z + gv.w*w.w;
        }
        mb += __shfl_xor(mb, 16, 64);
        mb += __shfl_xor(mb, 32, 64);
        if (lg == 0) mbrow[c0] = mb;
    }
    __syncthreads();

    // ---------------- bwd: crbf + ts staging (ntl*512 items each) ----------
    for (int e = 0; e < ntl; e++) {
        int idx = t + e * NTHREADS;
        int p = idx >> 5, k = idx & 31;
        float d = (p < cnt) ? nd[p] : 1.0f;
        float u = d - CSTEP * (float)k;
        float r = __expf(-GAMMA_ * u * u);
        float cd = -2.f * GAMMA_ * u * r;
        unsigned short hc = f2bf(cd);
        crbf_h[p * RSTU + k] = hc;
        crbf_l[p * RSTU + k] = f2bf(cd - bf2f(hc));
    }
    for (int e = 0; e < ntl; e++) {
        int idx = t + e * NTHREADS;
        int p = idx >> 5, c4g = (idx & 31) * 4;
        ushort4 hv = {0,0,0,0}, lv = {0,0,0,0};
        if (p < cnt) {
            float4 mb4 = *(const float4*)(mbrow + c4g);
            float4 hj4 = (e < 2) ? hj0[e]
                                 : *(const float4*)(h + nj[p] * FD + c4g);
            float v0 = mb4.x*hj4.x, v1 = mb4.y*hj4.y;
            float v2 = mb4.z*hj4.z, v3 = mb4.w*hj4.w;
            hv.x = f2bf(v0); lv.x = f2bf(v0 - bf2f(hv.x));
            hv.y = f2bf(v1); lv.y = f2bf(v1 - bf2f(hv.y));
            hv.z = f2bf(v2); lv.z = f2bf(v2 - bf2f(hv.z));
            hv.w = f2bf(v3); lv.w = f2bf(v3 - bf2f(hv.w));
        }
        *(ushort4*)(ts_h + p * TST + c4g) = hv;
        *(ushort4*)(ts_l + p * TST + c4g) = lv;
    }
    __syncthreads();                       // crbf + ts ready

    // ---------------- bwd (tile loop): gef + GEMM + fold + reduce ----------
    for (int tl = 0; tl < ntl; tl++) {
        int rb = tl * 16;
        // gef: ef = crbf@W1 split; gate via mask bits (4*tl..4*tl+3).
        f32x4 ef = {0.f, 0.f, 0.f, 0.f};
        {
            short8v ch = *(const short8v*)(crbf_h + (rb + lr) * RSTU + lg * 8);
            short8v cl = *(const short8v*)(crbf_l + (rb + lr) * RSTU + lg * 8);
            ef = MFMA_B16(ch, w1h_r, ef, 0,0,0);
            ef = MFMA_B16(ch, w1l_r, ef, 0,0,0);
            ef = MFMA_B16(cl, w1h_r, ef, 0,0,0);
        }
        unsigned int mt = (mk >> (4 * tl)) & 0xFu;
#pragma unroll
        for (int r = 0; r < 4; r++)
            ef[r] = (mt & (1u << r)) ? ef[r] : 0.f;

        // GEMM: du1 = ts @ W2T (register B operands).
        f32x4 acc = {0.f, 0.f, 0.f, 0.f};
#pragma unroll
        for (int ks = 0; ks < 4; ks++) {
            int kb = ks * 32 + lg * 8;
            short8v ah = *(const short8v*)(ts_h + (rb + lr) * TST + kb);
            short8v al = *(const short8v*)(ts_l + (rb + lr) * TST + kb);
            acc = MFMA_B16(ah, w2b_h[ks], acc, 0,0,0);
            acc = MFMA_B16(ah, w2b_l[ks], acc, 0,0,0);
            acc = MFMA_B16(al, w2b_h[ks], acc, 0,0,0);
        }

        float p4[4];
#pragma unroll
        for (int r = 0; r < 4; r++) p4[r] = acc[r] * ef[r];
#pragma unroll
        for (int mask = 1; mask < 16; mask <<= 1) {
#pragma unroll
            for (int e = 0; e < 4; e++) p4[e] += __shfl_xor(p4[e], mask, 64);
        }
        if (lr == 0) {
#pragma unroll
            for (int r = 0; r < 4; r++)
                sred[wid * MAXN + rb + lg * 4 + r] = p4[r];
        }
    }
    __syncthreads();

    // ---------------- scatter (single pass over up to 64 pairs) ------------
    float iax = 0.f, iay = 0.f, iaz = 0.f;
    if (t < MAXN && t < cnt) {
        float s = 0.f;
#pragma unroll
        for (int w = 0; w < 8; w++) s += sred[w * MAXN + t];
        float coef = s / nd[t];
        float fx = coef * ndx[t];
        float fy = coef * ndy[t];
        float fz = coef * ndz[t];
        iax = fx; iay = fy; iaz = fz;
        atomicAdd(f_acc + nj[t]*3 + 0, fx);
        atomicAdd(f_acc + nj[t]*3 + 1, fy);
        atomicAdd(f_acc + nj[t]*3 + 2, fz);
    }

    // i-side reduce across wave 0 (full 64 lanes), then 3 atomics per block.
    if (t < MAXN) {
#pragma unroll
        for (int mask = 1; mask < 64; mask <<= 1) {
            iax += __shfl_xor(iax, mask, 64);
            iay += __shfl_xor(iay, mask, 64);
            iaz += __shfl_xor(iaz, mask, 64);
        }
        if (t == 0) {
            atomicAdd(f_acc + i*3 + 0, -iax);
            atomicAdd(f_acc + i*3 + 1, -iay);
            atomicAdd(f_acc + i*3 + 2, -iaz);
        }
    }
}

// ---------------------------------------------------------------- finalize
__global__ __launch_bounds__(256) void fin_kernel(
    const float* __restrict__ v, const float* __restrict__ mass,
    const float* __restrict__ p_eta, const float* __restrict__ f_acc,
    float* __restrict__ out)
{
    __shared__ float red[256];
    int t = threadIdx.x;
    float ke = 0.f;
    float c = p_eta[0] / Q0_F;
    for (int idx = t; idx < 3 * N_ATOMS; idx += 256) {
        int a = idx / 3;
        float vv = v[idx], mi = mass[a];
        out[DVDT_OFF + idx] = (f_acc[idx] - c * vv * mi) / mi;
        out[V_OFF + idx] = vv;
        ke += 0.5f * mi * vv * vv;
    }
    red[t] = ke;
    __syncthreads();
    for (int s = 128; s > 0; s >>= 1) {
        if (t < s) red[t] += red[t + s];
        __syncthreads();
    }
    if (t == 0) {
        float k0 = red[0];
        float e0 = p_eta[0], e1 = p_eta[1], e2 = p_eta[2], e3 = p_eta[3];
        out[PETA_OFF + 0] = 2.f * (k0 - TARGET_KE) - e0 * e1 / QI_F;
        out[PETA_OFF + 1] = e0 * e0 / Q0_F - KT_F - e1 * e2 / QI_F;
        out[PETA_OFF + 2] = e1 * e1 / QI_F - KT_F - e2 * e3 / QI_F;
        out[PETA_OFF + 3] = e2 * e2 / QI_F - KT_F;
    }
}

// ---------------------------------------------------------------- launch
extern "C" void kernel_launch(void* const* d_in, const int* in_sizes, int n_in,
                              void* d_out, int out_size, void* d_ws, size_t ws_size,
                              hipStream_t stream)
{
    const float* v     = (const float*)d_in[0];
    const float* q     = (const float*)d_in[1];
    const float* p_eta = (const float*)d_in[2];
    const float* mass  = (const float*)d_in[3];
    const float* embed = (const float*)d_in[4];
    const float* W1    = (const float*)d_in[5];
    const float* b1    = (const float*)d_in[6];
    const float* W2    = (const float*)d_in[7];
    const float* b2    = (const float*)d_in[8];
    const float* W3    = (const float*)d_in[9];
    const float* wout  = (const float*)d_in[10];
    const int*   z     = (const int*)d_in[11];
    float* out = (float*)d_out;

    float* h     = (float*)d_ws;                    // 98304
    float* W3T   = h + N_ATOMS * FD;                // 16384
    float* f_acc = W3T + FD * FD;                   // 2304
    unsigned short* w2bh = (unsigned short*)(f_acc + 3 * N_ATOMS);
    unsigned short* w2bl = w2bh + FD * FD;
    unsigned short* w2fh = w2bl + FD * FD;
    unsigned short* w2fl = w2fh + FD * FD;
    unsigned short* w1fh = w2fl + FD * FD;
    unsigned short* w1fl = w1fh + NRBF * FD;

    prep_kernel<<<384, 256, 0, stream>>>(z, embed, W1, W2, W3, h, W3T,
                                         w1fh, w1fl, w2fh, w2fl, w2bh, w2bl,
                                         f_acc);
    atom_kernel<<<N_ATOMS, NTHREADS, 0, stream>>>(q, w1fh, w1fl, b1, w2fh, w2fl,
                                                  w2bh, w2bl, b2, h, W3, W3T, wout,
                                                  f_acc);
    fin_kernel<<<1, 256, 0, stream>>>(v, mass, p_eta, f_acc, out);
}

// Round 18
// 117.886 us; speedup vs baseline: 1.2489x; 1.0425x over previous
//
#include <hip/hip_runtime.h>
#include <math.h>

// Problem constants (match reference)
#define N_ATOMS 768
#define FD 128          // feature width
#define NRBF 32
#define MAXN 64         // per-atom neighbor cap (mean ~26)
#define NTHREADS 512    // 8 waves/block
#define TST 136         // padded LDS stride for [*][128] bf16 (ushort) tiles
#define RSTU 40         // padded ushort stride for [*][32] bf16 rbf tiles (80B, 16B-aligned)

constexpr float  CUT2   = 25.0f;
constexpr float  GAMMA_ = 40.96f;            // 1/(5/32)^2
constexpr float  CSTEP  = 5.0f / 31.0f;      // linspace(0,5,32) step
constexpr double KB_D   = 8.617330337217213e-05;
constexpr double KT_D   = 300.0 * KB_D;
constexpr float  KT_F   = (float)KT_D;
constexpr float  TARGET_KE = (float)(0.5 * 2304.0 * KT_D);
constexpr float  Q0_F   = (float)(2.0 * 2304.0 * KT_D * 400.0);  // Q[0]
constexpr float  QI_F   = (float)(2.0 * KT_D * 400.0);           // Q[1..3]

#define DVDT_OFF 0
#define V_OFF    (3 * N_ATOMS)
#define PETA_OFF (6 * N_ATOMS)

using short8v = __attribute__((ext_vector_type(8))) short;
using f32x4   = __attribute__((ext_vector_type(4))) float;

#define MFMA_B16 __builtin_amdgcn_mfma_f32_16x16x32_bf16

__device__ __forceinline__ unsigned short f2bf(float x) {
    unsigned int u = __float_as_uint(x);
    u += 0x7FFF + ((u >> 16) & 1);           // round-to-nearest-even
    return (unsigned short)(u >> 16);
}
__device__ __forceinline__ float bf2f(unsigned short h) {
    return __uint_as_float(((unsigned int)h) << 16);
}

// Hard-won rules (33 rounds of counters):
// 1. NO __launch_bounds__ min-wave hints on GEMM kernels (spill cliff).
// 2. NEVER put __threadfence / completion counters on the hot grid (R14).
// 3. R22-R24 WIN: MFMA split-bf16 (AhBh+AhBl+AlBh, err ~2^-17) for all dense
//    phases. Layouts: bwd B native W2 rows; fwd B = W2 columns;
//    W1 B = W1 columns. C/D: col=lane&15, row=(lane>>4)*4+reg (verified).
// 4. R26 REGRESSED: multiplying atomics in fused epilogues.
// 5. R28 WIN: fwd+mbar+bwd fused per-atom megakernel.
// 6. R29-R32: parallelism/LDS/barrier/weight-hoist levers each <=7% — atom
//    kernel is per-block serial-path bound with all counters low.
// 7. R33 WIN (-4us atom): runtime tile loops (code-size diet) — partial
//    I-fetch confirmation + mid-weight atoms save a tile.
// 8. R34: prep DELETED. Weight fragments loaded per-thread directly from
//    fp32 W1/W2 at kernel top (latency under neighbor build, R31 pattern),
//    split to bf16 hi/lo in regs. h == embed[z[j]]: z staged in LDS (3KB),
//    gathers read embed directly. mbar GEMV1 reads W3 strided (L2-res).
//    prep -> hipMemsetAsync(f_acc); dispatches 3 -> 2(+memset).

// ---------------------------------------------------------------- atom (768 blocks x 512)
__global__ __launch_bounds__(NTHREADS) void atom_kernel(
    const float* __restrict__ q,
    const float* __restrict__ W1, const float* __restrict__ b1,
    const float* __restrict__ W2, const float* __restrict__ b2,
    const float* __restrict__ embed, const int* __restrict__ z,
    const float* __restrict__ W3, const float* __restrict__ wout,
    float* __restrict__ f_acc)
{
    __shared__ int   nj[MAXN];
    __shared__ float nd[MAXN], ndx[MAXN], ndy[MAXN], ndz[MAXN];
    __shared__ int   cnt_s;
    __shared__ int   z_s[N_ATOMS];                                   // 3072 B
    // Overlaid pools: fwd {rbf,a1} and bwd {crbf,ts} are temporally disjoint.
    __shared__ __align__(16) unsigned short poolR[2 * MAXN * RSTU];  // 10240 B
    __shared__ __align__(16) unsigned short poolA[2 * MAXN * TST];   // 34816 B
    __shared__ float mrow[FD], gb[FD], mbrow[FD];                    // 1536 B
    __shared__ float sred[8 * MAXN];                                 // 2048 B
    // total ~53.2 KB -> 3 blocks/CU (768 all co-resident)

    unsigned short* rbf_h  = poolR;
    unsigned short* rbf_l  = poolR + MAXN * RSTU;
    unsigned short* crbf_h = poolR;                // overlay (bwd)
    unsigned short* crbf_l = poolR + MAXN * RSTU;
    unsigned short* a1h  = poolA;
    unsigned short* a1l  = poolA + MAXN * TST;
    unsigned short* ts_h = poolA;                  // overlay (bwd)
    unsigned short* ts_l = poolA + MAXN * TST;

    int i = blockIdx.x, t = threadIdx.x;
    int wid = t >> 6, lane = t & 63;             // wid 0..7
    int lr = lane & 15, lg = lane >> 4;
    int c0 = wid * 16 + lr;                      // this wave's single col-tile

    if (t == 0) cnt_s = 0;
    __syncthreads();

    // fp32 weight fragment loads issued NOW — latency covered by the
    // neighbor-build loop below (R31 pattern). Split to bf16 after it.
    float w1f32[8], w2ff32[4][8];
#pragma unroll
    for (int e = 0; e < 8; e++)
        w1f32[e] = W1[(lg * 8 + e) * FD + c0];           // W1[k][c0]
#pragma unroll
    for (int ks = 0; ks < 4; ks++)
#pragma unroll
        for (int e = 0; e < 8; e++)
            w2ff32[ks][e] = W2[(ks * 32 + lg * 8 + e) * FD + c0];  // W2[k][c0]
    float bb0  = b1[c0];
    float b2c0 = b2[c0];

    float qx = q[i*3], qy = q[i*3+1], qz = q[i*3+2];
    for (int j = t; j < N_ATOMS; j += NTHREADS) {
        z_s[j] = z[j];
        if (j == i) continue;
        float dx = qx - q[j*3], dy = qy - q[j*3+1], dz = qz - q[j*3+2];
        float d2 = dx*dx + dy*dy + dz*dz;
        if (d2 < CUT2) {
            int p = atomicAdd(&cnt_s, 1);
            if (p < MAXN) { nj[p] = j; nd[p] = sqrtf(d2);
                            ndx[p] = dx; ndy[p] = dy; ndz[p] = dz; }
        }
    }
    __syncthreads();
    int cnt = min(cnt_s, MAXN);
    if (cnt == 0) return;                        // no pairs, no forces
    int ntl = (cnt + 15) >> 4;                   // 1..4 M-tiles (block-uniform)

    // Split weight fragments to bf16 hi/lo registers (identical values to
    // the old prep pre-split; same math, same absmax).
    short8v w1h_r, w1l_r, w2f_h[4], w2f_l[4];
#pragma unroll
    for (int e = 0; e < 8; e++) {
        unsigned short hb = f2bf(w1f32[e]);
        w1h_r[e] = (short)hb;
        w1l_r[e] = (short)f2bf(w1f32[e] - bf2f(hb));
    }
#pragma unroll
    for (int ks = 0; ks < 4; ks++)
#pragma unroll
        for (int e = 0; e < 8; e++) {
            unsigned short hb = f2bf(w2ff32[ks][e]);
            w2f_h[ks][e] = (short)hb;
            w2f_l[ks][e] = (short)f2bf(w2ff32[ks][e] - bf2f(hb));
        }

    float macc0 = 0.f;                           // m[i][c0] partial
    unsigned int mk = 0;                         // relu gate mask (4b/tile)

    // T14 prefetch: ts-fill h gathers for rows 0-31 issued NOW (h == embed
    // row via z_s); latency hides under the entire fwd + mbar section.
    float4 hj0[2];
#pragma unroll
    for (int e = 0; e < 2; e++) {
        int idx = t + e * NTHREADS;
        int p = idx >> 5, c4g = (idx & 31) * 4;
        hj0[e] = (p < cnt)
            ? *(const float4*)(embed + z_s[nj[p]] * FD + c4g)
            : make_float4(0.f, 0.f, 0.f, 0.f);
    }

    // ---------------- rbf staging (ntl*512 items) --------------------------
    for (int e = 0; e < ntl; e++) {
        int idx = t + e * NTHREADS;
        int p = idx >> 5, k = idx & 31;
        float d = (p < cnt) ? nd[p] : 1.0f;
        float u = d - CSTEP * (float)k;
        float r = __expf(-GAMMA_ * u * u);
        unsigned short hb = f2bf(r);
        rbf_h[p * RSTU + k] = hb;
        rbf_l[p * RSTU + k] = f2bf(r - bf2f(hb));
    }
    __syncthreads();

    // ---------------- Phase A (tile loop): u = b1 + rbf@W1; relu; mask -----
    for (int tl = 0; tl < ntl; tl++) {
        int rb = tl * 16;
        f32x4 u0 = {bb0, bb0, bb0, bb0};
        short8v rh = *(const short8v*)(rbf_h + (rb + lr) * RSTU + lg * 8);
        short8v rl = *(const short8v*)(rbf_l + (rb + lr) * RSTU + lg * 8);
        u0 = MFMA_B16(rh, w1h_r, u0, 0,0,0);
        u0 = MFMA_B16(rh, w1l_r, u0, 0,0,0);
        u0 = MFMA_B16(rl, w1h_r, u0, 0,0,0);
        // C/D: col=lane&15, row=(lane>>4)*4+reg  [verified]
#pragma unroll
        for (int r = 0; r < 4; r++) {
            int p = rb + lg * 4 + r;
            if (u0[r] > 0.f) mk |= 1u << (4 * tl + r);
            float v = fmaxf(u0[r], 0.f);
            unsigned short hb = f2bf(v);
            a1h[p * TST + c0] = hb;
            a1l[p * TST + c0] = f2bf(v - bf2f(hb));
        }
    }
    __syncthreads();

    // ---------------- Phase B (tile loop): filt = a1@W2; accumulate m ------
    for (int tl = 0; tl < ntl; tl++) {
        int rb = tl * 16;
        float hv[4];
#pragma unroll
        for (int r = 0; r < 4; r++) {
            int p = rb + lg * 4 + r;
            hv[r] = (p < cnt) ? embed[z_s[nj[p]] * FD + c0] : 0.f;
        }
        f32x4 acc = {0.f, 0.f, 0.f, 0.f};
#pragma unroll
        for (int ks = 0; ks < 4; ks++) {
            int kb = ks * 32 + lg * 8;
            short8v ah = *(const short8v*)(a1h + (rb + lr) * TST + kb);
            short8v al = *(const short8v*)(a1l + (rb + lr) * TST + kb);
            acc = MFMA_B16(ah, w2f_h[ks], acc, 0,0,0);
            acc = MFMA_B16(ah, w2f_l[ks], acc, 0,0,0);
            acc = MFMA_B16(al, w2f_h[ks], acc, 0,0,0);
        }
#pragma unroll
        for (int r = 0; r < 4; r++) macc0 += (acc[r] + b2c0) * hv[r];
    }

    // bwd weights into registers NOW (fp32 rows of W2, contiguous float4) —
    // latency covered by m-reduce + mbar.
    short8v w2b_h[4], w2b_l[4];
#pragma unroll
    for (int ks = 0; ks < 4; ks++) {
        int kb = ks * 32 + lg * 8;
        float4 a = *(const float4*)(W2 + c0 * FD + kb);      // W2[c0][k..]
        float4 b = *(const float4*)(W2 + c0 * FD + kb + 4);
        float vv[8] = {a.x, a.y, a.z, a.w, b.x, b.y, b.z, b.w};
#pragma unroll
        for (int e = 0; e < 8; e++) {
            unsigned short hb = f2bf(vv[e]);
            w2b_h[ks][e] = (short)hb;
            w2b_l[ks][e] = (short)f2bf(vv[e] - bf2f(hb));
        }
    }

    // ---------------- m reduce -> LDS mrow ---------------------------------
    {
        float r0 = macc0 + __shfl_xor(macc0, 16, 64);
        r0 += __shfl_xor(r0, 32, 64);
        if (lg == 0) mrow[c0] = r0;        // 8 waves x 16 lr cover 0..127
    }
    __syncthreads();

    // ---------------- mbar: in-wave GEMVs (lg = f-quarter) -----------------
    {
        int f0h = lg * 32;
        float g = 0.f;
#pragma unroll 8
        for (int f = f0h; f < f0h + 32; f++)
            g += mrow[f] * W3[f * FD + c0];                  // W3[f][c0] strided
        g += __shfl_xor(g, 16, 64);
        g += __shfl_xor(g, 32, 64);
        if (lg == 0) gb[c0] = (g > 0.f) ? wout[c0] : 0.f;
    }
    __syncthreads();
    {
        int f0h = lg * 32;
        float mb = 0.f;
#pragma unroll
        for (int f4 = 0; f4 < 32; f4 += 4) {
            float4 w  = *(const float4*)(W3 + c0 * FD + f0h + f4);   // W3[c0][f]
            float4 gv = *(const float4*)(gb + f0h + f4);
            mb += gv.x*w.x + gv.y*w.y + gv.z*w.z + gv.w*w.w;
        }
        mb += __shfl_xor(mb, 16, 64);
        mb += __shfl_xor(mb, 32, 64);
        if (lg == 0) mbrow[c0] = mb;
    }
    __syncthreads();

    // ---------------- bwd: crbf + ts staging (ntl*512 items each) ----------
    for (int e = 0; e < ntl; e++) {
        int idx = t + e * NTHREADS;
        int p = idx >> 5, k = idx & 31;
        float d = (p < cnt) ? nd[p] : 1.0f;
        float u = d - CSTEP * (float)k;
        float r = __expf(-GAMMA_ * u * u);
        float cd = -2.f * GAMMA_ * u * r;
        unsigned short hc = f2bf(cd);
        crbf_h[p * RSTU + k] = hc;
        crbf_l[p * RSTU + k] = f2bf(cd - bf2f(hc));
    }
    for (int e = 0; e < ntl; e++) {
        int idx = t + e * NTHREADS;
        int p = idx >> 5, c4g = (idx & 31) * 4;
        ushort4 hv = {0,0,0,0}, lv = {0,0,0,0};
        if (p < cnt) {
            float4 mb4 = *(const float4*)(mbrow + c4g);
            float4 hj4 = (e < 2) ? hj0[e]
                : *(const float4*)(embed + z_s[nj[p]] * FD + c4g);
            float v0 = mb4.x*hj4.x, v1 = mb4.y*hj4.y;
            float v2 = mb4.z*hj4.z, v3 = mb4.w*hj4.w;
            hv.x = f2bf(v0); lv.x = f2bf(v0 - bf2f(hv.x));
            hv.y = f2bf(v1); lv.y = f2bf(v1 - bf2f(hv.y));
            hv.z = f2bf(v2); lv.z = f2bf(v2 - bf2f(hv.z));
            hv.w = f2bf(v3); lv.w = f2bf(v3 - bf2f(hv.w));
        }
        *(ushort4*)(ts_h + p * TST + c4g) = hv;
        *(ushort4*)(ts_l + p * TST + c4g) = lv;
    }
    __syncthreads();                       // crbf + ts ready

    // ---------------- bwd (tile loop): gef + GEMM + fold + reduce ----------
    for (int tl = 0; tl < ntl; tl++) {
        int rb = tl * 16;
        // gef: ef = crbf@W1 split; gate via mask bits (4*tl..4*tl+3).
        f32x4 ef = {0.f, 0.f, 0.f, 0.f};
        {
            short8v ch = *(const short8v*)(crbf_h + (rb + lr) * RSTU + lg * 8);
            short8v cl = *(const short8v*)(crbf_l + (rb + lr) * RSTU + lg * 8);
            ef = MFMA_B16(ch, w1h_r, ef, 0,0,0);
            ef = MFMA_B16(ch, w1l_r, ef, 0,0,0);
            ef = MFMA_B16(cl, w1h_r, ef, 0,0,0);
        }
        unsigned int mt = (mk >> (4 * tl)) & 0xFu;
#pragma unroll
        for (int r = 0; r < 4; r++)
            ef[r] = (mt & (1u << r)) ? ef[r] : 0.f;

        // GEMM: du1 = ts @ W2T (register B operands).
        f32x4 acc = {0.f, 0.f, 0.f, 0.f};
#pragma unroll
        for (int ks = 0; ks < 4; ks++) {
            int kb = ks * 32 + lg * 8;
            short8v ah = *(const short8v*)(ts_h + (rb + lr) * TST + kb);
            short8v al = *(const short8v*)(ts_l + (rb + lr) * TST + kb);
            acc = MFMA_B16(ah, w2b_h[ks], acc, 0,0,0);
            acc = MFMA_B16(ah, w2b_l[ks], acc, 0,0,0);
            acc = MFMA_B16(al, w2b_h[ks], acc, 0,0,0);
        }

        float p4[4];
#pragma unroll
        for (int r = 0; r < 4; r++) p4[r] = acc[r] * ef[r];
#pragma unroll
        for (int mask = 1; mask < 16; mask <<= 1) {
#pragma unroll
            for (int e = 0; e < 4; e++) p4[e] += __shfl_xor(p4[e], mask, 64);
        }
        if (lr == 0) {
#pragma unroll
            for (int r = 0; r < 4; r++)
                sred[wid * MAXN + rb + lg * 4 + r] = p4[r];
        }
    }
    __syncthreads();

    // ---------------- scatter (single pass over up to 64 pairs) ------------
    float iax = 0.f, iay = 0.f, iaz = 0.f;
    if (t < MAXN && t < cnt) {
        float s = 0.f;
#pragma unroll
        for (int w = 0; w < 8; w++) s += sred[w * MAXN + t];
        float coef = s / nd[t];
        float fx = coef * ndx[t];
        float fy = coef * ndy[t];
        float fz = coef * ndz[t];
        iax = fx; iay = fy; iaz = fz;
        atomicAdd(f_acc + nj[t]*3 + 0, fx);
        atomicAdd(f_acc + nj[t]*3 + 1, fy);
        atomicAdd(f_acc + nj[t]*3 + 2, fz);
    }

    // i-side reduce across wave 0 (full 64 lanes), then 3 atomics per block.
    if (t < MAXN) {
#pragma unroll
        for (int mask = 1; mask < 64; mask <<= 1) {
            iax += __shfl_xor(iax, mask, 64);
            iay += __shfl_xor(iay, mask, 64);
            iaz += __shfl_xor(iaz, mask, 64);
        }
        if (t == 0) {
            atomicAdd(f_acc + i*3 + 0, -iax);
            atomicAdd(f_acc + i*3 + 1, -iay);
            atomicAdd(f_acc + i*3 + 2, -iaz);
        }
    }
}

// ---------------------------------------------------------------- finalize
__global__ __launch_bounds__(256) void fin_kernel(
    const float* __restrict__ v, const float* __restrict__ mass,
    const float* __restrict__ p_eta, const float* __restrict__ f_acc,
    float* __restrict__ out)
{
    __shared__ float red[256];
    int t = threadIdx.x;
    float ke = 0.f;
    float c = p_eta[0] / Q0_F;
    for (int idx = t; idx < 3 * N_ATOMS; idx += 256) {
        int a = idx / 3;
        float vv = v[idx], mi = mass[a];
        out[DVDT_OFF + idx] = (f_acc[idx] - c * vv * mi) / mi;
        out[V_OFF + idx] = vv;
        ke += 0.5f * mi * vv * vv;
    }
    red[t] = ke;
    __syncthreads();
    for (int s = 128; s > 0; s >>= 1) {
        if (t < s) red[t] += red[t + s];
        __syncthreads();
    }
    if (t == 0) {
        float k0 = red[0];
        float e0 = p_eta[0], e1 = p_eta[1], e2 = p_eta[2], e3 = p_eta[3];
        out[PETA_OFF + 0] = 2.f * (k0 - TARGET_KE) - e0 * e1 / QI_F;
        out[PETA_OFF + 1] = e0 * e0 / Q0_F - KT_F - e1 * e2 / QI_F;
        out[PETA_OFF + 2] = e1 * e1 / QI_F - KT_F - e2 * e3 / QI_F;
        out[PETA_OFF + 3] = e2 * e2 / QI_F - KT_F;
    }
}

// ---------------------------------------------------------------- launch
extern "C" void kernel_launch(void* const* d_in, const int* in_sizes, int n_in,
                              void* d_out, int out_size, void* d_ws, size_t ws_size,
                              hipStream_t stream)
{
    const float* v     = (const float*)d_in[0];
    const float* q     = (const float*)d_in[1];
    const float* p_eta = (const float*)d_in[2];
    const float* mass  = (const float*)d_in[3];
    const float* embed = (const float*)d_in[4];
    const float* W1    = (const float*)d_in[5];
    const float* b1    = (const float*)d_in[6];
    const float* W2    = (const float*)d_in[7];
    const float* b2    = (const float*)d_in[8];
    const float* W3    = (const float*)d_in[9];
    const float* wout  = (const float*)d_in[10];
    const int*   z     = (const int*)d_in[11];
    float* out = (float*)d_out;

    float* f_acc = (float*)d_ws;                 // only workspace user now

    hipMemsetAsync(f_acc, 0, 3 * N_ATOMS * sizeof(float), stream);

    atom_kernel<<<N_ATOMS, NTHREADS, 0, stream>>>(q, W1, b1, W2, b2,
                                                  embed, z, W3, wout, f_acc);
    fin_kernel<<<1, 256, 0, stream>>>(v, mass, p_eta, f_acc, out);
}

// Round 19
// 109.547 us; speedup vs baseline: 1.3439x; 1.0761x over previous
//
#include <hip/hip_runtime.h>
#include <math.h>

// Problem constants (match reference)
#define N_ATOMS 768
#define FD 128          // feature width
#define NRBF 32
#define MAXN 64         // per-atom neighbor cap (mean ~26)
#define NTHREADS 512    // 8 waves/block
#define NBLOCKS 256     // persistent: each block owns atoms b, b+256, b+512
#define TST 136         // padded LDS stride for [*][128] bf16 (ushort) tiles
#define RSTU 40         // padded ushort stride for [*][32] bf16 rbf tiles (80B, 16B-aligned)

constexpr float  CUT2   = 25.0f;
constexpr float  GAMMA_ = 40.96f;            // 1/(5/32)^2
constexpr float  CSTEP  = 5.0f / 31.0f;      // linspace(0,5,32) step
constexpr double KB_D   = 8.617330337217213e-05;
constexpr double KT_D   = 300.0 * KB_D;
constexpr float  KT_F   = (float)KT_D;
constexpr float  TARGET_KE = (float)(0.5 * 2304.0 * KT_D);
constexpr float  Q0_F   = (float)(2.0 * 2304.0 * KT_D * 400.0);  // Q[0]
constexpr float  QI_F   = (float)(2.0 * KT_D * 400.0);           // Q[1..3]

#define DVDT_OFF 0
#define V_OFF    (3 * N_ATOMS)
#define PETA_OFF (6 * N_ATOMS)

using short8v = __attribute__((ext_vector_type(8))) short;
using f32x4   = __attribute__((ext_vector_type(4))) float;

#define MFMA_B16 __builtin_amdgcn_mfma_f32_16x16x32_bf16

__device__ __forceinline__ unsigned short f2bf(float x) {
    unsigned int u = __float_as_uint(x);
    u += 0x7FFF + ((u >> 16) & 1);           // round-to-nearest-even
    return (unsigned short)(u >> 16);
}
__device__ __forceinline__ float bf2f(unsigned short h) {
    return __uint_as_float(((unsigned int)h) << 16);
}

// Hard-won rules (34 rounds of counters):
// 1. NO __launch_bounds__ min-wave hints on GEMM kernels (spill cliff).
// 2. NEVER put __threadfence / completion counters on the hot grid (R14).
// 3. R22-R24 WIN: MFMA split-bf16 (AhBh+AhBl+AlBh, err ~2^-17) for all dense
//    phases. C/D: col=lane&15, row=(lane>>4)*4+reg (verified).
// 4. R26 REGRESSED: multiplying atomics in fused epilogues.
// 5. R28 WIN: fwd+mbar+bwd fused per-atom megakernel.
// 6. R29-R32 ~null levers; R33 WIN: runtime tile loops (I-fetch diet);
//    R34 WIN: prep deleted (weights split in-kernel, embed read direct).
// 7. OccupancyPercent == threads/2048 in EVERY config -> effectively 1
//    resident block/CU: kernel executes as ~3 sequential 256-block rounds,
//    each paying the full phase-chain latency. Explains the R29 null.
// 8. R35: PERSISTENT blocks — 256 blocks x 3 atoms {b, b+256, b+512}.
//    Weights split + z_s staged ONCE per block; next atom's neighbor build
//    (double-buffered lists) overlaps current atom's mbar/bwd; 2 launch
//    ramps removed. cnt==0 -> ntl=0 (empty loops, uniform barriers).

// ---------------------------------------------------------------- atom (256 blocks x 512, persistent)
__global__ __launch_bounds__(NTHREADS) void atom_kernel(
    const float* __restrict__ q,
    const float* __restrict__ W1, const float* __restrict__ b1,
    const float* __restrict__ W2, const float* __restrict__ b2,
    const float* __restrict__ embed, const int* __restrict__ z,
    const float* __restrict__ W3, const float* __restrict__ wout,
    float* __restrict__ f_acc)
{
    __shared__ int   nj2[2][MAXN];
    __shared__ float nd2[2][MAXN], ndx2[2][MAXN], ndy2[2][MAXN], ndz2[2][MAXN];
    __shared__ int   cnt2[2];
    __shared__ int   z_s[N_ATOMS];                                   // 3072 B
    // Overlaid pools: fwd {rbf,a1} and bwd {crbf,ts} are temporally disjoint.
    __shared__ __align__(16) unsigned short poolR[2 * MAXN * RSTU];  // 10240 B
    __shared__ __align__(16) unsigned short poolA[2 * MAXN * TST];   // 34816 B
    __shared__ float mrow[FD], gb[FD], mbrow[FD];                    // 1536 B
    __shared__ float sred[8 * MAXN];                                 // 2048 B
    // total ~54.4 KB

    unsigned short* rbf_h  = poolR;
    unsigned short* rbf_l  = poolR + MAXN * RSTU;
    unsigned short* crbf_h = poolR;                // overlay (bwd)
    unsigned short* crbf_l = poolR + MAXN * RSTU;
    unsigned short* a1h  = poolA;
    unsigned short* a1l  = poolA + MAXN * TST;
    unsigned short* ts_h = poolA;                  // overlay (bwd)
    unsigned short* ts_l = poolA + MAXN * TST;

    int b = blockIdx.x, t = threadIdx.x;
    int wid = t >> 6, lane = t & 63;             // wid 0..7
    int lr = lane & 15, lg = lane >> 4;
    int c0 = wid * 16 + lr;                      // this wave's single col-tile

    if (t < 2) cnt2[t] = 0;
    __syncthreads();

    // fp32 fwd-weight fragment loads issued NOW — latency covered by the
    // z_s staging + first neighbor build below (R31 pattern).
    float w1f32[8], w2ff32[4][8];
#pragma unroll
    for (int e = 0; e < 8; e++)
        w1f32[e] = W1[(lg * 8 + e) * FD + c0];           // W1[k][c0]
#pragma unroll
    for (int ks = 0; ks < 4; ks++)
#pragma unroll
        for (int e = 0; e < 8; e++)
            w2ff32[ks][e] = W2[(ks * 32 + lg * 8 + e) * FD + c0];  // W2[k][c0]
    float bb0  = b1[c0];
    float b2c0 = b2[c0];

    // z_s staging + neighbor build for atom b (buf 0)
    {
        float qx = q[b*3], qy = q[b*3+1], qz = q[b*3+2];
        for (int j = t; j < N_ATOMS; j += NTHREADS) {
            z_s[j] = z[j];
            if (j == b) continue;
            float dx = qx - q[j*3], dy = qy - q[j*3+1], dz = qz - q[j*3+2];
            float d2 = dx*dx + dy*dy + dz*dz;
            if (d2 < CUT2) {
                int p = atomicAdd(&cnt2[0], 1);
                if (p < MAXN) { nj2[0][p] = j; nd2[0][p] = sqrtf(d2);
                                ndx2[0][p] = dx; ndy2[0][p] = dy; ndz2[0][p] = dz; }
            }
        }
    }

    // Split fwd weights to bf16 hi/lo registers (same values as old prep).
    short8v w1h_r, w1l_r, w2f_h[4], w2f_l[4];
#pragma unroll
    for (int e = 0; e < 8; e++) {
        unsigned short hb = f2bf(w1f32[e]);
        w1h_r[e] = (short)hb;
        w1l_r[e] = (short)f2bf(w1f32[e] - bf2f(hb));
    }
#pragma unroll
    for (int ks = 0; ks < 4; ks++)
#pragma unroll
        for (int e = 0; e < 8; e++) {
            unsigned short hb = f2bf(w2ff32[ks][e]);
            w2f_h[ks][e] = (short)hb;
            w2f_l[ks][e] = (short)f2bf(w2ff32[ks][e] - bf2f(hb));
        }
    // bwd weights: contiguous fp32 rows of W2, split immediately (low pressure).
    short8v w2b_h[4], w2b_l[4];
#pragma unroll
    for (int ks = 0; ks < 4; ks++) {
        int kb = ks * 32 + lg * 8;
        float4 a4 = *(const float4*)(W2 + c0 * FD + kb);      // W2[c0][k..]
        float4 b4 = *(const float4*)(W2 + c0 * FD + kb + 4);
        float vv[8] = {a4.x, a4.y, a4.z, a4.w, b4.x, b4.y, b4.z, b4.w};
#pragma unroll
        for (int e = 0; e < 8; e++) {
            unsigned short hb = f2bf(vv[e]);
            w2b_h[ks][e] = (short)hb;
            w2b_l[ks][e] = (short)f2bf(vv[e] - bf2f(hb));
        }
    }
    __syncthreads();                       // build(atom b) + z_s complete

    // ================= persistent atom loop ================================
    for (int a = 0; a < 3; a++) {
        int i   = b + NBLOCKS * a;
        int buf = a & 1;
        int nbuf = buf ^ 1;
        int* njb = nj2[buf];
        float* ndb = nd2[buf], *ndxb = ndx2[buf], *ndyb = ndy2[buf], *ndzb = ndz2[buf];

        int cnt = min(cnt2[buf], MAXN);
        int ntl = (cnt + 15) >> 4;                   // 0..4 (block-uniform)
        if (a < 2 && t == 0) cnt2[nbuf] = 0;         // visible after next barrier

        float macc0 = 0.f;                           // m[i][c0] partial
        unsigned int mk = 0;                         // relu gate mask (4b/tile)

        // T14 prefetch: ts-fill h gathers for rows 0-31; latency hides under
        // fwd + mbar.
        float4 hj0[2];
#pragma unroll
        for (int e = 0; e < 2; e++) {
            int idx = t + e * NTHREADS;
            int p = idx >> 5, c4g = (idx & 31) * 4;
            hj0[e] = (p < cnt)
                ? *(const float4*)(embed + z_s[njb[p]] * FD + c4g)
                : make_float4(0.f, 0.f, 0.f, 0.f);
        }

        // ---- rbf staging (ntl*512 items) ----
        for (int e = 0; e < ntl; e++) {
            int idx = t + e * NTHREADS;
            int p = idx >> 5, k = idx & 31;
            float d = (p < cnt) ? ndb[p] : 1.0f;
            float u = d - CSTEP * (float)k;
            float r = __expf(-GAMMA_ * u * u);
            unsigned short hb = f2bf(r);
            rbf_h[p * RSTU + k] = hb;
            rbf_l[p * RSTU + k] = f2bf(r - bf2f(hb));
        }
        __syncthreads();                   // also fences cnt2[nbuf] zero

        // ---- Phase A (tile loop): u = b1 + rbf@W1; relu; mask ----
        for (int tl = 0; tl < ntl; tl++) {
            int rb = tl * 16;
            f32x4 u0 = {bb0, bb0, bb0, bb0};
            short8v rh = *(const short8v*)(rbf_h + (rb + lr) * RSTU + lg * 8);
            short8v rl = *(const short8v*)(rbf_l + (rb + lr) * RSTU + lg * 8);
            u0 = MFMA_B16(rh, w1h_r, u0, 0,0,0);
            u0 = MFMA_B16(rh, w1l_r, u0, 0,0,0);
            u0 = MFMA_B16(rl, w1h_r, u0, 0,0,0);
            // C/D: col=lane&15, row=(lane>>4)*4+reg  [verified]
#pragma unroll
            for (int r = 0; r < 4; r++) {
                int p = rb + lg * 4 + r;
                if (u0[r] > 0.f) mk |= 1u << (4 * tl + r);
                float v = fmaxf(u0[r], 0.f);
                unsigned short hb = f2bf(v);
                a1h[p * TST + c0] = hb;
                a1l[p * TST + c0] = f2bf(v - bf2f(hb));
            }
        }
        __syncthreads();

        // ---- Phase B (tile loop): filt = a1@W2; accumulate m ----
        for (int tl = 0; tl < ntl; tl++) {
            int rb = tl * 16;
            float hv[4];
#pragma unroll
            for (int r = 0; r < 4; r++) {
                int p = rb + lg * 4 + r;
                hv[r] = (p < cnt) ? embed[z_s[njb[p]] * FD + c0] : 0.f;
            }
            f32x4 acc = {0.f, 0.f, 0.f, 0.f};
#pragma unroll
            for (int ks = 0; ks < 4; ks++) {
                int kb = ks * 32 + lg * 8;
                short8v ah = *(const short8v*)(a1h + (rb + lr) * TST + kb);
                short8v al = *(const short8v*)(a1l + (rb + lr) * TST + kb);
                acc = MFMA_B16(ah, w2f_h[ks], acc, 0,0,0);
                acc = MFMA_B16(ah, w2f_l[ks], acc, 0,0,0);
                acc = MFMA_B16(al, w2f_h[ks], acc, 0,0,0);
            }
#pragma unroll
            for (int r = 0; r < 4; r++) macc0 += (acc[r] + b2c0) * hv[r];
        }

        // ---- overlap: build NEXT atom's neighbor list (buf^1) ----
        // Runs while mbar section below stalls on shuffles/barriers; its
        // q loads are L2-warm. cnt2[nbuf] zero fenced by staging barrier.
        if (a < 2) {
            int in = b + NBLOCKS * (a + 1);
            float qx = q[in*3], qy = q[in*3+1], qz = q[in*3+2];
            for (int j = t; j < N_ATOMS; j += NTHREADS) {
                if (j == in) continue;
                float dx = qx - q[j*3], dy = qy - q[j*3+1], dz = qz - q[j*3+2];
                float d2 = dx*dx + dy*dy + dz*dz;
                if (d2 < CUT2) {
                    int p = atomicAdd(&cnt2[nbuf], 1);
                    if (p < MAXN) { nj2[nbuf][p] = j; nd2[nbuf][p] = sqrtf(d2);
                                    ndx2[nbuf][p] = dx; ndy2[nbuf][p] = dy;
                                    ndz2[nbuf][p] = dz; }
                }
            }
        }

        // ---- m reduce -> LDS mrow ----
        {
            float r0 = macc0 + __shfl_xor(macc0, 16, 64);
            r0 += __shfl_xor(r0, 32, 64);
            if (lg == 0) mrow[c0] = r0;    // 8 waves x 16 lr cover 0..127
        }
        __syncthreads();

        // ---- mbar: in-wave GEMVs (lg = f-quarter) ----
        {
            int f0h = lg * 32;
            float g = 0.f;
#pragma unroll 8
            for (int f = f0h; f < f0h + 32; f++)
                g += mrow[f] * W3[f * FD + c0];              // W3[f][c0] strided
            g += __shfl_xor(g, 16, 64);
            g += __shfl_xor(g, 32, 64);
            if (lg == 0) gb[c0] = (g > 0.f) ? wout[c0] : 0.f;
        }
        __syncthreads();
        {
            int f0h = lg * 32;
            float mb = 0.f;
#pragma unroll
            for (int f4 = 0; f4 < 32; f4 += 4) {
                float4 w  = *(const float4*)(W3 + c0 * FD + f0h + f4);   // W3[c0][f]
                float4 gv = *(const float4*)(gb + f0h + f4);
                mb += gv.x*w.x + gv.y*w.y + gv.z*w.z + gv.w*w.w;
            }
            mb += __shfl_xor(mb, 16, 64);
            mb += __shfl_xor(mb, 32, 64);
            if (lg == 0) mbrow[c0] = mb;
        }
        __syncthreads();

        // ---- bwd: crbf + ts staging (ntl*512 items each) ----
        for (int e = 0; e < ntl; e++) {
            int idx = t + e * NTHREADS;
            int p = idx >> 5, k = idx & 31;
            float d = (p < cnt) ? ndb[p] : 1.0f;
            float u = d - CSTEP * (float)k;
            float r = __expf(-GAMMA_ * u * u);
            float cd = -2.f * GAMMA_ * u * r;
            unsigned short hc = f2bf(cd);
            crbf_h[p * RSTU + k] = hc;
            crbf_l[p * RSTU + k] = f2bf(cd - bf2f(hc));
        }
        for (int e = 0; e < ntl; e++) {
            int idx = t + e * NTHREADS;
            int p = idx >> 5, c4g = (idx & 31) * 4;
            ushort4 hv = {0,0,0,0}, lv = {0,0,0,0};
            if (p < cnt) {
                float4 mb4 = *(const float4*)(mbrow + c4g);
                float4 hj4 = (e < 2) ? hj0[e]
                    : *(const float4*)(embed + z_s[njb[p]] * FD + c4g);
                float v0 = mb4.x*hj4.x, v1 = mb4.y*hj4.y;
                float v2 = mb4.z*hj4.z, v3 = mb4.w*hj4.w;
                hv.x = f2bf(v0); lv.x = f2bf(v0 - bf2f(hv.x));
                hv.y = f2bf(v1); lv.y = f2bf(v1 - bf2f(hv.y));
                hv.z = f2bf(v2); lv.z = f2bf(v2 - bf2f(hv.z));
                hv.w = f2bf(v3); lv.w = f2bf(v3 - bf2f(hv.w));
            }
            *(ushort4*)(ts_h + p * TST + c4g) = hv;
            *(ushort4*)(ts_l + p * TST + c4g) = lv;
        }
        __syncthreads();                   // crbf + ts ready

        // ---- bwd (tile loop): gef + GEMM + fold + reduce ----
        for (int tl = 0; tl < ntl; tl++) {
            int rb = tl * 16;
            f32x4 ef = {0.f, 0.f, 0.f, 0.f};
            {
                short8v ch = *(const short8v*)(crbf_h + (rb + lr) * RSTU + lg * 8);
                short8v cl = *(const short8v*)(crbf_l + (rb + lr) * RSTU + lg * 8);
                ef = MFMA_B16(ch, w1h_r, ef, 0,0,0);
                ef = MFMA_B16(ch, w1l_r, ef, 0,0,0);
                ef = MFMA_B16(cl, w1h_r, ef, 0,0,0);
            }
            unsigned int mt = (mk >> (4 * tl)) & 0xFu;
#pragma unroll
            for (int r = 0; r < 4; r++)
                ef[r] = (mt & (1u << r)) ? ef[r] : 0.f;

            f32x4 acc = {0.f, 0.f, 0.f, 0.f};
#pragma unroll
            for (int ks = 0; ks < 4; ks++) {
                int kb = ks * 32 + lg * 8;
                short8v ah = *(const short8v*)(ts_h + (rb + lr) * TST + kb);
                short8v al = *(const short8v*)(ts_l + (rb + lr) * TST + kb);
                acc = MFMA_B16(ah, w2b_h[ks], acc, 0,0,0);
                acc = MFMA_B16(ah, w2b_l[ks], acc, 0,0,0);
                acc = MFMA_B16(al, w2b_h[ks], acc, 0,0,0);
            }

            float p4[4];
#pragma unroll
            for (int r = 0; r < 4; r++) p4[r] = acc[r] * ef[r];
#pragma unroll
            for (int mask = 1; mask < 16; mask <<= 1) {
#pragma unroll
                for (int e = 0; e < 4; e++) p4[e] += __shfl_xor(p4[e], mask, 64);
            }
            if (lr == 0) {
#pragma unroll
                for (int r = 0; r < 4; r++)
                    sred[wid * MAXN + rb + lg * 4 + r] = p4[r];
            }
        }
        __syncthreads();

        // ---- scatter (single pass over up to 64 pairs) ----
        float iax = 0.f, iay = 0.f, iaz = 0.f;
        if (t < MAXN && t < cnt) {
            float s = 0.f;
#pragma unroll
            for (int w = 0; w < 8; w++) s += sred[w * MAXN + t];
            float coef = s / ndb[t];
            float fx = coef * ndxb[t];
            float fy = coef * ndyb[t];
            float fz = coef * ndzb[t];
            iax = fx; iay = fy; iaz = fz;
            atomicAdd(f_acc + njb[t]*3 + 0, fx);
            atomicAdd(f_acc + njb[t]*3 + 1, fy);
            atomicAdd(f_acc + njb[t]*3 + 2, fz);
        }
        if (t < MAXN) {
#pragma unroll
            for (int mask = 1; mask < 64; mask <<= 1) {
                iax += __shfl_xor(iax, mask, 64);
                iay += __shfl_xor(iay, mask, 64);
                iaz += __shfl_xor(iaz, mask, 64);
            }
            if (t == 0 && cnt > 0) {
                atomicAdd(f_acc + i*3 + 0, -iax);
                atomicAdd(f_acc + i*3 + 1, -iay);
                atomicAdd(f_acc + i*3 + 2, -iaz);
            }
        }
        __syncthreads();                   // pools/sred reuse next atom
    }
}

// ---------------------------------------------------------------- finalize
__global__ __launch_bounds__(256) void fin_kernel(
    const float* __restrict__ v, const float* __restrict__ mass,
    const float* __restrict__ p_eta, const float* __restrict__ f_acc,
    float* __restrict__ out)
{
    __shared__ float red[256];
    int t = threadIdx.x;
    float ke = 0.f;
    float c = p_eta[0] / Q0_F;
    for (int idx = t; idx < 3 * N_ATOMS; idx += 256) {
        int a = idx / 3;
        float vv = v[idx], mi = mass[a];
        out[DVDT_OFF + idx] = (f_acc[idx] - c * vv * mi) / mi;
        out[V_OFF + idx] = vv;
        ke += 0.5f * mi * vv * vv;
    }
    red[t] = ke;
    __syncthreads();
    for (int s = 128; s > 0; s >>= 1) {
        if (t < s) red[t] += red[t + s];
        __syncthreads();
    }
    if (t == 0) {
        float k0 = red[0];
        float e0 = p_eta[0], e1 = p_eta[1], e2 = p_eta[2], e3 = p_eta[3];
        out[PETA_OFF + 0] = 2.f * (k0 - TARGET_KE) - e0 * e1 / QI_F;
        out[PETA_OFF + 1] = e0 * e0 / Q0_F - KT_F - e1 * e2 / QI_F;
        out[PETA_OFF + 2] = e1 * e1 / QI_F - KT_F - e2 * e3 / QI_F;
        out[PETA_OFF + 3] = e2 * e2 / QI_F - KT_F;
    }
}

// ---------------------------------------------------------------- launch
extern "C" void kernel_launch(void* const* d_in, const int* in_sizes, int n_in,
                              void* d_out, int out_size, void* d_ws, size_t ws_size,
                              hipStream_t stream)
{
    const float* v     = (const float*)d_in[0];
    const float* q     = (const float*)d_in[1];
    const float* p_eta = (const float*)d_in[2];
    const float* mass  = (const float*)d_in[3];
    const float* embed = (const float*)d_in[4];
    const float* W1    = (const float*)d_in[5];
    const float* b1    = (const float*)d_in[6];
    const float* W2    = (const float*)d_in[7];
    const float* b2    = (const float*)d_in[8];
    const float* W3    = (const float*)d_in[9];
    const float* wout  = (const float*)d_in[10];
    const int*   z     = (const int*)d_in[11];
    float* out = (float*)d_out;

    float* f_acc = (float*)d_ws;                 // only workspace user

    hipMemsetAsync(f_acc, 0, 3 * N_ATOMS * sizeof(float), stream);

    atom_kernel<<<NBLOCKS, NTHREADS, 0, stream>>>(q, W1, b1, W2, b2,
                                                  embed, z, W3, wout, f_acc);
    fin_kernel<<<1, 256, 0, stream>>>(v, mass, p_eta, f_acc, out);
}

// Round 20
// 109.524 us; speedup vs baseline: 1.3442x; 1.0002x over previous
//
#include <hip/hip_runtime.h>
#include <math.h>

// Problem constants (match reference)
#define N_ATOMS 768
#define FD 128          // feature width
#define NRBF 32
#define MAXN 64         // per-atom neighbor cap (mean ~26)
#define NTHREADS 512    // 8 waves/block
#define NBLOCKS 256     // persistent: each block owns atoms b, b+256, b+512
#define TST 136         // padded LDS stride for [*][128] bf16 (ushort) tiles
#define RSTU 40         // padded ushort stride for [*][32] bf16 rbf tiles (80B, 16B-aligned)

constexpr float  CUT2   = 25.0f;
constexpr float  GAMMA_ = 40.96f;            // 1/(5/32)^2
constexpr float  CSTEP  = 5.0f / 31.0f;      // linspace(0,5,32) step
constexpr double KB_D   = 8.617330337217213e-05;
constexpr double KT_D   = 300.0 * KB_D;
constexpr float  KT_F   = (float)KT_D;
constexpr float  TARGET_KE = (float)(0.5 * 2304.0 * KT_D);
constexpr float  Q0_F   = (float)(2.0 * 2304.0 * KT_D * 400.0);  // Q[0]
constexpr float  QI_F   = (float)(2.0 * KT_D * 400.0);           // Q[1..3]

#define DVDT_OFF 0
#define V_OFF    (3 * N_ATOMS)
#define PETA_OFF (6 * N_ATOMS)

using short8v = __attribute__((ext_vector_type(8))) short;
using f32x4   = __attribute__((ext_vector_type(4))) float;

#define MFMA_B16 __builtin_amdgcn_mfma_f32_16x16x32_bf16

__device__ __forceinline__ unsigned short f2bf(float x) {
    unsigned int u = __float_as_uint(x);
    u += 0x7FFF + ((u >> 16) & 1);           // round-to-nearest-even
    return (unsigned short)(u >> 16);
}
__device__ __forceinline__ float bf2f(unsigned short h) {
    return __uint_as_float(((unsigned int)h) << 16);
}

// Hard-won rules (35 rounds of counters):
// 1. NO __launch_bounds__ min-wave hints on GEMM kernels (spill cliff).
// 2. NEVER put __threadfence / completion counters on the hot grid (R14).
// 3. R22-R24 WIN: MFMA split-bf16 (AhBh+AhBl+AlBh, err ~2^-17) for all dense
//    phases. C/D: col=lane&15, row=(lane>>4)*4+reg (verified).
// 4. R26 REGRESSED: multiplying atomics in fused epilogues.
// 5. R28 WIN: fwd+mbar+bwd fused per-atom megakernel.
// 6. R33 WIN: runtime tile loops (I-fetch diet). R34 WIN: prep deleted.
// 7. OccupancyPercent == threads/2048 in EVERY config -> ~1 resident
//    block/CU; kernel = sequential rounds. R35 WIN (-8.4us): persistent
//    256 blocks x 3 atoms; weights/z_s amortized; build(a+1) overlapped.
// 8. R36: (a) end-of-atom barrier removed (scatter fenced from next
//    writers by 2+ barriers); (b) hj0 gathers for atom a+1 issued right
//    after m-reduce barrier of atom a (nj2[nbuf] stable there) — latency
//    hides under mbar+staging+bwd; ts-fill e=0/1 peeled to use carried
//    registers (rule #20: no runtime-indexed float4 arrays).

// ---------------------------------------------------------------- atom (256 blocks x 512, persistent)
__global__ __launch_bounds__(NTHREADS) void atom_kernel(
    const float* __restrict__ q,
    const float* __restrict__ W1, const float* __restrict__ b1,
    const float* __restrict__ W2, const float* __restrict__ b2,
    const float* __restrict__ embed, const int* __restrict__ z,
    const float* __restrict__ W3, const float* __restrict__ wout,
    float* __restrict__ f_acc)
{
    __shared__ int   nj2[2][MAXN];
    __shared__ float nd2[2][MAXN], ndx2[2][MAXN], ndy2[2][MAXN], ndz2[2][MAXN];
    __shared__ int   cnt2[2];
    __shared__ int   z_s[N_ATOMS];                                   // 3072 B
    // Overlaid pools: fwd {rbf,a1} and bwd {crbf,ts} are temporally disjoint.
    __shared__ __align__(16) unsigned short poolR[2 * MAXN * RSTU];  // 10240 B
    __shared__ __align__(16) unsigned short poolA[2 * MAXN * TST];   // 34816 B
    __shared__ float mrow[FD], gb[FD], mbrow[FD];                    // 1536 B
    __shared__ float sred[8 * MAXN];                                 // 2048 B
    // total ~54.4 KB

    unsigned short* rbf_h  = poolR;
    unsigned short* rbf_l  = poolR + MAXN * RSTU;
    unsigned short* crbf_h = poolR;                // overlay (bwd)
    unsigned short* crbf_l = poolR + MAXN * RSTU;
    unsigned short* a1h  = poolA;
    unsigned short* a1l  = poolA + MAXN * TST;
    unsigned short* ts_h = poolA;                  // overlay (bwd)
    unsigned short* ts_l = poolA + MAXN * TST;

    int b = blockIdx.x, t = threadIdx.x;
    int wid = t >> 6, lane = t & 63;             // wid 0..7
    int lr = lane & 15, lg = lane >> 4;
    int c0 = wid * 16 + lr;                      // this wave's single col-tile

    if (t < 2) cnt2[t] = 0;
    __syncthreads();

    // fp32 fwd-weight fragment loads issued NOW — latency covered by the
    // z_s staging + first neighbor build below (R31 pattern).
    float w1f32[8], w2ff32[4][8];
#pragma unroll
    for (int e = 0; e < 8; e++)
        w1f32[e] = W1[(lg * 8 + e) * FD + c0];           // W1[k][c0]
#pragma unroll
    for (int ks = 0; ks < 4; ks++)
#pragma unroll
        for (int e = 0; e < 8; e++)
            w2ff32[ks][e] = W2[(ks * 32 + lg * 8 + e) * FD + c0];  // W2[k][c0]
    float bb0  = b1[c0];
    float b2c0 = b2[c0];

    // z_s staging + neighbor build for atom b (buf 0)
    {
        float qx = q[b*3], qy = q[b*3+1], qz = q[b*3+2];
        for (int j = t; j < N_ATOMS; j += NTHREADS) {
            z_s[j] = z[j];
            if (j == b) continue;
            float dx = qx - q[j*3], dy = qy - q[j*3+1], dz = qz - q[j*3+2];
            float d2 = dx*dx + dy*dy + dz*dz;
            if (d2 < CUT2) {
                int p = atomicAdd(&cnt2[0], 1);
                if (p < MAXN) { nj2[0][p] = j; nd2[0][p] = sqrtf(d2);
                                ndx2[0][p] = dx; ndy2[0][p] = dy; ndz2[0][p] = dz; }
            }
        }
    }

    // Split fwd weights to bf16 hi/lo registers (same values as old prep).
    short8v w1h_r, w1l_r, w2f_h[4], w2f_l[4];
#pragma unroll
    for (int e = 0; e < 8; e++) {
        unsigned short hb = f2bf(w1f32[e]);
        w1h_r[e] = (short)hb;
        w1l_r[e] = (short)f2bf(w1f32[e] - bf2f(hb));
    }
#pragma unroll
    for (int ks = 0; ks < 4; ks++)
#pragma unroll
        for (int e = 0; e < 8; e++) {
            unsigned short hb = f2bf(w2ff32[ks][e]);
            w2f_h[ks][e] = (short)hb;
            w2f_l[ks][e] = (short)f2bf(w2ff32[ks][e] - bf2f(hb));
        }
    // bwd weights: contiguous fp32 rows of W2, split immediately (low pressure).
    short8v w2b_h[4], w2b_l[4];
#pragma unroll
    for (int ks = 0; ks < 4; ks++) {
        int kb = ks * 32 + lg * 8;
        float4 a4 = *(const float4*)(W2 + c0 * FD + kb);      // W2[c0][k..]
        float4 b4 = *(const float4*)(W2 + c0 * FD + kb + 4);
        float vv[8] = {a4.x, a4.y, a4.z, a4.w, b4.x, b4.y, b4.z, b4.w};
#pragma unroll
        for (int e = 0; e < 8; e++) {
            unsigned short hb = f2bf(vv[e]);
            w2b_h[ks][e] = (short)hb;
            w2b_l[ks][e] = (short)f2bf(vv[e] - bf2f(hb));
        }
    }
    __syncthreads();                       // build(atom b) + z_s complete

    // hj0 prefetch for atom 0 (ts-fill rows 0-31), carried in registers.
    float4 hj0_0, hj0_1;
    {
        int cnt0 = min(cnt2[0], MAXN);
        int p0 = t >> 5, c4g = (t & 31) * 4;
        int p1 = (t + NTHREADS) >> 5;
        hj0_0 = (p0 < cnt0)
            ? *(const float4*)(embed + z_s[nj2[0][p0]] * FD + c4g)
            : make_float4(0.f, 0.f, 0.f, 0.f);
        hj0_1 = (p1 < cnt0)
            ? *(const float4*)(embed + z_s[nj2[0][p1]] * FD + c4g)
            : make_float4(0.f, 0.f, 0.f, 0.f);
    }

    // ================= persistent atom loop ================================
    for (int a = 0; a < 3; a++) {
        int i   = b + NBLOCKS * a;
        int buf = a & 1;
        int nbuf = buf ^ 1;
        int* njb = nj2[buf];
        float* ndb = nd2[buf], *ndxb = ndx2[buf], *ndyb = ndy2[buf], *ndzb = ndz2[buf];

        int cnt = min(cnt2[buf], MAXN);
        int ntl = (cnt + 15) >> 4;                   // 0..4 (block-uniform)
        if (a < 2 && t == 0) cnt2[nbuf] = 0;         // fenced by staging barrier

        float macc0 = 0.f;                           // m[i][c0] partial
        unsigned int mk = 0;                         // relu gate mask (4b/tile)

        // ---- rbf staging (ntl*512 items) ----
        for (int e = 0; e < ntl; e++) {
            int idx = t + e * NTHREADS;
            int p = idx >> 5, k = idx & 31;
            float d = (p < cnt) ? ndb[p] : 1.0f;
            float u = d - CSTEP * (float)k;
            float r = __expf(-GAMMA_ * u * u);
            unsigned short hb = f2bf(r);
            rbf_h[p * RSTU + k] = hb;
            rbf_l[p * RSTU + k] = f2bf(r - bf2f(hb));
        }
        __syncthreads();                   // also fences cnt2[nbuf] zero + scatter(a-1)

        // ---- Phase A (tile loop): u = b1 + rbf@W1; relu; mask ----
        for (int tl = 0; tl < ntl; tl++) {
            int rb = tl * 16;
            f32x4 u0 = {bb0, bb0, bb0, bb0};
            short8v rh = *(const short8v*)(rbf_h + (rb + lr) * RSTU + lg * 8);
            short8v rl = *(const short8v*)(rbf_l + (rb + lr) * RSTU + lg * 8);
            u0 = MFMA_B16(rh, w1h_r, u0, 0,0,0);
            u0 = MFMA_B16(rh, w1l_r, u0, 0,0,0);
            u0 = MFMA_B16(rl, w1h_r, u0, 0,0,0);
            // C/D: col=lane&15, row=(lane>>4)*4+reg  [verified]
#pragma unroll
            for (int r = 0; r < 4; r++) {
                int p = rb + lg * 4 + r;
                if (u0[r] > 0.f) mk |= 1u << (4 * tl + r);
                float v = fmaxf(u0[r], 0.f);
                unsigned short hb = f2bf(v);
                a1h[p * TST + c0] = hb;
                a1l[p * TST + c0] = f2bf(v - bf2f(hb));
            }
        }
        __syncthreads();

        // ---- Phase B (tile loop): filt = a1@W2; accumulate m ----
        for (int tl = 0; tl < ntl; tl++) {
            int rb = tl * 16;
            float hv[4];
#pragma unroll
            for (int r = 0; r < 4; r++) {
                int p = rb + lg * 4 + r;
                hv[r] = (p < cnt) ? embed[z_s[njb[p]] * FD + c0] : 0.f;
            }
            f32x4 acc = {0.f, 0.f, 0.f, 0.f};
#pragma unroll
            for (int ks = 0; ks < 4; ks++) {
                int kb = ks * 32 + lg * 8;
                short8v ah = *(const short8v*)(a1h + (rb + lr) * TST + kb);
                short8v al = *(const short8v*)(a1l + (rb + lr) * TST + kb);
                acc = MFMA_B16(ah, w2f_h[ks], acc, 0,0,0);
                acc = MFMA_B16(ah, w2f_l[ks], acc, 0,0,0);
                acc = MFMA_B16(al, w2f_h[ks], acc, 0,0,0);
            }
#pragma unroll
            for (int r = 0; r < 4; r++) macc0 += (acc[r] + b2c0) * hv[r];
        }

        // ---- overlap: build NEXT atom's neighbor list (buf^1) ----
        if (a < 2) {
            int in = b + NBLOCKS * (a + 1);
            float qx = q[in*3], qy = q[in*3+1], qz = q[in*3+2];
            for (int j = t; j < N_ATOMS; j += NTHREADS) {
                if (j == in) continue;
                float dx = qx - q[j*3], dy = qy - q[j*3+1], dz = qz - q[j*3+2];
                float d2 = dx*dx + dy*dy + dz*dz;
                if (d2 < CUT2) {
                    int p = atomicAdd(&cnt2[nbuf], 1);
                    if (p < MAXN) { nj2[nbuf][p] = j; nd2[nbuf][p] = sqrtf(d2);
                                    ndx2[nbuf][p] = dx; ndy2[nbuf][p] = dy;
                                    ndz2[nbuf][p] = dz; }
                }
            }
        }

        // ---- m reduce -> LDS mrow ----
        {
            float r0 = macc0 + __shfl_xor(macc0, 16, 64);
            r0 += __shfl_xor(r0, 32, 64);
            if (lg == 0) mrow[c0] = r0;    // 8 waves x 16 lr cover 0..127
        }
        __syncthreads();                   // fences build(a+1) writes too

        // ---- prefetch NEXT atom's hj0 gathers (nj2[nbuf] stable now) ----
        float4 nx0 = make_float4(0.f,0.f,0.f,0.f);
        float4 nx1 = make_float4(0.f,0.f,0.f,0.f);
        if (a < 2) {
            int cntn = min(cnt2[nbuf], MAXN);
            int p0 = t >> 5, c4g = (t & 31) * 4;
            int p1 = (t + NTHREADS) >> 5;
            if (p0 < cntn)
                nx0 = *(const float4*)(embed + z_s[nj2[nbuf][p0]] * FD + c4g);
            if (p1 < cntn)
                nx1 = *(const float4*)(embed + z_s[nj2[nbuf][p1]] * FD + c4g);
        }

        // ---- mbar: in-wave GEMVs (lg = f-quarter) ----
        {
            int f0h = lg * 32;
            float g = 0.f;
#pragma unroll 8
            for (int f = f0h; f < f0h + 32; f++)
                g += mrow[f] * W3[f * FD + c0];              // W3[f][c0] strided
            g += __shfl_xor(g, 16, 64);
            g += __shfl_xor(g, 32, 64);
            if (lg == 0) gb[c0] = (g > 0.f) ? wout[c0] : 0.f;
        }
        __syncthreads();
        {
            int f0h = lg * 32;
            float mb = 0.f;
#pragma unroll
            for (int f4 = 0; f4 < 32; f4 += 4) {
                float4 w  = *(const float4*)(W3 + c0 * FD + f0h + f4);   // W3[c0][f]
                float4 gv = *(const float4*)(gb + f0h + f4);
                mb += gv.x*w.x + gv.y*w.y + gv.z*w.z + gv.w*w.w;
            }
            mb += __shfl_xor(mb, 16, 64);
            mb += __shfl_xor(mb, 32, 64);
            if (lg == 0) mbrow[c0] = mb;
        }
        __syncthreads();

        // ---- bwd: crbf staging (ntl*512 items) ----
        for (int e = 0; e < ntl; e++) {
            int idx = t + e * NTHREADS;
            int p = idx >> 5, k = idx & 31;
            float d = (p < cnt) ? ndb[p] : 1.0f;
            float u = d - CSTEP * (float)k;
            float r = __expf(-GAMMA_ * u * u);
            float cd = -2.f * GAMMA_ * u * r;
            unsigned short hc = f2bf(cd);
            crbf_h[p * RSTU + k] = hc;
            crbf_l[p * RSTU + k] = f2bf(cd - bf2f(hc));
        }
        // ---- ts fill: e=0/1 peeled (carried hj0 regs), e>=2 loads ----
        {
            int p0 = t >> 5, c4g = (t & 31) * 4;
            if (ntl > 0) {
                ushort4 hv = {0,0,0,0}, lv = {0,0,0,0};
                if (p0 < cnt) {
                    float4 mb4 = *(const float4*)(mbrow + c4g);
                    float v0 = mb4.x*hj0_0.x, v1 = mb4.y*hj0_0.y;
                    float v2 = mb4.z*hj0_0.z, v3 = mb4.w*hj0_0.w;
                    hv.x = f2bf(v0); lv.x = f2bf(v0 - bf2f(hv.x));
                    hv.y = f2bf(v1); lv.y = f2bf(v1 - bf2f(hv.y));
                    hv.z = f2bf(v2); lv.z = f2bf(v2 - bf2f(hv.z));
                    hv.w = f2bf(v3); lv.w = f2bf(v3 - bf2f(hv.w));
                }
                *(ushort4*)(ts_h + p0 * TST + c4g) = hv;
                *(ushort4*)(ts_l + p0 * TST + c4g) = lv;
            }
            if (ntl > 1) {
                int p1 = (t + NTHREADS) >> 5;
                ushort4 hv = {0,0,0,0}, lv = {0,0,0,0};
                if (p1 < cnt) {
                    float4 mb4 = *(const float4*)(mbrow + c4g);
                    float v0 = mb4.x*hj0_1.x, v1 = mb4.y*hj0_1.y;
                    float v2 = mb4.z*hj0_1.z, v3 = mb4.w*hj0_1.w;
                    hv.x = f2bf(v0); lv.x = f2bf(v0 - bf2f(hv.x));
                    hv.y = f2bf(v1); lv.y = f2bf(v1 - bf2f(hv.y));
                    hv.z = f2bf(v2); lv.z = f2bf(v2 - bf2f(hv.z));
                    hv.w = f2bf(v3); lv.w = f2bf(v3 - bf2f(hv.w));
                }
                *(ushort4*)(ts_h + p1 * TST + c4g) = hv;
                *(ushort4*)(ts_l + p1 * TST + c4g) = lv;
            }
            for (int e = 2; e < ntl; e++) {
                int idx = t + e * NTHREADS;
                int p = idx >> 5;
                ushort4 hv = {0,0,0,0}, lv = {0,0,0,0};
                if (p < cnt) {
                    float4 mb4 = *(const float4*)(mbrow + c4g);
                    float4 hj4 = *(const float4*)(embed + z_s[njb[p]] * FD + c4g);
                    float v0 = mb4.x*hj4.x, v1 = mb4.y*hj4.y;
                    float v2 = mb4.z*hj4.z, v3 = mb4.w*hj4.w;
                    hv.x = f2bf(v0); lv.x = f2bf(v0 - bf2f(hv.x));
                    hv.y = f2bf(v1); lv.y = f2bf(v1 - bf2f(hv.y));
                    hv.z = f2bf(v2); lv.z = f2bf(v2 - bf2f(hv.z));
                    hv.w = f2bf(v3); lv.w = f2bf(v3 - bf2f(hv.w));
                }
                *(ushort4*)(ts_h + p * TST + c4g) = hv;
                *(ushort4*)(ts_l + p * TST + c4g) = lv;
            }
        }
        __syncthreads();                   // crbf + ts ready

        // ---- bwd (tile loop): gef + GEMM + fold + reduce ----
        for (int tl = 0; tl < ntl; tl++) {
            int rb = tl * 16;
            f32x4 ef = {0.f, 0.f, 0.f, 0.f};
            {
                short8v ch = *(const short8v*)(crbf_h + (rb + lr) * RSTU + lg * 8);
                short8v cl = *(const short8v*)(crbf_l + (rb + lr) * RSTU + lg * 8);
                ef = MFMA_B16(ch, w1h_r, ef, 0,0,0);
                ef = MFMA_B16(ch, w1l_r, ef, 0,0,0);
                ef = MFMA_B16(cl, w1h_r, ef, 0,0,0);
            }
            unsigned int mt = (mk >> (4 * tl)) & 0xFu;
#pragma unroll
            for (int r = 0; r < 4; r++)
                ef[r] = (mt & (1u << r)) ? ef[r] : 0.f;

            f32x4 acc = {0.f, 0.f, 0.f, 0.f};
#pragma unroll
            for (int ks = 0; ks < 4; ks++) {
                int kb = ks * 32 + lg * 8;
                short8v ah = *(const short8v*)(ts_h + (rb + lr) * TST + kb);
                short8v al = *(const short8v*)(ts_l + (rb + lr) * TST + kb);
                acc = MFMA_B16(ah, w2b_h[ks], acc, 0,0,0);
                acc = MFMA_B16(ah, w2b_l[ks], acc, 0,0,0);
                acc = MFMA_B16(al, w2b_h[ks], acc, 0,0,0);
            }

            float p4[4];
#pragma unroll
            for (int r = 0; r < 4; r++) p4[r] = acc[r] * ef[r];
#pragma unroll
            for (int mask = 1; mask < 16; mask <<= 1) {
#pragma unroll
                for (int e = 0; e < 4; e++) p4[e] += __shfl_xor(p4[e], mask, 64);
            }
            if (lr == 0) {
#pragma unroll
                for (int r = 0; r < 4; r++)
                    sred[wid * MAXN + rb + lg * 4 + r] = p4[r];
            }
        }
        __syncthreads();

        // ---- scatter (single pass over up to 64 pairs) ----
        float iax = 0.f, iay = 0.f, iaz = 0.f;
        if (t < MAXN && t < cnt) {
            float s = 0.f;
#pragma unroll
            for (int w = 0; w < 8; w++) s += sred[w * MAXN + t];
            float coef = s / ndb[t];
            float fx = coef * ndxb[t];
            float fy = coef * ndyb[t];
            float fz = coef * ndzb[t];
            iax = fx; iay = fy; iaz = fz;
            atomicAdd(f_acc + njb[t]*3 + 0, fx);
            atomicAdd(f_acc + njb[t]*3 + 1, fy);
            atomicAdd(f_acc + njb[t]*3 + 2, fz);
        }
        if (t < MAXN) {
#pragma unroll
            for (int mask = 1; mask < 64; mask <<= 1) {
                iax += __shfl_xor(iax, mask, 64);
                iay += __shfl_xor(iay, mask, 64);
                iaz += __shfl_xor(iaz, mask, 64);
            }
            if (t == 0 && cnt > 0) {
                atomicAdd(f_acc + i*3 + 0, -iax);
                atomicAdd(f_acc + i*3 + 1, -iay);
                atomicAdd(f_acc + i*3 + 2, -iaz);
            }
        }
        // NO end-of-atom barrier (R36): scatter's sred/neighbor reads are
        // fenced from next writers by the next atom's staging + phase
        // barriers; scatter atomics drain under next rbf staging.
        hj0_0 = nx0;
        hj0_1 = nx1;
    }
}

// ---------------------------------------------------------------- finalize
__global__ __launch_bounds__(256) void fin_kernel(
    const float* __restrict__ v, const float* __restrict__ mass,
    const float* __restrict__ p_eta, const float* __restrict__ f_acc,
    float* __restrict__ out)
{
    __shared__ float red[256];
    int t = threadIdx.x;
    float ke = 0.f;
    float c = p_eta[0] / Q0_F;
    for (int idx = t; idx < 3 * N_ATOMS; idx += 256) {
        int a = idx / 3;
        float vv = v[idx], mi = mass[a];
        out[DVDT_OFF + idx] = (f_acc[idx] - c * vv * mi) / mi;
        out[V_OFF + idx] = vv;
        ke += 0.5f * mi * vv * vv;
    }
    red[t] = ke;
    __syncthreads();
    for (int s = 128; s > 0; s >>= 1) {
        if (t < s) red[t] += red[t + s];
        __syncthreads();
    }
    if (t == 0) {
        float k0 = red[0];
        float e0 = p_eta[0], e1 = p_eta[1], e2 = p_eta[2], e3 = p_eta[3];
        out[PETA_OFF + 0] = 2.f * (k0 - TARGET_KE) - e0 * e1 / QI_F;
        out[PETA_OFF + 1] = e0 * e0 / Q0_F - KT_F - e1 * e2 / QI_F;
        out[PETA_OFF + 2] = e1 * e1 / QI_F - KT_F - e2 * e3 / QI_F;
        out[PETA_OFF + 3] = e2 * e2 / QI_F - KT_F;
    }
}

// ---------------------------------------------------------------- launch
extern "C" void kernel_launch(void* const* d_in, const int* in_sizes, int n_in,
                              void* d_out, int out_size, void* d_ws, size_t ws_size,
                              hipStream_t stream)
{
    const float* v     = (const float*)d_in[0];
    const float* q     = (const float*)d_in[1];
    const float* p_eta = (const float*)d_in[2];
    const float* mass  = (const float*)d_in[3];
    const float* embed = (const float*)d_in[4];
    const float* W1    = (const float*)d_in[5];
    const float* b1    = (const float*)d_in[6];
    const float* W2    = (const float*)d_in[7];
    const float* b2    = (const float*)d_in[8];
    const float* W3    = (const float*)d_in[9];
    const float* wout  = (const float*)d_in[10];
    const int*   z     = (const int*)d_in[11];
    float* out = (float*)d_out;

    float* f_acc = (float*)d_ws;                 // only workspace user

    hipMemsetAsync(f_acc, 0, 3 * N_ATOMS * sizeof(float), stream);

    atom_kernel<<<NBLOCKS, NTHREADS, 0, stream>>>(q, W1, b1, W2, b2,
                                                  embed, z, W3, wout, f_acc);
    fin_kernel<<<1, 256, 0, stream>>>(v, mass, p_eta, f_acc, out);
}